// Round 2
// baseline (492.398 us; speedup 1.0000x reference)
//
#include <hip/hip_runtime.h>
#include <hip/hip_bf16.h>

constexpr int B = 4, L = 256, D = 256;
constexpr int RS = 288, PADC = 16;            // padded row stride / col offset
constexpr size_t SZ  = (size_t)B * L * D;     // 262144
constexpr size_t SZP = (size_t)B * L * RS;    // 294912

// workspace offsets (floats)
constexpr size_t OFF_E1   = 0;
constexpr size_t OFF_E2   = OFF_E1 + SZ;
constexpr size_t OFF_Q    = OFF_E2 + SZ;
constexpr size_t OFF_KT   = OFF_Q + SZ;
constexpr size_t OFF_S    = OFF_KT + SZ;
constexpr size_t OFF_STN  = OFF_S + SZ;
constexpr size_t OFF_TMPA = OFF_STN + SZ;           // 2 proteins padded
constexpr size_t OFF_TMPB = OFF_TMPA + 2 * SZP;
constexpr size_t OFF_BS   = OFF_TMPB + 2 * SZP;     // 256
constexpr size_t OFF_SUM  = OFF_BS + 256;           // 4
constexpr size_t OFF_PP   = OFF_SUM + 4;            // 65536
constexpr size_t OFF_POOL = OFF_PP + 65536;         // 1024
constexpr size_t OFF_H    = OFF_POOL + 1024;        // 8192
constexpr size_t OFF_F1P  = OFF_H + 8192;           // 19200
constexpr size_t OFF_H1   = OFF_F1P + 19200;        // 2400
constexpr size_t OFF_H2   = OFF_H1 + 2400;          // 1200

__device__ __forceinline__ float tanh_fast(float x) {
  float e = __expf(2.0f * x);
  return 1.0f - __fdividef(2.0f, e + 1.0f);
}
__device__ __forceinline__ float sig_fast(float x) {
  return __fdividef(1.0f, 1.0f + __expf(-x));
}
__device__ __forceinline__ float lrelu(float x) { return x >= 0.0f ? x : 0.1f * x; }

// ---------------- embedding ----------------
__global__ __launch_bounds__(256) void k_embed(const int* __restrict__ t1,
                                               const int* __restrict__ t2,
                                               const float* __restrict__ emb,
                                               float* __restrict__ ws) {
  int blk = blockIdx.x;                 // p(1) b(2) l(8)
  int l = blk & 255, b = (blk >> 8) & 3, p = blk >> 10;
  const int* tok = p ? t2 : t1;
  int tv = tok[b * L + l];
  float* dst = ws + OFF_TMPA + (size_t)p * SZP + (size_t)(b * L + l) * RS + PADC;
  dst[threadIdx.x] = emb[(size_t)tv * D + threadIdx.x];
}

// ---------------- fused conv: LDS-staged, 8 oc/thread, bias+relu epilogue ----------------
// Block: 512 threads. Computes 8 output channels x 256 cols for one (p,b).
// Contraction over 256 input rows, split per 16-row chunk: waves 0-3 take rows 0-7,
// waves 4-7 take rows 8-15 of each chunk; LDS reduce at the end.
template <int K, int PL>
__global__ __launch_bounds__(512) void k_conv(const float* __restrict__ in,   // padded [p][b*256+i][RS]
                                              const float* __restrict__ w,    // [O][I][K]
                                              const float* __restrict__ bias,
                                              float* __restrict__ outp,
                                              int out_rs, int out_pad, size_t out_pstride) {
  constexpr int CH = 16;                      // rows per chunk
  constexpr int V4 = CH * RS / 4;             // 1152 float4 per chunk
  __shared__ float sx[2][CH * RS];            // 2 x 18 KB

  int blk = blockIdx.x;                       // p(1) b(2) oct(5)
  int oct = blk & 31, b = (blk >> 5) & 3, p = blk >> 7;
  int oc0 = oct * 8;
  int tid = threadIdx.x;
  int j = tid & 255, half = tid >> 8;         // half: contraction split within chunk

  const float* src = in + (size_t)p * SZP + (size_t)b * 256 * RS;
  const float4* s4 = (const float4*)src;

  float4 pre0, pre1, pre2;
  // prefetch chunk 0
  pre0 = s4[tid]; pre1 = s4[tid + 512];
  if (tid < 128) pre2 = s4[tid + 1024];

  float acc[8];
#pragma unroll
  for (int m = 0; m < 8; ++m) acc[m] = 0.0f;

  for (int c = 0; c < 16; ++c) {
    float* sbuf = sx[c & 1];
    float4* d4 = (float4*)sbuf;
    d4[tid] = pre0; d4[tid + 512] = pre1;
    if (tid < 128) d4[tid + 1024] = pre2;
    __syncthreads();
    if (c < 15) {
      const float4* n4 = s4 + (size_t)(c + 1) * V4;
      pre0 = n4[tid]; pre1 = n4[tid + 512];
      if (tid < 128) pre2 = n4[tid + 1024];
    }
    int rbase = half * 8;                     // LDS row base for this half
    int ibase = c * CH + rbase;               // global contraction row
#pragma unroll 2
    for (int r = 0; r < 8; ++r) {
      const float* row = sbuf + (rbase + r) * RS + (PADC - PL) + j;
      float xw[K];
#pragma unroll
      for (int q = 0; q < K; ++q) xw[q] = row[q];
      // force wave-uniform (scalar) weight base
      int woff = __builtin_amdgcn_readfirstlane((oc0 * 256 + ibase + r) * K);
      const float* wrow = w + woff;
#pragma unroll
      for (int m = 0; m < 8; ++m) {
#pragma unroll
        for (int q = 0; q < K; ++q)
          acc[m] = fmaf(wrow[m * 256 * K + q], xw[q], acc[m]);
      }
    }
    __syncthreads();
  }

  // cross-half reduction via LDS
  float* red = sx[0];
  if (half == 1) {
#pragma unroll
    for (int m = 0; m < 8; ++m) red[m * 256 + j] = acc[m];
  }
  __syncthreads();
  if (half == 0) {
    float* ob = outp + (size_t)p * out_pstride + ((size_t)b * 256 + oc0) * out_rs + out_pad + j;
#pragma unroll
    for (int m = 0; m < 8; ++m) {
      float s = acc[m] + red[m * 256 + j] + bias[oc0 + m];
      ob[(size_t)m * out_rs] = fmaxf(s, 0.0f);
    }
  }
}

// ---------------- joint-attention projections: q and k^T ----------------
__global__ __launch_bounds__(256) void k_ja(const float* __restrict__ e_base,
                                            const float* __restrict__ w1,
                                            const float* __restrict__ b1,
                                            const float* __restrict__ w2,
                                            const float* __restrict__ b2,
                                            float* __restrict__ q,
                                            float* __restrict__ kT) {
  int blk = blockIdx.x;                 // p(1) b(2) it(5)
  int it = blk & 31, b = (blk >> 5) & 3, p = blk >> 7;
  int n = threadIdx.x, i0 = it * 8;
  const float* e = e_base + (size_t)p * SZ + ((size_t)b * 256 + i0) * 256;
  const float* W = p ? w2 : w1;
  float bv = (p ? b2 : b1)[n];
  float a[8];
#pragma unroll
  for (int m = 0; m < 8; ++m) a[m] = bv;
#pragma unroll 4
  for (int d = 0; d < 256; ++d) {
    float wv = W[(size_t)d * 256 + n];
#pragma unroll
    for (int m = 0; m < 8; ++m) a[m] = fmaf(e[m * 256 + d], wv, a[m]);
  }
  if (p == 0) {
    float* qp = q + ((size_t)b * 256 + i0) * 256 + n;
#pragma unroll
    for (int m = 0; m < 8; ++m) qp[(size_t)m * 256] = a[m];
  } else {
    float* kp = kT + ((size_t)b * 256 + n) * 256 + i0;
    float4 v0 = make_float4(a[0], a[1], a[2], a[3]);
    float4 v1 = make_float4(a[4], a[5], a[6], a[7]);
    *(float4*)kp = v0;
    *(float4*)(kp + 4) = v1;
  }
}

// ---------------- scores: sigmoid(q k^T) + block partial sums ----------------
__global__ __launch_bounds__(256) void k_scores(const float* __restrict__ q,
                                                const float* __restrict__ kT,
                                                float* __restrict__ S,
                                                float* __restrict__ bsums) {
  int blk = blockIdx.x;                 // b(2) it(5) -> 128 blocks
  int it = blk & 31, b = blk >> 5;
  int k = threadIdx.x, i0 = it * 8;
  const float* qb = q + ((size_t)b * 256 + i0) * 256;
  const float* kTb = kT + (size_t)b * 65536 + k;
  float a[8];
#pragma unroll
  for (int m = 0; m < 8; ++m) a[m] = 0.0f;
#pragma unroll 4
  for (int n = 0; n < 256; ++n) {
    float kv = kTb[(size_t)n * 256];
#pragma unroll
    for (int m = 0; m < 8; ++m) a[m] = fmaf(qb[m * 256 + n], kv, a[m]);
  }
  float tot = 0.0f;
#pragma unroll
  for (int m = 0; m < 8; ++m) {
    float s = sig_fast(a[m]);
    S[((size_t)b * 256 + i0 + m) * 256 + k] = s;
    tot += s;
  }
  __shared__ float red[256];
  red[k] = tot;
  __syncthreads();
  for (int st = 128; st > 0; st >>= 1) {
    if (k < st) red[k] += red[k + st];
    __syncthreads();
  }
  if (k == 0) bsums[blk] = red[0];
}

__global__ __launch_bounds__(256) void k_sumreduce(const float* __restrict__ bsums,
                                                   float* __restrict__ sums) {
  int t = threadIdx.x, b = t >> 6, l = t & 63;
  float v = (l < 32) ? bsums[b * 32 + l] : 0.0f;
  for (int off = 32; off; off >>= 1) v += __shfl_down(v, off, 64);
  if (l == 0) sums[b] = v;
}

// ---------------- normalize + write inter output + transposed copy ----------------
__global__ __launch_bounds__(256) void k_norm_t(const float* __restrict__ S,
                                                const float* __restrict__ sums,
                                                float* __restrict__ inter_out,
                                                float* __restrict__ STn) {
  int blk = blockIdx.x;                 // b(2) ti(2) tk(2)
  int tk = blk & 3, ti = (blk >> 2) & 3, b = blk >> 4;
  int i0 = ti * 64, k0 = tk * 64;
  float inv = 1.0f / sums[b];
  __shared__ float lds[64][65];
  int c = threadIdx.x & 63, rq = threadIdx.x >> 6;
#pragma unroll
  for (int ps = 0; ps < 16; ++ps) {
    int r = ps * 4 + rq;
    float v = S[(size_t)(b * L + i0 + r) * D + k0 + c] * inv;
    inter_out[(size_t)(b * L + i0 + r) * D + k0 + c] = v;
    lds[r][c] = v;
  }
  __syncthreads();
#pragma unroll
  for (int ps = 0; ps < 16; ++ps) {
    int r = ps * 4 + rq;                // local k index
    STn[(size_t)(b * L + k0 + r) * D + i0 + c] = lds[c][r];
  }
}

// ---------------- bilinear tanh pooling ----------------
__global__ __launch_bounds__(256) void k_pool(const float* __restrict__ e1,
                                              const float* __restrict__ e2,
                                              const float* __restrict__ STn,
                                              float* __restrict__ pp) {
  int blk = blockIdx.x;                 // b(2) ich(4) kch(2)
  int kch = blk & 3, ich = (blk >> 2) & 15, b = blk >> 6;
  int d = threadIdx.x, i0 = ich * 16, k0 = kch * 64;
  float ev[16];
#pragma unroll
  for (int ii = 0; ii < 16; ++ii) ev[ii] = e1[(size_t)(b * L + i0 + ii) * D + d];
  float acc = 0.f;
  for (int k = k0; k < k0 + 64; ++k) {
    float e2v = e2[(size_t)(b * L + k) * D + d];
    const float* sp = STn + (size_t)(b * L + k) * D + i0;
#pragma unroll
    for (int ii = 0; ii < 16; ++ii)
      acc = fmaf(tanh_fast(ev[ii] * e2v), sp[ii], acc);
  }
  pp[(((size_t)b * 16 + ich) * 4 + kch) * D + d] = acc;
}

__global__ __launch_bounds__(256) void k_poolcomb(const float* __restrict__ pp,
                                                  float* __restrict__ pooled) {
  int b = blockIdx.x, d = threadIdx.x;
  float s = 0.f;
  for (int m = 0; m < 64; ++m) s += pp[((size_t)b * 64 + m) * D + d];
  pooled[b * D + d] = s;
}

// ---------------- head: conv(stride2) + lrelu + maxpool4 ----------------
__global__ __launch_bounds__(256) void k_head1(const float* __restrict__ pooled,
                                               const float* __restrict__ rcw,
                                               const float* __restrict__ rcb,
                                               float* __restrict__ h) {
  int t = threadIdx.x, b = t >> 6, c = t & 63;
  float w0 = rcw[c * 4 + 0], w1 = rcw[c * 4 + 1], w2 = rcw[c * 4 + 2], w3 = rcw[c * 4 + 3];
  float bias = rcb[c];
  const float* pb = pooled + b * D;
  for (int m = 0; m < 32; ++m) {
    float mx = -1e30f;
#pragma unroll
    for (int r = 0; r < 4; ++r) {
      int p = 4 * m + r;
      int base = 2 * p - 1;
      float y = bias;
      if (base >= 0) y = fmaf(w0, pb[base], y);
      y = fmaf(w1, pb[base + 1], y);
      y = fmaf(w2, pb[base + 2], y);
      if (base + 3 < 256) y = fmaf(w3, pb[base + 3], y);
      y = lrelu(y);
      mx = fmaxf(mx, y);
    }
    h[(size_t)(b * 64 + c) * 32 + m] = mx;
  }
}

// ---------------- fc1 (i-split partials) ----------------
__global__ __launch_bounds__(256) void k_fc1(const float* __restrict__ h,
                                             const float* __restrict__ w,
                                             float* __restrict__ f1p) {
  int blk = blockIdx.x;
  int ot = blk % 10, ich = blk / 10;
  int t = threadIdx.x, o = ot * 64 + (t & 63), b = t >> 6;
  if (o >= 600) return;
  float acc = 0.f;
  const float* hb = h + (size_t)b * 2048 + (size_t)ich * 256;
  const float* wb = w + (size_t)ich * 256 * 600 + o;
  for (int i = 0; i < 256; ++i) acc = fmaf(hb[i], wb[(size_t)i * 600], acc);
  f1p[((size_t)ich * 4 + b) * 600 + o] = acc;
}

__global__ __launch_bounds__(256) void k_fc1c(const float* __restrict__ f1p,
                                              const float* __restrict__ bias,
                                              float* __restrict__ h1) {
  int idx = blockIdx.x * 256 + threadIdx.x;
  if (idx >= 2400) return;
  int o = idx % 600, b = idx / 600;
  float s = bias[o];
#pragma unroll
  for (int ich = 0; ich < 8; ++ich) s += f1p[((size_t)ich * 4 + b) * 600 + o];
  h1[(size_t)b * 600 + o] = lrelu(s);
}

__global__ __launch_bounds__(256) void k_fc2(const float* __restrict__ h1,
                                             const float* __restrict__ w,
                                             const float* __restrict__ bias,
                                             float* __restrict__ h2) {
  int idx = blockIdx.x * 256 + threadIdx.x;
  if (idx >= 1200) return;
  int o = idx % 300, b = idx / 300;
  float s = bias[o];
  const float* hb = h1 + (size_t)b * 600;
  for (int i = 0; i < 600; ++i) s = fmaf(hb[i], w[(size_t)i * 300 + o], s);
  h2[(size_t)b * 300 + o] = lrelu(s);
}

__global__ __launch_bounds__(256) void k_fc3(const float* __restrict__ h2,
                                             const float* __restrict__ w,
                                             const float* __restrict__ bias,
                                             float* __restrict__ out) {
  int t = threadIdx.x, b = t >> 6, l = t & 63;
  float s = 0.f;
#pragma unroll
  for (int m = 0; m < 5; ++m) {
    int i = l + m * 64;
    if (i < 300) s = fmaf(h2[(size_t)b * 300 + i], w[i], s);
  }
  for (int off = 32; off; off >>= 1) s += __shfl_down(s, off, 64);
  if (l == 0) out[262144 + b] = s + bias[0];
}

extern "C" void kernel_launch(void* const* d_in, const int* in_sizes, int n_in,
                              void* d_out, int out_size, void* d_ws, size_t ws_size,
                              hipStream_t stream) {
  float* ws = (float*)d_ws;
  const int* p1 = (const int*)d_in[0];
  const int* p2 = (const int*)d_in[1];
  const float* emb  = (const float*)d_in[2];
  const float* w0   = (const float*)d_in[3];
  const float* b0   = (const float*)d_in[4];
  const float* w1   = (const float*)d_in[5];
  const float* b1   = (const float*)d_in[6];
  const float* w2   = (const float*)d_in[7];
  const float* b2   = (const float*)d_in[8];
  const float* ja1w = (const float*)d_in[9];
  const float* ja1b = (const float*)d_in[10];
  const float* ja2w = (const float*)d_in[11];
  const float* ja2b = (const float*)d_in[12];
  const float* rcw  = (const float*)d_in[13];
  const float* rcb  = (const float*)d_in[14];
  const float* fc1w = (const float*)d_in[15];
  const float* fc1b = (const float*)d_in[16];
  const float* fc2w = (const float*)d_in[17];
  const float* fc2b = (const float*)d_in[18];
  const float* fc3w = (const float*)d_in[19];
  const float* fc3b = (const float*)d_in[20];
  float* out = (float*)d_out;

  // zero padded staging buffers (margins must be 0)
  hipMemsetAsync(ws + OFF_TMPA, 0, sizeof(float) * 4 * SZP, stream);

  k_embed<<<2048, 256, 0, stream>>>(p1, p2, emb, ws);

  k_conv<4, 1><<<256, 512, 0, stream>>>(ws + OFF_TMPA, w0, b0, ws + OFF_TMPB, RS, PADC, SZP);
  k_conv<8, 3><<<256, 512, 0, stream>>>(ws + OFF_TMPB, w1, b1, ws + OFF_TMPA, RS, PADC, SZP);
  k_conv<12, 5><<<256, 512, 0, stream>>>(ws + OFF_TMPA, w2, b2, ws + OFF_E1, D, 0, SZ);

  k_ja<<<256, 256, 0, stream>>>(ws + OFF_E1, ja1w, ja1b, ja2w, ja2b, ws + OFF_Q, ws + OFF_KT);
  k_scores<<<128, 256, 0, stream>>>(ws + OFF_Q, ws + OFF_KT, ws + OFF_S, ws + OFF_BS);
  k_sumreduce<<<1, 256, 0, stream>>>(ws + OFF_BS, ws + OFF_SUM);
  k_norm_t<<<64, 256, 0, stream>>>(ws + OFF_S, ws + OFF_SUM, out, ws + OFF_STN);

  k_pool<<<256, 256, 0, stream>>>(ws + OFF_E1, ws + OFF_E2, ws + OFF_STN, ws + OFF_PP);
  k_poolcomb<<<4, 256, 0, stream>>>(ws + OFF_PP, ws + OFF_POOL);

  k_head1<<<1, 256, 0, stream>>>(ws + OFF_POOL, rcw, rcb, ws + OFF_H);
  k_fc1<<<80, 256, 0, stream>>>(ws + OFF_H, fc1w, ws + OFF_F1P);
  k_fc1c<<<10, 256, 0, stream>>>(ws + OFF_F1P, fc1b, ws + OFF_H1);
  k_fc2<<<5, 256, 0, stream>>>(ws + OFF_H1, fc2w, fc2b, ws + OFF_H2);
  k_fc3<<<1, 256, 0, stream>>>(ws + OFF_H2, fc3w, fc3b, out);
}

// Round 3
// 388.414 us; speedup vs baseline: 1.2677x; 1.2677x over previous
//
#include <hip/hip_runtime.h>
#include <hip/hip_bf16.h>

constexpr int B = 4, L = 256, D = 256;
constexpr int RS = 288, PADC = 16;            // padded row stride / col offset
constexpr size_t SZ  = (size_t)B * L * D;     // 262144
constexpr size_t SZP = (size_t)B * L * RS;    // 294912

// workspace offsets (floats)
constexpr size_t OFF_E1   = 0;
constexpr size_t OFF_E2   = OFF_E1 + SZ;
constexpr size_t OFF_Q    = OFF_E2 + SZ;
constexpr size_t OFF_KT   = OFF_Q + SZ;
constexpr size_t OFF_S    = OFF_KT + SZ;
constexpr size_t OFF_STN  = OFF_S + SZ;
constexpr size_t OFF_TMPA = OFF_STN + SZ;           // 2 proteins padded
constexpr size_t OFF_TMPB = OFF_TMPA + 2 * SZP;
constexpr size_t OFF_PART = OFF_TMPB + 2 * SZP;     // 2 is * 2 p * B*256*256
constexpr size_t OFF_BS   = OFF_PART + 4 * SZ;      // 256
constexpr size_t OFF_SUM  = OFF_BS + 256;           // 4
constexpr size_t OFF_PP   = OFF_SUM + 4;            // 65536
constexpr size_t OFF_POOL = OFF_PP + 65536;         // 1024
constexpr size_t OFF_H    = OFF_POOL + 1024;        // 8192
constexpr size_t OFF_F1P  = OFF_H + 8192;           // 19200
constexpr size_t OFF_H1   = OFF_F1P + 19200;        // 2400
constexpr size_t OFF_H2   = OFF_H1 + 2400;          // 1200

__device__ __forceinline__ float tanh_fast(float x) {
  float e = __expf(2.0f * x);
  return 1.0f - __fdividef(2.0f, e + 1.0f);
}
__device__ __forceinline__ float sig_fast(float x) {
  return __fdividef(1.0f, 1.0f + __expf(-x));
}
__device__ __forceinline__ float lrelu(float x) { return x >= 0.0f ? x : 0.1f * x; }

// ---------------- embedding ----------------
__global__ __launch_bounds__(256) void k_embed(const int* __restrict__ t1,
                                               const int* __restrict__ t2,
                                               const float* __restrict__ emb,
                                               float* __restrict__ ws) {
  int blk = blockIdx.x;                 // p(1) b(2) l(8)
  int l = blk & 255, b = (blk >> 8) & 3, p = blk >> 10;
  const int* tok = p ? t2 : t1;
  int tv = tok[b * L + l];
  float* dst = ws + OFF_TMPA + (size_t)p * SZP + (size_t)(b * L + l) * RS + PADC;
  dst[threadIdx.x] = emb[(size_t)tv * D + threadIdx.x];
}

// ---------------- conv: register-blocked 8oc x 4j, barrier-free hot loop ----------------
// Block 256 thr = 4 waves; wave w handles i-quarter [is*128 + w*32, +32).
// Each thread: lane -> j = lane*4 (4 adjacent cols), fixed 8 output channels.
// Weights are wave-uniform -> scalar loads. One LDS reduce at the end.
// Two i-split blocks write fp32 partials; k_comb2 sums + bias + relu.
template <int K, int PL>
__global__ __launch_bounds__(256, 2) void k_conv2(const float* __restrict__ in,   // padded
                                                  const float* __restrict__ w,    // [O][I][K]
                                                  float* __restrict__ part) {
  int blk = blockIdx.x;                 // p(1) b(2) ocg(5) is(1)
  int is = blk & 1, ocg = (blk >> 1) & 31, b = (blk >> 6) & 3, p = blk >> 8;
  int oc0 = ocg * 8;
  int lane = threadIdx.x & 63, wv = threadIdx.x >> 6;
  int j = lane * 4;
  int i0 = is * 128 + wv * 32;

  const float* src = in + (size_t)p * SZP + (size_t)b * 256 * RS;

  float acc[8][4];
#pragma unroll
  for (int m = 0; m < 8; ++m)
#pragma unroll
    for (int jj = 0; jj < 4; ++jj) acc[m][jj] = 0.0f;

#pragma unroll 2
  for (int i = i0; i < i0 + 32; ++i) {
    const float* row = src + (size_t)i * RS + (PADC - PL) + j;
    float win[K + 3];
#pragma unroll
    for (int q = 0; q < K + 3; ++q) win[q] = row[q];
    const float* wb = w + ((size_t)oc0 * 256 + (size_t)i) * K;
#pragma unroll
    for (int m = 0; m < 8; ++m) {
#pragma unroll
      for (int q = 0; q < K; ++q) {
        float wvv = wb[(size_t)m * 256 * K + q];
#pragma unroll
        for (int jj = 0; jj < 4; ++jj)
          acc[m][jj] = fmaf(wvv, win[q + jj], acc[m][jj]);
      }
    }
  }

  // cross-wave reduce (waves 1-3 -> LDS, wave 0 sums and stores)
  __shared__ float red[3][32][64];      // 24 KB, [wave-1][m*4+jj][lane]
  if (wv > 0) {
#pragma unroll
    for (int m = 0; m < 8; ++m)
#pragma unroll
      for (int jj = 0; jj < 4; ++jj) red[wv - 1][m * 4 + jj][lane] = acc[m][jj];
  }
  __syncthreads();
  if (wv == 0) {
    float* pp = part + (((size_t)(is * 2 + p) * B + b) * 256 + oc0) * 256 + j;
#pragma unroll
    for (int m = 0; m < 8; ++m) {
      float4 r;
      float* rr = (float*)&r;
#pragma unroll
      for (int jj = 0; jj < 4; ++jj)
        rr[jj] = acc[m][jj] + red[0][m * 4 + jj][lane] + red[1][m * 4 + jj][lane] +
                 red[2][m * 4 + jj][lane];
      *(float4*)(pp + (size_t)m * 256) = r;
    }
  }
}

// ---------------- combine 2 i-split partials + bias + relu -> (padded) out ----------------
__global__ __launch_bounds__(256) void k_comb2(const float* __restrict__ part,
                                               const float* __restrict__ bias,
                                               float* __restrict__ outp,
                                               int out_rs, int out_pad, size_t out_pstride) {
  int t = blockIdx.x * 256 + threadIdx.x;      // 131072 threads, float4 each
  int j4 = t & 63, oc = (t >> 6) & 255, b = (t >> 14) & 3, p = t >> 16;
  size_t base = (((size_t)p * B + b) * 256 + oc) * 256 + j4 * 4;
  const float4 a = *(const float4*)(part + base);                      // is=0
  const float4 c = *(const float4*)(part + (size_t)2 * SZ + base);     // is=1
  float bv = bias[oc];
  float4 r;
  r.x = fmaxf(a.x + c.x + bv, 0.f);
  r.y = fmaxf(a.y + c.y + bv, 0.f);
  r.z = fmaxf(a.z + c.z + bv, 0.f);
  r.w = fmaxf(a.w + c.w + bv, 0.f);
  float* ob = outp + (size_t)p * out_pstride + ((size_t)b * 256 + oc) * out_rs + out_pad + j4 * 4;
  *(float4*)ob = r;
}

// ---------------- joint-attention projections: q and k^T ----------------
__global__ __launch_bounds__(256) void k_ja(const float* __restrict__ e_base,
                                            const float* __restrict__ w1,
                                            const float* __restrict__ b1,
                                            const float* __restrict__ w2,
                                            const float* __restrict__ b2,
                                            float* __restrict__ q,
                                            float* __restrict__ kT) {
  int blk = blockIdx.x;                 // p(1) b(2) it(5)
  int it = blk & 31, b = (blk >> 5) & 3, p = blk >> 7;
  int n = threadIdx.x, i0 = it * 8;
  const float* e = e_base + (size_t)p * SZ + ((size_t)b * 256 + i0) * 256;
  const float* W = p ? w2 : w1;
  float bv = (p ? b2 : b1)[n];
  float a[8];
#pragma unroll
  for (int m = 0; m < 8; ++m) a[m] = bv;
#pragma unroll 4
  for (int d = 0; d < 256; ++d) {
    float wv = W[(size_t)d * 256 + n];
#pragma unroll
    for (int m = 0; m < 8; ++m) a[m] = fmaf(e[m * 256 + d], wv, a[m]);
  }
  if (p == 0) {
    float* qp = q + ((size_t)b * 256 + i0) * 256 + n;
#pragma unroll
    for (int m = 0; m < 8; ++m) qp[(size_t)m * 256] = a[m];
  } else {
    float* kp = kT + ((size_t)b * 256 + n) * 256 + i0;
    float4 v0 = make_float4(a[0], a[1], a[2], a[3]);
    float4 v1 = make_float4(a[4], a[5], a[6], a[7]);
    *(float4*)kp = v0;
    *(float4*)(kp + 4) = v1;
  }
}

// ---------------- scores: sigmoid(q k^T) + block partial sums ----------------
__global__ __launch_bounds__(256) void k_scores(const float* __restrict__ q,
                                                const float* __restrict__ kT,
                                                float* __restrict__ S,
                                                float* __restrict__ bsums) {
  int blk = blockIdx.x;                 // b(2) it(5) -> 128 blocks
  int it = blk & 31, b = blk >> 5;
  int k = threadIdx.x, i0 = it * 8;
  const float* qb = q + ((size_t)b * 256 + i0) * 256;
  const float* kTb = kT + (size_t)b * 65536 + k;
  float a[8];
#pragma unroll
  for (int m = 0; m < 8; ++m) a[m] = 0.0f;
#pragma unroll 4
  for (int n = 0; n < 256; ++n) {
    float kv = kTb[(size_t)n * 256];
#pragma unroll
    for (int m = 0; m < 8; ++m) a[m] = fmaf(qb[m * 256 + n], kv, a[m]);
  }
  float tot = 0.0f;
#pragma unroll
  for (int m = 0; m < 8; ++m) {
    float s = sig_fast(a[m]);
    S[((size_t)b * 256 + i0 + m) * 256 + k] = s;
    tot += s;
  }
  __shared__ float red[256];
  red[k] = tot;
  __syncthreads();
  for (int st = 128; st > 0; st >>= 1) {
    if (k < st) red[k] += red[k + st];
    __syncthreads();
  }
  if (k == 0) bsums[blk] = red[0];
}

__global__ __launch_bounds__(256) void k_sumreduce(const float* __restrict__ bsums,
                                                   float* __restrict__ sums) {
  int t = threadIdx.x, b = t >> 6, l = t & 63;
  float v = (l < 32) ? bsums[b * 32 + l] : 0.0f;
  for (int off = 32; off; off >>= 1) v += __shfl_down(v, off, 64);
  if (l == 0) sums[b] = v;
}

// ---------------- normalize + write inter output + transposed copy ----------------
__global__ __launch_bounds__(256) void k_norm_t(const float* __restrict__ S,
                                                const float* __restrict__ sums,
                                                float* __restrict__ inter_out,
                                                float* __restrict__ STn) {
  int blk = blockIdx.x;                 // b(2) ti(2) tk(2)
  int tk = blk & 3, ti = (blk >> 2) & 3, b = blk >> 4;
  int i0 = ti * 64, k0 = tk * 64;
  float inv = 1.0f / sums[b];
  __shared__ float lds[64][65];
  int c = threadIdx.x & 63, rq = threadIdx.x >> 6;
#pragma unroll
  for (int ps = 0; ps < 16; ++ps) {
    int r = ps * 4 + rq;
    float v = S[(size_t)(b * L + i0 + r) * D + k0 + c] * inv;
    inter_out[(size_t)(b * L + i0 + r) * D + k0 + c] = v;
    lds[r][c] = v;
  }
  __syncthreads();
#pragma unroll
  for (int ps = 0; ps < 16; ++ps) {
    int r = ps * 4 + rq;                // local k index
    STn[(size_t)(b * L + k0 + r) * D + i0 + c] = lds[c][r];
  }
}

// ---------------- bilinear tanh pooling ----------------
__global__ __launch_bounds__(256) void k_pool(const float* __restrict__ e1,
                                              const float* __restrict__ e2,
                                              const float* __restrict__ STn,
                                              float* __restrict__ pp) {
  int blk = blockIdx.x;                 // b(2) ich(4) kch(2)
  int kch = blk & 3, ich = (blk >> 2) & 15, b = blk >> 6;
  int d = threadIdx.x, i0 = ich * 16, k0 = kch * 64;
  float ev[16];
#pragma unroll
  for (int ii = 0; ii < 16; ++ii) ev[ii] = e1[(size_t)(b * L + i0 + ii) * D + d];
  float acc = 0.f;
  for (int k = k0; k < k0 + 64; ++k) {
    float e2v = e2[(size_t)(b * L + k) * D + d];
    const float* sp = STn + (size_t)(b * L + k) * D + i0;
#pragma unroll
    for (int ii = 0; ii < 16; ++ii)
      acc = fmaf(tanh_fast(ev[ii] * e2v), sp[ii], acc);
  }
  pp[(((size_t)b * 16 + ich) * 4 + kch) * D + d] = acc;
}

__global__ __launch_bounds__(256) void k_poolcomb(const float* __restrict__ pp,
                                                  float* __restrict__ pooled) {
  int b = blockIdx.x, d = threadIdx.x;
  float s = 0.f;
  for (int m = 0; m < 64; ++m) s += pp[((size_t)b * 64 + m) * D + d];
  pooled[b * D + d] = s;
}

// ---------------- head: conv(stride2) + lrelu + maxpool4 ----------------
__global__ __launch_bounds__(256) void k_head1(const float* __restrict__ pooled,
                                               const float* __restrict__ rcw,
                                               const float* __restrict__ rcb,
                                               float* __restrict__ h) {
  int t = threadIdx.x, b = t >> 6, c = t & 63;
  float w0 = rcw[c * 4 + 0], w1 = rcw[c * 4 + 1], w2 = rcw[c * 4 + 2], w3 = rcw[c * 4 + 3];
  float bias = rcb[c];
  const float* pb = pooled + b * D;
  for (int m = 0; m < 32; ++m) {
    float mx = -1e30f;
#pragma unroll
    for (int r = 0; r < 4; ++r) {
      int p = 4 * m + r;
      int base = 2 * p - 1;
      float y = bias;
      if (base >= 0) y = fmaf(w0, pb[base], y);
      y = fmaf(w1, pb[base + 1], y);
      y = fmaf(w2, pb[base + 2], y);
      if (base + 3 < 256) y = fmaf(w3, pb[base + 3], y);
      y = lrelu(y);
      mx = fmaxf(mx, y);
    }
    h[(size_t)(b * 64 + c) * 32 + m] = mx;
  }
}

// ---------------- fc1 (i-split partials) ----------------
__global__ __launch_bounds__(256) void k_fc1(const float* __restrict__ h,
                                             const float* __restrict__ w,
                                             float* __restrict__ f1p) {
  int blk = blockIdx.x;
  int ot = blk % 10, ich = blk / 10;
  int t = threadIdx.x, o = ot * 64 + (t & 63), b = t >> 6;
  if (o >= 600) return;
  float acc = 0.f;
  const float* hb = h + (size_t)b * 2048 + (size_t)ich * 256;
  const float* wb = w + (size_t)ich * 256 * 600 + o;
  for (int i = 0; i < 256; ++i) acc = fmaf(hb[i], wb[(size_t)i * 600], acc);
  f1p[((size_t)ich * 4 + b) * 600 + o] = acc;
}

__global__ __launch_bounds__(256) void k_fc1c(const float* __restrict__ f1p,
                                              const float* __restrict__ bias,
                                              float* __restrict__ h1) {
  int idx = blockIdx.x * 256 + threadIdx.x;
  if (idx >= 2400) return;
  int o = idx % 600, b = idx / 600;
  float s = bias[o];
#pragma unroll
  for (int ich = 0; ich < 8; ++ich) s += f1p[((size_t)ich * 4 + b) * 600 + o];
  h1[(size_t)b * 600 + o] = lrelu(s);
}

__global__ __launch_bounds__(256) void k_fc2(const float* __restrict__ h1,
                                             const float* __restrict__ w,
                                             const float* __restrict__ bias,
                                             float* __restrict__ h2) {
  int idx = blockIdx.x * 256 + threadIdx.x;
  if (idx >= 1200) return;
  int o = idx % 300, b = idx / 300;
  float s = bias[o];
  const float* hb = h1 + (size_t)b * 600;
  for (int i = 0; i < 600; ++i) s = fmaf(hb[i], w[(size_t)i * 300 + o], s);
  h2[(size_t)b * 300 + o] = lrelu(s);
}

__global__ __launch_bounds__(256) void k_fc3(const float* __restrict__ h2,
                                             const float* __restrict__ w,
                                             const float* __restrict__ bias,
                                             float* __restrict__ out) {
  int t = threadIdx.x, b = t >> 6, l = t & 63;
  float s = 0.f;
#pragma unroll
  for (int m = 0; m < 5; ++m) {
    int i = l + m * 64;
    if (i < 300) s = fmaf(h2[(size_t)b * 300 + i], w[i], s);
  }
  for (int off = 32; off; off >>= 1) s += __shfl_down(s, off, 64);
  if (l == 0) out[262144 + b] = s + bias[0];
}

extern "C" void kernel_launch(void* const* d_in, const int* in_sizes, int n_in,
                              void* d_out, int out_size, void* d_ws, size_t ws_size,
                              hipStream_t stream) {
  float* ws = (float*)d_ws;
  const int* p1 = (const int*)d_in[0];
  const int* p2 = (const int*)d_in[1];
  const float* emb  = (const float*)d_in[2];
  const float* w0   = (const float*)d_in[3];
  const float* b0   = (const float*)d_in[4];
  const float* w1   = (const float*)d_in[5];
  const float* b1   = (const float*)d_in[6];
  const float* w2   = (const float*)d_in[7];
  const float* b2   = (const float*)d_in[8];
  const float* ja1w = (const float*)d_in[9];
  const float* ja1b = (const float*)d_in[10];
  const float* ja2w = (const float*)d_in[11];
  const float* ja2b = (const float*)d_in[12];
  const float* rcw  = (const float*)d_in[13];
  const float* rcb  = (const float*)d_in[14];
  const float* fc1w = (const float*)d_in[15];
  const float* fc1b = (const float*)d_in[16];
  const float* fc2w = (const float*)d_in[17];
  const float* fc2b = (const float*)d_in[18];
  const float* fc3w = (const float*)d_in[19];
  const float* fc3b = (const float*)d_in[20];
  float* out = (float*)d_out;

  // zero padded staging buffers (margins must be 0)
  hipMemsetAsync(ws + OFF_TMPA, 0, sizeof(float) * 4 * SZP, stream);

  k_embed<<<2048, 256, 0, stream>>>(p1, p2, emb, ws);

  k_conv2<4, 1><<<512, 256, 0, stream>>>(ws + OFF_TMPA, w0, ws + OFF_PART);
  k_comb2<<<512, 256, 0, stream>>>(ws + OFF_PART, b0, ws + OFF_TMPB, RS, PADC, SZP);
  k_conv2<8, 3><<<512, 256, 0, stream>>>(ws + OFF_TMPB, w1, ws + OFF_PART);
  k_comb2<<<512, 256, 0, stream>>>(ws + OFF_PART, b1, ws + OFF_TMPA, RS, PADC, SZP);
  k_conv2<12, 5><<<512, 256, 0, stream>>>(ws + OFF_TMPA, w2, ws + OFF_PART);
  k_comb2<<<512, 256, 0, stream>>>(ws + OFF_PART, b2, ws + OFF_E1, D, 0, SZ);

  k_ja<<<256, 256, 0, stream>>>(ws + OFF_E1, ja1w, ja1b, ja2w, ja2b, ws + OFF_Q, ws + OFF_KT);
  k_scores<<<128, 256, 0, stream>>>(ws + OFF_Q, ws + OFF_KT, ws + OFF_S, ws + OFF_BS);
  k_sumreduce<<<1, 256, 0, stream>>>(ws + OFF_BS, ws + OFF_SUM);
  k_norm_t<<<64, 256, 0, stream>>>(ws + OFF_S, ws + OFF_SUM, out, ws + OFF_STN);

  k_pool<<<256, 256, 0, stream>>>(ws + OFF_E1, ws + OFF_E2, ws + OFF_STN, ws + OFF_PP);
  k_poolcomb<<<4, 256, 0, stream>>>(ws + OFF_PP, ws + OFF_POOL);

  k_head1<<<1, 256, 0, stream>>>(ws + OFF_POOL, rcw, rcb, ws + OFF_H);
  k_fc1<<<80, 256, 0, stream>>>(ws + OFF_H, fc1w, ws + OFF_F1P);
  k_fc1c<<<10, 256, 0, stream>>>(ws + OFF_F1P, fc1b, ws + OFF_H1);
  k_fc2<<<5, 256, 0, stream>>>(ws + OFF_H1, fc2w, fc2b, ws + OFF_H2);
  k_fc3<<<1, 256, 0, stream>>>(ws + OFF_H2, fc3w, fc3b, out);
}

// Round 4
// 269.864 us; speedup vs baseline: 1.8246x; 1.4393x over previous
//
#include <hip/hip_runtime.h>
#include <hip/hip_bf16.h>

typedef unsigned short u16;
typedef unsigned int u32;
typedef short s8v __attribute__((ext_vector_type(8)));      // 8 bf16 bit-patterns
typedef float f32x16 __attribute__((ext_vector_type(16)));

constexpr int B = 4, L = 256, D = 256;
constexpr size_t SZ = (size_t)B * L * D;          // 262144

// Xt (transposed, padded) geometry: rows = j(-8..263) -> 272, cols = i 0..255
constexpr int XROWS = 272;
constexpr size_t XT_PLANE = (size_t)8 * XROWS * 256;   // ushorts per plane = 557056

// workspace offsets (floats)
constexpr size_t OFF_E1  = 0;
constexpr size_t OFF_E2  = SZ;
constexpr size_t OFF_Q   = 2 * SZ;
constexpr size_t OFF_KT  = 3 * SZ;
constexpr size_t OFF_S   = 4 * SZ;
constexpr size_t OFF_STN = 5 * SZ;
constexpr size_t OFF_E0  = OFF_S;                 // alias: embed staging (2*SZ), dead before S/STN written
constexpr size_t OFF_XA  = 6 * SZ;                        // 557056 floats (hi+lo planes)
constexpr size_t OFF_XB  = OFF_XA + 557056;
constexpr size_t OFF_WB  = OFF_XB + 557056;               // 1572864 floats (3 layers)
constexpr size_t OFF_BS   = OFF_WB + 1572864;
constexpr size_t OFF_SUM  = OFF_BS + 256;
constexpr size_t OFF_PP   = OFF_SUM + 4;
constexpr size_t OFF_POOL = OFF_PP + 65536;
constexpr size_t OFF_H    = OFF_POOL + 1024;
constexpr size_t OFF_F1P  = OFF_H + 8192;
constexpr size_t OFF_H1   = OFF_F1P + 19200;
constexpr size_t OFF_H2   = OFF_H1 + 2400;

// Wb layer offsets in ushorts
constexpr size_t WB_L1 = 0;
constexpr size_t WB_L2 = (size_t)4 * 2 * 65536;     // 524288
constexpr size_t WB_L3 = WB_L2 + (size_t)8 * 2 * 65536;  // 1572864

__device__ __forceinline__ float tanh_fast(float x) {
  float e = __expf(2.0f * x);
  return 1.0f - __fdividef(2.0f, e + 1.0f);
}
__device__ __forceinline__ float sig_fast(float x) {
  return __fdividef(1.0f, 1.0f + __expf(-x));
}
__device__ __forceinline__ float lrelu(float x) { return x >= 0.0f ? x : 0.1f * x; }

__device__ __forceinline__ void split_bf16(float v, u16& h, u16& l) {
  __bf16 hb = (__bf16)v;
  float hf = (float)hb;
  __bf16 lb = (__bf16)(v - hf);
  h = __builtin_bit_cast(u16, hb);
  l = __builtin_bit_cast(u16, lb);
}

__device__ __forceinline__ s8v lds16_8al(const u16* p) {   // 16B from LDS, 8B-aligned
  union { uint2 u[2]; s8v v; } r;
  r.u[0] = *(const uint2*)p;
  r.u[1] = *(const uint2*)(p + 4);
  return r.v;
}

// ---------------- embedding -> e0[pb][l][d] fp32 ----------------
__global__ __launch_bounds__(256) void k_embed(const int* __restrict__ t1,
                                               const int* __restrict__ t2,
                                               const float* __restrict__ emb,
                                               float* __restrict__ e0) {
  int blk = blockIdx.x;                 // p(1) b(2) l(8)
  int l = blk & 255, pb = blk >> 8;     // pb = p*4+b
  const int* tok = (pb >> 2) ? t2 : t1;
  int tv = tok[(pb & 3) * L + l];
  e0[(size_t)pb * 65536 + (size_t)l * 256 + threadIdx.x] = emb[(size_t)tv * D + threadIdx.x];
}

// ---------------- weight prep: fragment-major bf16 hi/lo ----------------
// Wb[(q*2+plane)][igrp 0..31][oc 0..255][8]  (ushorts)
template <int K>
__global__ __launch_bounds__(256) void k_prepW(const float* __restrict__ w,
                                               u16* __restrict__ wl) {
  int q = blockIdx.x >> 5, ig = blockIdx.x & 31, oc = threadIdx.x;
  union { u16 us[8]; uint4 v; } H, Lo;
#pragma unroll
  for (int e = 0; e < 8; ++e) {
    float v = w[((size_t)oc * 256 + ig * 8 + e) * K + q];
    split_bf16(v, H.us[e], Lo.us[e]);
  }
  size_t dst = (size_t)(q * 2) * 65536 + (size_t)ig * 2048 + (size_t)oc * 8;
  *(uint4*)(wl + dst) = H.v;
  *(uint4*)(wl + dst + 65536) = Lo.v;
}

// ---------------- e0 fp32 [pb][l][d] -> Xt hi/lo [pb][8+d][l] ----------------
__global__ __launch_bounds__(256) void k_t32(const float* __restrict__ e0,
                                             u16* __restrict__ yhi,
                                             u16* __restrict__ ylo) {
  int blk = blockIdx.x;                 // pb(3) lt(3) dt(3)
  int dt = blk & 7, lt = (blk >> 3) & 7, pb = blk >> 6;
  int l0 = lt * 32, d0 = dt * 32;
  __shared__ float st[32][33];
  int c = threadIdx.x & 31, rq = threadIdx.x >> 5;
#pragma unroll
  for (int rr = 0; rr < 4; ++rr) {
    int r = rq * 4 + rr;
    st[r][c] = e0[(size_t)pb * 65536 + (size_t)(l0 + r) * 256 + d0 + c];
  }
  __syncthreads();
  u16 hb[4], lb[4];
#pragma unroll
  for (int cc = 0; cc < 4; ++cc) split_bf16(st[rq * 4 + cc][c], hb[cc], lb[cc]);
  size_t ro = (size_t)pb * ((size_t)XROWS * 256) + (size_t)(8 + d0 + c) * 256 + l0 + rq * 4;
  *(ushort4*)(yhi + ro) = make_ushort4(hb[0], hb[1], hb[2], hb[3]);
  *(ushort4*)(ylo + ro) = make_ushort4(lb[0], lb[1], lb[2], lb[3]);
}

// ---------------- conv via MFMA ----------------
// block: 256 thr = 4 waves. tile: (pb, oc0=oct*32, j0=jt*32). wave w: i-slice w*64..+63.
// OUTMODE 0: write next Xt hi/lo (transposed, padded). OUTMODE 1: write e fp32 [pb][oc][j].
template <int K, int P, int OUTMODE>
__global__ __launch_bounds__(256, 2) void k_cmf(const u16* __restrict__ xhi,
                                                const u16* __restrict__ xlo,
                                                const u16* __restrict__ wb,
                                                const float* __restrict__ bias,
                                                u16* __restrict__ yhi,
                                                u16* __restrict__ ylo,
                                                float* __restrict__ eout) {
  __shared__ u16 xs[2 * 12480];         // 2 planes x 48 rows x 260 ushorts (520B stride)

  int blk = blockIdx.x;                 // pb(3) oct(3) jt(3)
  int jt = blk & 7, oct = (blk >> 3) & 7, pb = blk >> 6;
  int oc0 = oct * 32, j0 = jt * 32;
  int tid = threadIdx.x;
  int lane = tid & 63, wv = tid >> 6;
  int l31 = lane & 31, lhi = lane >> 5;

  // stage X rows j0..j0+47 (global row idx = j+8), full i, both planes
  {
    const u32* sh = (const u32*)(xhi + (size_t)pb * (XROWS * 256) + (size_t)j0 * 256);
    const u32* sl = (const u32*)(xlo + (size_t)pb * (XROWS * 256) + (size_t)j0 * 256);
    u32* xd = (u32*)xs;
    for (int idx = tid; idx < 3072; idx += 256) {       // 48 rows x 64 x 8B
      int r = idx >> 6, c2 = (idx & 63) * 2;
      *(uint2*)(xd + r * 130 + c2) = *(const uint2*)(sh + (size_t)r * 128 + c2);
      *(uint2*)(xd + 6240 + r * 130 + c2) = *(const uint2*)(sl + (size_t)r * 128 + c2);
    }
  }
  __syncthreads();

  f32x16 acc = {};
  size_t abase = (size_t)(oc0 + l31) * 8 + (size_t)(wv * 8 + lhi) * 2048;
  int ib0 = wv * 64 + 8 * lhi;

  for (int q = 0; q < K; ++q) {
    int jr = l31 + q + (8 - P);
    const u16* bh0 = xs + jr * 260 + ib0;
    const u16* bl0 = bh0 + 12480;
    size_t aq = (size_t)q * 131072 + abase;
#pragma unroll
    for (int ic = 0; ic < 4; ++ic) {
      s8v ah = *(const s8v*)(wb + aq + ic * 4096);
      s8v al = *(const s8v*)(wb + aq + 65536 + ic * 4096);
      s8v bh = lds16_8al(bh0 + ic * 16);
      s8v bl = lds16_8al(bl0 + ic * 16);
      acc = __builtin_amdgcn_mfma_f32_32x32x16_bf16(ah, bh, acc, 0, 0, 0);
      acc = __builtin_amdgcn_mfma_f32_32x32x16_bf16(ah, bl, acc, 0, 0, 0);
      acc = __builtin_amdgcn_mfma_f32_32x32x16_bf16(al, bh, acc, 0, 0, 0);
    }
  }

  // cross-wave reduce + epilogue
  __syncthreads();
  float* cd = (float*)xs;
  int j = l31;
  if (wv > 0) {
#pragma unroll
    for (int r = 0; r < 16; ++r) {
      int ocr = (r & 3) + 8 * (r >> 2) + 4 * lhi;
      cd[(wv - 1) * 1024 + ocr * 32 + j] = acc[r];
    }
  }
  __syncthreads();
  if (wv == 0) {
#pragma unroll
    for (int r = 0; r < 16; ++r) {
      int ocr = (r & 3) + 8 * (r >> 2) + 4 * lhi;
      int idx = ocr * 32 + j;
      float s = acc[r] + cd[idx] + cd[1024 + idx] + cd[2048 + idx] + bias[oc0 + ocr];
      cd[3072 + ocr * 33 + j] = fmaxf(s, 0.0f);
    }
  }
  __syncthreads();

  int jj = tid & 31, oq = tid >> 5;
  if constexpr (OUTMODE == 0) {
    u16 hb[4], lb[4];
#pragma unroll
    for (int c2 = 0; c2 < 4; ++c2)
      split_bf16(cd[3072 + (oq * 4 + c2) * 33 + jj], hb[c2], lb[c2]);
    size_t ro = (size_t)pb * (XROWS * 256) + (size_t)(8 + j0 + jj) * 256 + oc0 + oq * 4;
    *(ushort4*)(yhi + ro) = make_ushort4(hb[0], hb[1], hb[2], hb[3]);
    *(ushort4*)(ylo + ro) = make_ushort4(lb[0], lb[1], lb[2], lb[3]);
  } else {
#pragma unroll
    for (int c2 = 0; c2 < 4; ++c2)
      eout[(size_t)pb * 65536 + (size_t)(oc0 + oq * 4 + c2) * 256 + j0 + jj] =
          cd[3072 + (oq * 4 + c2) * 33 + jj];
  }
}

// ---------------- joint-attention projections: q and k^T ----------------
__global__ __launch_bounds__(256) void k_ja(const float* __restrict__ e_base,
                                            const float* __restrict__ w1,
                                            const float* __restrict__ b1,
                                            const float* __restrict__ w2,
                                            const float* __restrict__ b2,
                                            float* __restrict__ q,
                                            float* __restrict__ kT) {
  int blk = blockIdx.x;                 // p(1) b(2) it(5)
  int it = blk & 31, b = (blk >> 5) & 3, p = blk >> 7;
  int n = threadIdx.x, i0 = it * 8;
  const float* e = e_base + (size_t)p * SZ + ((size_t)b * 256 + i0) * 256;
  const float* W = p ? w2 : w1;
  float bv = (p ? b2 : b1)[n];
  float a[8];
#pragma unroll
  for (int m = 0; m < 8; ++m) a[m] = bv;
#pragma unroll 4
  for (int d = 0; d < 256; ++d) {
    float wv = W[(size_t)d * 256 + n];
#pragma unroll
    for (int m = 0; m < 8; ++m) a[m] = fmaf(e[m * 256 + d], wv, a[m]);
  }
  if (p == 0) {
    float* qp = q + ((size_t)b * 256 + i0) * 256 + n;
#pragma unroll
    for (int m = 0; m < 8; ++m) qp[(size_t)m * 256] = a[m];
  } else {
    float* kp = kT + ((size_t)b * 256 + n) * 256 + i0;
    *(float4*)kp = make_float4(a[0], a[1], a[2], a[3]);
    *(float4*)(kp + 4) = make_float4(a[4], a[5], a[6], a[7]);
  }
}

// ---------------- scores: sigmoid(q k^T) + block partial sums ----------------
__global__ __launch_bounds__(256) void k_scores(const float* __restrict__ q,
                                                const float* __restrict__ kT,
                                                float* __restrict__ S,
                                                float* __restrict__ bsums) {
  int blk = blockIdx.x;                 // b(2) it(5)
  int it = blk & 31, b = blk >> 5;
  int k = threadIdx.x, i0 = it * 8;
  const float* qb = q + ((size_t)b * 256 + i0) * 256;
  const float* kTb = kT + (size_t)b * 65536 + k;
  float a[8];
#pragma unroll
  for (int m = 0; m < 8; ++m) a[m] = 0.0f;
#pragma unroll 4
  for (int n = 0; n < 256; ++n) {
    float kv = kTb[(size_t)n * 256];
#pragma unroll
    for (int m = 0; m < 8; ++m) a[m] = fmaf(qb[m * 256 + n], kv, a[m]);
  }
  float tot = 0.0f;
#pragma unroll
  for (int m = 0; m < 8; ++m) {
    float s = sig_fast(a[m]);
    S[((size_t)b * 256 + i0 + m) * 256 + k] = s;
    tot += s;
  }
  __shared__ float red[256];
  red[k] = tot;
  __syncthreads();
  for (int st = 128; st > 0; st >>= 1) {
    if (k < st) red[k] += red[k + st];
    __syncthreads();
  }
  if (k == 0) bsums[blk] = red[0];
}

__global__ __launch_bounds__(256) void k_sumreduce(const float* __restrict__ bsums,
                                                   float* __restrict__ sums) {
  int t = threadIdx.x, b = t >> 6, l = t & 63;
  float v = (l < 32) ? bsums[b * 32 + l] : 0.0f;
  for (int off = 32; off; off >>= 1) v += __shfl_down(v, off, 64);
  if (l == 0) sums[b] = v;
}

// ---------------- normalize + write inter output + transposed copy ----------------
__global__ __launch_bounds__(256) void k_norm_t(const float* __restrict__ S,
                                                const float* __restrict__ sums,
                                                float* __restrict__ inter_out,
                                                float* __restrict__ STn) {
  int blk = blockIdx.x;                 // b(2) ti(2) tk(2)
  int tk = blk & 3, ti = (blk >> 2) & 3, b = blk >> 4;
  int i0 = ti * 64, k0 = tk * 64;
  float inv = 1.0f / sums[b];
  __shared__ float lds[64][65];
  int c = threadIdx.x & 63, rq = threadIdx.x >> 6;
#pragma unroll
  for (int ps = 0; ps < 16; ++ps) {
    int r = ps * 4 + rq;
    float v = S[(size_t)(b * L + i0 + r) * D + k0 + c] * inv;
    inter_out[(size_t)(b * L + i0 + r) * D + k0 + c] = v;
    lds[r][c] = v;
  }
  __syncthreads();
#pragma unroll
  for (int ps = 0; ps < 16; ++ps) {
    int r = ps * 4 + rq;
    STn[(size_t)(b * L + k0 + r) * D + i0 + c] = lds[c][r];
  }
}

// ---------------- bilinear tanh pooling ----------------
__global__ __launch_bounds__(256) void k_pool(const float* __restrict__ e1,
                                              const float* __restrict__ e2,
                                              const float* __restrict__ STn,
                                              float* __restrict__ pp) {
  int blk = blockIdx.x;                 // b(2) ich(4) kch(2)
  int kch = blk & 3, ich = (blk >> 2) & 15, b = blk >> 6;
  int d = threadIdx.x, i0 = ich * 16, k0 = kch * 64;
  float ev[16];
#pragma unroll
  for (int ii = 0; ii < 16; ++ii) ev[ii] = e1[(size_t)(b * L + i0 + ii) * D + d];
  float acc = 0.f;
  for (int k = k0; k < k0 + 64; ++k) {
    float e2v = e2[(size_t)(b * L + k) * D + d];
    const float* sp = STn + (size_t)(b * L + k) * D + i0;
#pragma unroll
    for (int ii = 0; ii < 16; ++ii)
      acc = fmaf(tanh_fast(ev[ii] * e2v), sp[ii], acc);
  }
  pp[(((size_t)b * 16 + ich) * 4 + kch) * D + d] = acc;
}

__global__ __launch_bounds__(256) void k_poolcomb(const float* __restrict__ pp,
                                                  float* __restrict__ pooled) {
  int b = blockIdx.x, d = threadIdx.x;
  float s = 0.f;
  for (int m = 0; m < 64; ++m) s += pp[((size_t)b * 64 + m) * D + d];
  pooled[b * D + d] = s;
}

// ---------------- head: conv(stride2) + lrelu + maxpool4 ----------------
__global__ __launch_bounds__(256) void k_head1(const float* __restrict__ pooled,
                                               const float* __restrict__ rcw,
                                               const float* __restrict__ rcb,
                                               float* __restrict__ h) {
  int t = threadIdx.x, b = t >> 6, c = t & 63;
  float w0 = rcw[c * 4 + 0], w1 = rcw[c * 4 + 1], w2 = rcw[c * 4 + 2], w3 = rcw[c * 4 + 3];
  float bias = rcb[c];
  const float* pb = pooled + b * D;
  for (int m = 0; m < 32; ++m) {
    float mx = -1e30f;
#pragma unroll
    for (int r = 0; r < 4; ++r) {
      int p = 4 * m + r;
      int base = 2 * p - 1;
      float y = bias;
      if (base >= 0) y = fmaf(w0, pb[base], y);
      y = fmaf(w1, pb[base + 1], y);
      y = fmaf(w2, pb[base + 2], y);
      if (base + 3 < 256) y = fmaf(w3, pb[base + 3], y);
      y = lrelu(y);
      mx = fmaxf(mx, y);
    }
    h[(size_t)(b * 64 + c) * 32 + m] = mx;
  }
}

// ---------------- fc layers ----------------
__global__ __launch_bounds__(256) void k_fc1(const float* __restrict__ h,
                                             const float* __restrict__ w,
                                             float* __restrict__ f1p) {
  int blk = blockIdx.x;
  int ot = blk % 10, ich = blk / 10;
  int t = threadIdx.x, o = ot * 64 + (t & 63), b = t >> 6;
  if (o >= 600) return;
  float acc = 0.f;
  const float* hb = h + (size_t)b * 2048 + (size_t)ich * 256;
  const float* wb = w + (size_t)ich * 256 * 600 + o;
  for (int i = 0; i < 256; ++i) acc = fmaf(hb[i], wb[(size_t)i * 600], acc);
  f1p[((size_t)ich * 4 + b) * 600 + o] = acc;
}

__global__ __launch_bounds__(256) void k_fc1c(const float* __restrict__ f1p,
                                              const float* __restrict__ bias,
                                              float* __restrict__ h1) {
  int idx = blockIdx.x * 256 + threadIdx.x;
  if (idx >= 2400) return;
  int o = idx % 600, b = idx / 600;
  float s = bias[o];
#pragma unroll
  for (int ich = 0; ich < 8; ++ich) s += f1p[((size_t)ich * 4 + b) * 600 + o];
  h1[(size_t)b * 600 + o] = lrelu(s);
}

__global__ __launch_bounds__(256) void k_fc2(const float* __restrict__ h1,
                                             const float* __restrict__ w,
                                             const float* __restrict__ bias,
                                             float* __restrict__ h2) {
  int idx = blockIdx.x * 256 + threadIdx.x;
  if (idx >= 1200) return;
  int o = idx % 300, b = idx / 300;
  float s = bias[o];
  const float* hb = h1 + (size_t)b * 600;
  for (int i = 0; i < 600; ++i) s = fmaf(hb[i], w[(size_t)i * 300 + o], s);
  h2[(size_t)b * 300 + o] = lrelu(s);
}

__global__ __launch_bounds__(256) void k_fc3(const float* __restrict__ h2,
                                             const float* __restrict__ w,
                                             const float* __restrict__ bias,
                                             float* __restrict__ out) {
  int t = threadIdx.x, b = t >> 6, l = t & 63;
  float s = 0.f;
#pragma unroll
  for (int m = 0; m < 5; ++m) {
    int i = l + m * 64;
    if (i < 300) s = fmaf(h2[(size_t)b * 300 + i], w[i], s);
  }
  for (int off = 32; off; off >>= 1) s += __shfl_down(s, off, 64);
  if (l == 0) out[262144 + b] = s + bias[0];
}

extern "C" void kernel_launch(void* const* d_in, const int* in_sizes, int n_in,
                              void* d_out, int out_size, void* d_ws, size_t ws_size,
                              hipStream_t stream) {
  float* ws = (float*)d_ws;
  const int* p1 = (const int*)d_in[0];
  const int* p2 = (const int*)d_in[1];
  const float* emb  = (const float*)d_in[2];
  const float* w0   = (const float*)d_in[3];
  const float* b0   = (const float*)d_in[4];
  const float* w1   = (const float*)d_in[5];
  const float* b1   = (const float*)d_in[6];
  const float* w2   = (const float*)d_in[7];
  const float* b2   = (const float*)d_in[8];
  const float* ja1w = (const float*)d_in[9];
  const float* ja1b = (const float*)d_in[10];
  const float* ja2w = (const float*)d_in[11];
  const float* ja2b = (const float*)d_in[12];
  const float* rcw  = (const float*)d_in[13];
  const float* rcb  = (const float*)d_in[14];
  const float* fc1w = (const float*)d_in[15];
  const float* fc1b = (const float*)d_in[16];
  const float* fc2w = (const float*)d_in[17];
  const float* fc2b = (const float*)d_in[18];
  const float* fc3w = (const float*)d_in[19];
  const float* fc3b = (const float*)d_in[20];
  float* out = (float*)d_out;

  u16* xa_hi = (u16*)(ws + OFF_XA);
  u16* xa_lo = xa_hi + XT_PLANE;
  u16* xb_hi = (u16*)(ws + OFF_XB);
  u16* xb_lo = xb_hi + XT_PLANE;
  u16* wbu = (u16*)(ws + OFF_WB);

  // zero Xt buffers (pads must be 0)
  hipMemsetAsync(ws + OFF_XA, 0, 2 * 557056 * sizeof(float), stream);

  k_embed<<<2048, 256, 0, stream>>>(p1, p2, emb, ws + OFF_E0);
  k_prepW<4><<<128, 256, 0, stream>>>(w0, wbu + WB_L1);
  k_prepW<8><<<256, 256, 0, stream>>>(w1, wbu + WB_L2);
  k_prepW<12><<<384, 256, 0, stream>>>(w2, wbu + WB_L3);
  k_t32<<<512, 256, 0, stream>>>(ws + OFF_E0, xa_hi, xa_lo);

  k_cmf<4, 1, 0><<<512, 256, 0, stream>>>(xa_hi, xa_lo, wbu + WB_L1, b0, xb_hi, xb_lo, nullptr);
  k_cmf<8, 3, 0><<<512, 256, 0, stream>>>(xb_hi, xb_lo, wbu + WB_L2, b1, xa_hi, xa_lo, nullptr);
  k_cmf<12, 5, 1><<<512, 256, 0, stream>>>(xa_hi, xa_lo, wbu + WB_L3, b2, nullptr, nullptr,
                                           ws + OFF_E1);

  k_ja<<<256, 256, 0, stream>>>(ws + OFF_E1, ja1w, ja1b, ja2w, ja2b, ws + OFF_Q, ws + OFF_KT);
  k_scores<<<128, 256, 0, stream>>>(ws + OFF_Q, ws + OFF_KT, ws + OFF_S, ws + OFF_BS);
  k_sumreduce<<<1, 256, 0, stream>>>(ws + OFF_BS, ws + OFF_SUM);
  k_norm_t<<<64, 256, 0, stream>>>(ws + OFF_S, ws + OFF_SUM, out, ws + OFF_STN);

  k_pool<<<256, 256, 0, stream>>>(ws + OFF_E1, ws + OFF_E2, ws + OFF_STN, ws + OFF_PP);
  k_poolcomb<<<4, 256, 0, stream>>>(ws + OFF_PP, ws + OFF_POOL);

  k_head1<<<1, 256, 0, stream>>>(ws + OFF_POOL, rcw, rcb, ws + OFF_H);
  k_fc1<<<80, 256, 0, stream>>>(ws + OFF_H, fc1w, ws + OFF_F1P);
  k_fc1c<<<10, 256, 0, stream>>>(ws + OFF_F1P, fc1b, ws + OFF_H1);
  k_fc2<<<5, 256, 0, stream>>>(ws + OFF_H1, fc2w, fc2b, ws + OFF_H2);
  k_fc3<<<1, 256, 0, stream>>>(ws + OFF_H2, fc3w, fc3b, out);
}

// Round 5
// 214.896 us; speedup vs baseline: 2.2913x; 1.2558x over previous
//
#include <hip/hip_runtime.h>
#include <hip/hip_bf16.h>

typedef unsigned short u16;
typedef unsigned int u32;
typedef short s8v __attribute__((ext_vector_type(8)));      // 8 bf16 bit-patterns
typedef float f32x16 __attribute__((ext_vector_type(16)));

constexpr int B = 4, L = 256, D = 256;
constexpr size_t SZ = (size_t)B * L * D;          // 262144

// Xt (transposed, padded) geometry: rows = j(-8..263) -> 272, cols = i 0..255
constexpr int XROWS = 272;
constexpr size_t XT_PLANE = (size_t)8 * XROWS * 256;   // ushorts per plane = 557056

// workspace offsets (floats)
constexpr size_t OFF_E    = 0;                        // 2*SZ fp32 e (pb 0..7)
constexpr size_t OFF_S    = 2 * SZ;
constexpr size_t OFF_STN  = 3 * SZ;
constexpr size_t OFF_E0   = 4 * SZ;                   // 2*SZ embed staging
constexpr size_t OFF_EBF  = OFF_E0;                   // alias: e bf16 hi/lo (2*SZ), E0 dead by then
constexpr size_t OFF_XA   = 6 * SZ;                   // 557056
constexpr size_t OFF_XB   = OFF_XA + 557056;
constexpr size_t OFF_WB   = OFF_XB + 557056;          // 1572864 floats (3145728 u16)
constexpr size_t OFF_WJ   = OFF_WB + 1572864;         // 131072 floats (262144 u16)
constexpr size_t OFF_QK   = OFF_WJ + 131072;          // 524288 floats (1048576 u16)
constexpr size_t OFF_BS   = OFF_QK + 524288;          // 64
constexpr size_t OFF_PP   = OFF_BS + 64;              // 262144
constexpr size_t OFF_POOL = OFF_PP + 262144;          // 1024
constexpr size_t OFF_H    = OFF_POOL + 1024;          // 8192
constexpr size_t OFF_F1P  = OFF_H + 8192;             // 19200
constexpr size_t OFF_H1   = OFF_F1P + 19200;          // 2400
constexpr size_t OFF_H2   = OFF_H1 + 2400;            // 1200

// Wb layer offsets in ushorts
constexpr size_t WB_L1 = 0;
constexpr size_t WB_L2 = (size_t)4 * 2 * 65536;
constexpr size_t WB_L3 = WB_L2 + (size_t)8 * 2 * 65536;

__device__ __forceinline__ float tanh_fast(float x) {
  float e = __expf(2.0f * x);
  return 1.0f - __fdividef(2.0f, e + 1.0f);
}
__device__ __forceinline__ float sig_fast(float x) {
  return __fdividef(1.0f, 1.0f + __expf(-x));
}
__device__ __forceinline__ float lrelu(float x) { return x >= 0.0f ? x : 0.1f * x; }

__device__ __forceinline__ void split_bf16(float v, u16& h, u16& l) {
  __bf16 hb = (__bf16)v;
  float hf = (float)hb;
  __bf16 lb = (__bf16)(v - hf);
  h = __builtin_bit_cast(u16, hb);
  l = __builtin_bit_cast(u16, lb);
}

__device__ __forceinline__ s8v lds16_8al(const u16* p) {   // 16B from LDS, 8B-aligned
  union { uint2 u[2]; s8v v; } r;
  r.u[0] = *(const uint2*)p;
  r.u[1] = *(const uint2*)(p + 4);
  return r.v;
}

// ---------------- embedding -> e0[pb][l][d] fp32 ----------------
__global__ __launch_bounds__(256) void k_embed(const int* __restrict__ t1,
                                               const int* __restrict__ t2,
                                               const float* __restrict__ emb,
                                               float* __restrict__ e0) {
  int blk = blockIdx.x;                 // pb(3) l(8)
  int l = blk & 255, pb = blk >> 8;
  const int* tok = (pb >> 2) ? t2 : t1;
  int tv = tok[(pb & 3) * L + l];
  e0[(size_t)pb * 65536 + (size_t)l * 256 + threadIdx.x] = emb[(size_t)tv * D + threadIdx.x];
}

// ---------------- conv-weight prep: fragment-major bf16 hi/lo ----------------
template <int K>
__global__ __launch_bounds__(256) void k_prepW(const float* __restrict__ w,
                                               u16* __restrict__ wl) {
  int q = blockIdx.x >> 5, ig = blockIdx.x & 31, oc = threadIdx.x;
  union { u16 us[8]; uint4 v; } H, Lo;
#pragma unroll
  for (int e = 0; e < 8; ++e) {
    float v = w[((size_t)oc * 256 + ig * 8 + e) * K + q];
    split_bf16(v, H.us[e], Lo.us[e]);
  }
  size_t dst = (size_t)(q * 2) * 65536 + (size_t)ig * 2048 + (size_t)oc * 8;
  *(uint4*)(wl + dst) = H.v;
  *(uint4*)(wl + dst + 65536) = Lo.v;
}

// ---------------- ja-weight prep: [p][plane][kg][n][8] bf16 hi/lo ----------------
__global__ __launch_bounds__(256) void k_prepJW(const float* __restrict__ w1,
                                                const float* __restrict__ w2,
                                                u16* __restrict__ wj) {
  int kg = blockIdx.x & 31, p = blockIdx.x >> 5;
  const float* W = p ? w2 : w1;
  int n = threadIdx.x;
  union { u16 us[8]; uint4 v; } H, Lo;
#pragma unroll
  for (int e = 0; e < 8; ++e) {
    float v = W[(size_t)(kg * 8 + e) * 256 + n];
    split_bf16(v, H.us[e], Lo.us[e]);
  }
  size_t dst = (size_t)(p * 2) * 65536 + ((size_t)kg * 256 + n) * 8;
  *(uint4*)(wj + dst) = H.v;
  *(uint4*)(wj + dst + 65536) = Lo.v;
}

// ---------------- e0 fp32 [pb][l][d] -> Xt hi/lo [pb][8+d][l] ----------------
__global__ __launch_bounds__(256) void k_t32(const float* __restrict__ e0,
                                             u16* __restrict__ yhi,
                                             u16* __restrict__ ylo) {
  int blk = blockIdx.x;                 // pb(3) lt(3) dt(3)
  int dt = blk & 7, lt = (blk >> 3) & 7, pb = blk >> 6;
  int l0 = lt * 32, d0 = dt * 32;
  __shared__ float st[32][33];
  int c = threadIdx.x & 31, rq = threadIdx.x >> 5;
#pragma unroll
  for (int rr = 0; rr < 4; ++rr) {
    int r = rq * 4 + rr;
    st[r][c] = e0[(size_t)pb * 65536 + (size_t)(l0 + r) * 256 + d0 + c];
  }
  __syncthreads();
  u16 hb[4], lb[4];
#pragma unroll
  for (int cc = 0; cc < 4; ++cc) split_bf16(st[rq * 4 + cc][c], hb[cc], lb[cc]);
  size_t ro = (size_t)pb * ((size_t)XROWS * 256) + (size_t)(8 + d0 + c) * 256 + l0 + rq * 4;
  *(ushort4*)(yhi + ro) = make_ushort4(hb[0], hb[1], hb[2], hb[3]);
  *(ushort4*)(ylo + ro) = make_ushort4(lb[0], lb[1], lb[2], lb[3]);
}

// ---------------- conv via MFMA ----------------
// OUTMODE 0: write next Xt hi/lo. OUTMODE 1: write e fp32 [pb][l][d] + e bf16 hi/lo planes.
template <int K, int P, int OUTMODE>
__global__ __launch_bounds__(256, 2) void k_cmf(const u16* __restrict__ xhi,
                                                const u16* __restrict__ xlo,
                                                const u16* __restrict__ wb,
                                                const float* __restrict__ bias,
                                                u16* __restrict__ yhi,
                                                u16* __restrict__ ylo,
                                                float* __restrict__ eout,
                                                u16* __restrict__ ebf_hi,
                                                u16* __restrict__ ebf_lo) {
  __shared__ u16 xs[2 * 12480];         // 2 planes x 48 rows x 260 ushorts

  int blk = blockIdx.x;                 // pb(3) oct(3) jt(3)
  int jt = blk & 7, oct = (blk >> 3) & 7, pb = blk >> 6;
  int oc0 = oct * 32, j0 = jt * 32;
  int tid = threadIdx.x;
  int lane = tid & 63, wv = tid >> 6;
  int l31 = lane & 31, lhi = lane >> 5;

  {
    const u32* sh = (const u32*)(xhi + (size_t)pb * (XROWS * 256) + (size_t)j0 * 256);
    const u32* sl = (const u32*)(xlo + (size_t)pb * (XROWS * 256) + (size_t)j0 * 256);
    u32* xd = (u32*)xs;
    for (int idx = tid; idx < 3072; idx += 256) {       // 48 rows x 64 x 8B
      int r = idx >> 6, c2 = (idx & 63) * 2;
      *(uint2*)(xd + r * 130 + c2) = *(const uint2*)(sh + (size_t)r * 128 + c2);
      *(uint2*)(xd + 6240 + r * 130 + c2) = *(const uint2*)(sl + (size_t)r * 128 + c2);
    }
  }
  __syncthreads();

  f32x16 acc = {};
  size_t abase = (size_t)(oc0 + l31) * 8 + (size_t)(wv * 8 + lhi) * 2048;
  int ib0 = wv * 64 + 8 * lhi;

  for (int q = 0; q < K; ++q) {
    int jr = l31 + q + (8 - P);
    const u16* bh0 = xs + jr * 260 + ib0;
    const u16* bl0 = bh0 + 12480;
    size_t aq = (size_t)q * 131072 + abase;
#pragma unroll
    for (int ic = 0; ic < 4; ++ic) {
      s8v ah = *(const s8v*)(wb + aq + ic * 4096);
      s8v al = *(const s8v*)(wb + aq + 65536 + ic * 4096);
      s8v bh = lds16_8al(bh0 + ic * 16);
      s8v bl = lds16_8al(bl0 + ic * 16);
      acc = __builtin_amdgcn_mfma_f32_32x32x16_bf16(ah, bh, acc, 0, 0, 0);
      acc = __builtin_amdgcn_mfma_f32_32x32x16_bf16(ah, bl, acc, 0, 0, 0);
      acc = __builtin_amdgcn_mfma_f32_32x32x16_bf16(al, bh, acc, 0, 0, 0);
    }
  }

  __syncthreads();
  float* cd = (float*)xs;
  int j = l31;
  if (wv > 0) {
#pragma unroll
    for (int r = 0; r < 16; ++r) {
      int ocr = (r & 3) + 8 * (r >> 2) + 4 * lhi;
      cd[(wv - 1) * 1024 + ocr * 32 + j] = acc[r];
    }
  }
  __syncthreads();
  if (wv == 0) {
#pragma unroll
    for (int r = 0; r < 16; ++r) {
      int ocr = (r & 3) + 8 * (r >> 2) + 4 * lhi;
      int idx = ocr * 32 + j;
      float s = acc[r] + cd[idx] + cd[1024 + idx] + cd[2048 + idx] + bias[oc0 + ocr];
      cd[3072 + ocr * 33 + j] = fmaxf(s, 0.0f);
    }
  }
  __syncthreads();

  if constexpr (OUTMODE == 0) {
    int jj = tid & 31, oq = tid >> 5;
    u16 hb[4], lb[4];
#pragma unroll
    for (int c2 = 0; c2 < 4; ++c2)
      split_bf16(cd[3072 + (oq * 4 + c2) * 33 + jj], hb[c2], lb[c2]);
    size_t ro = (size_t)pb * (XROWS * 256) + (size_t)(8 + j0 + jj) * 256 + oc0 + oq * 4;
    *(ushort4*)(yhi + ro) = make_ushort4(hb[0], hb[1], hb[2], hb[3]);
    *(ushort4*)(ylo + ro) = make_ushort4(lb[0], lb[1], lb[2], lb[3]);
  } else {
    int jj = tid & 31, oq = tid >> 5;
#pragma unroll
    for (int c2 = 0; c2 < 4; ++c2)
      eout[(size_t)pb * 65536 + (size_t)(oc0 + oq * 4 + c2) * 256 + j0 + jj] =
          cd[3072 + (oq * 4 + c2) * 33 + jj];
    // bf16 hi/lo planes, row-major [pb][l=oc][d=j]
    int ocl = tid >> 3, dg = tid & 7;
    u16 hb[4], lb[4];
#pragma unroll
    for (int c2 = 0; c2 < 4; ++c2)
      split_bf16(cd[3072 + ocl * 33 + dg * 4 + c2], hb[c2], lb[c2]);
    size_t ro2 = ((size_t)pb * 256 + oc0 + ocl) * 256 + j0 + dg * 4;
    *(ushort4*)(ebf_hi + ro2) = make_ushort4(hb[0], hb[1], hb[2], hb[3]);
    *(ushort4*)(ebf_lo + ro2) = make_ushort4(lb[0], lb[1], lb[2], lb[3]);
  }
}

// ---------------- joint-attention projections via MFMA -> q/k bf16 hi/lo ----------------
__global__ __launch_bounds__(256) void k_jam(const u16* __restrict__ ebf_hi,
                                             const u16* __restrict__ ebf_lo,
                                             const u16* __restrict__ wj,
                                             const float* __restrict__ b1,
                                             const float* __restrict__ b2,
                                             u16* __restrict__ qk_hi,
                                             u16* __restrict__ qk_lo) {
  __shared__ float tile[4][32][33];
  int blk = blockIdx.x;                 // p(1) b(2) tt(4)
  int tt = blk & 15, b = (blk >> 4) & 3, p = blk >> 6;
  int wv = threadIdx.x >> 6, lane = threadIdx.x & 63;
  int tl = tt * 4 + wv;                 // 0..63
  int it = tl >> 3, nt = tl & 7;
  int i0 = it * 32, n0 = nt * 32;
  int l31 = lane & 31, lhi = lane >> 5;

  const u16* eh = ebf_hi + ((size_t)(p * 4 + b) * 256 + i0 + l31) * 256 + lhi * 8;
  const u16* el = ebf_lo + ((size_t)(p * 4 + b) * 256 + i0 + l31) * 256 + lhi * 8;
  const u16* wjh = wj + (size_t)(p * 2) * 65536;

  f32x16 acc = {};
  for (int kc = 0; kc < 16; ++kc) {
    int kg = kc * 2 + lhi;
    s8v ah = *(const s8v*)(eh + kc * 16);
    s8v al = *(const s8v*)(el + kc * 16);
    s8v bh = *(const s8v*)(wjh + ((size_t)kg * 256 + n0 + l31) * 8);
    s8v bl = *(const s8v*)(wjh + 65536 + ((size_t)kg * 256 + n0 + l31) * 8);
    acc = __builtin_amdgcn_mfma_f32_32x32x16_bf16(ah, bh, acc, 0, 0, 0);
    acc = __builtin_amdgcn_mfma_f32_32x32x16_bf16(ah, bl, acc, 0, 0, 0);
    acc = __builtin_amdgcn_mfma_f32_32x32x16_bf16(al, bh, acc, 0, 0, 0);
  }

  float bv = (p ? b2 : b1)[n0 + l31];
#pragma unroll
  for (int r = 0; r < 16; ++r) {
    int row = (r & 3) + 8 * (r >> 2) + 4 * lhi;
    tile[wv][row][l31] = acc[r] + bv;
  }
  __syncthreads();

  float v[16];
#pragma unroll
  for (int c = 0; c < 16; ++c) v[c] = tile[wv][l31][lhi * 16 + c];
  union { u16 us[8]; uint4 q; } h0, h1, l0, l1;
#pragma unroll
  for (int c = 0; c < 8; ++c) split_bf16(v[c], h0.us[c], l0.us[c]);
#pragma unroll
  for (int c = 0; c < 8; ++c) split_bf16(v[8 + c], h1.us[c], l1.us[c]);
  size_t ro = ((size_t)(p * 4 + b) * 256 + i0 + l31) * 256 + n0 + lhi * 16;
  *(uint4*)(qk_hi + ro) = h0.q;
  *(uint4*)(qk_hi + ro + 8) = h1.q;
  *(uint4*)(qk_lo + ro) = l0.q;
  *(uint4*)(qk_lo + ro + 8) = l1.q;
}

// ---------------- scores via MFMA: sigmoid(q k^T) + per-block partial sums ----------------
__global__ __launch_bounds__(256) void k_scoresm(const u16* __restrict__ qk_hi,
                                                 const u16* __restrict__ qk_lo,
                                                 float* __restrict__ S,
                                                 float* __restrict__ bsums) {
  __shared__ float tile[4][32][33];
  __shared__ float wsum[4];
  int blk = blockIdx.x;                 // b(2) tt(4)
  int tt = blk & 15, b = blk >> 4;
  int wv = threadIdx.x >> 6, lane = threadIdx.x & 63;
  int tl = tt * 4 + wv;
  int it = tl >> 3, jt = tl & 7;
  int i0 = it * 32, j0 = jt * 32;
  int l31 = lane & 31, lhi = lane >> 5;

  const u16* qh = qk_hi + ((size_t)b * 256 + i0 + l31) * 256 + lhi * 8;
  const u16* ql = qk_lo + ((size_t)b * 256 + i0 + l31) * 256 + lhi * 8;
  const u16* kh = qk_hi + ((size_t)(4 + b) * 256 + j0 + l31) * 256 + lhi * 8;
  const u16* kl = qk_lo + ((size_t)(4 + b) * 256 + j0 + l31) * 256 + lhi * 8;

  f32x16 acc = {};
  for (int kc = 0; kc < 16; ++kc) {
    s8v ah = *(const s8v*)(qh + kc * 16);
    s8v al = *(const s8v*)(ql + kc * 16);
    s8v bh = *(const s8v*)(kh + kc * 16);
    s8v bl = *(const s8v*)(kl + kc * 16);
    acc = __builtin_amdgcn_mfma_f32_32x32x16_bf16(ah, bh, acc, 0, 0, 0);
    acc = __builtin_amdgcn_mfma_f32_32x32x16_bf16(ah, bl, acc, 0, 0, 0);
    acc = __builtin_amdgcn_mfma_f32_32x32x16_bf16(al, bh, acc, 0, 0, 0);
  }

  float part = 0.0f;
#pragma unroll
  for (int r = 0; r < 16; ++r) {
    int row = (r & 3) + 8 * (r >> 2) + 4 * lhi;
    float s = sig_fast(acc[r]);
    part += s;
    tile[wv][row][l31] = s;
  }
  for (int off = 32; off; off >>= 1) part += __shfl_down(part, off, 64);
  if (lane == 0) wsum[wv] = part;
  __syncthreads();

  // write S rows
  float* sp = S + ((size_t)b * 256 + i0 + l31) * 256 + j0 + lhi * 16;
#pragma unroll
  for (int c4 = 0; c4 < 4; ++c4) {
    float4 v;
    v.x = tile[wv][l31][lhi * 16 + c4 * 4 + 0];
    v.y = tile[wv][l31][lhi * 16 + c4 * 4 + 1];
    v.z = tile[wv][l31][lhi * 16 + c4 * 4 + 2];
    v.w = tile[wv][l31][lhi * 16 + c4 * 4 + 3];
    *(float4*)(sp + c4 * 4) = v;
  }
  if (threadIdx.x == 0) bsums[blk] = wsum[0] + wsum[1] + wsum[2] + wsum[3];
}

// ---------------- normalize + write inter output + transposed copy ----------------
__global__ __launch_bounds__(256) void k_norm_t(const float* __restrict__ S,
                                                const float* __restrict__ bsums,
                                                float* __restrict__ inter_out,
                                                float* __restrict__ STn) {
  int blk = blockIdx.x;                 // b(2) ti(2) tk(2)
  int tk = blk & 3, ti = (blk >> 2) & 3, b = blk >> 4;
  int i0 = ti * 64, k0 = tk * 64;
  float tot = 0.0f;
#pragma unroll
  for (int m = 0; m < 16; ++m) tot += bsums[b * 16 + m];
  float inv = 1.0f / tot;
  __shared__ float lds[64][65];
  int c = threadIdx.x & 63, rq = threadIdx.x >> 6;
#pragma unroll
  for (int ps = 0; ps < 16; ++ps) {
    int r = ps * 4 + rq;
    float v = S[(size_t)(b * L + i0 + r) * D + k0 + c] * inv;
    inter_out[(size_t)(b * L + i0 + r) * D + k0 + c] = v;
    lds[r][c] = v;
  }
  __syncthreads();
#pragma unroll
  for (int ps = 0; ps < 16; ++ps) {
    int r = ps * 4 + rq;
    STn[(size_t)(b * L + k0 + r) * D + i0 + c] = lds[c][r];
  }
}

// ---------------- bilinear tanh pooling (16 i x 16 k per block, 4-acc ILP) ----------------
__global__ __launch_bounds__(256) void k_pool(const float* __restrict__ e1,
                                              const float* __restrict__ e2,
                                              const float* __restrict__ STn,
                                              float* __restrict__ pp) {
  int blk = blockIdx.x;                 // b(2) ich(4) kch(4)
  int kch = blk & 15, ich = (blk >> 4) & 15, b = blk >> 8;
  int d = threadIdx.x, i0 = ich * 16, k0 = kch * 16;
  float ev[16];
#pragma unroll
  for (int ii = 0; ii < 16; ++ii) ev[ii] = e1[(size_t)(b * L + i0 + ii) * D + d];
  float a[4] = {0.f, 0.f, 0.f, 0.f};
  for (int kk = 0; kk < 16; ++kk) {
    int k = k0 + kk;
    float e2v = e2[(size_t)(b * L + k) * D + d];
    const float* sp = STn + (size_t)(b * L + k) * D + i0;
#pragma unroll
    for (int ii = 0; ii < 16; ++ii)
      a[ii & 3] = fmaf(tanh_fast(ev[ii] * e2v), sp[ii], a[ii & 3]);
  }
  pp[(((size_t)b * 16 + ich) * 16 + kch) * 256 + d] = a[0] + a[1] + a[2] + a[3];
}

__global__ __launch_bounds__(256) void k_poolcomb(const float* __restrict__ pp,
                                                  float* __restrict__ pooled) {
  int b = blockIdx.x, d = threadIdx.x;
  float s = 0.f;
  for (int m = 0; m < 256; ++m) s += pp[((size_t)b * 256 + m) * 256 + d];
  pooled[b * D + d] = s;
}

// ---------------- head: conv(stride2) + lrelu + maxpool4 ----------------
__global__ __launch_bounds__(256) void k_head1(const float* __restrict__ pooled,
                                               const float* __restrict__ rcw,
                                               const float* __restrict__ rcb,
                                               float* __restrict__ h) {
  int t = threadIdx.x, b = t >> 6, c = t & 63;
  float w0 = rcw[c * 4 + 0], w1 = rcw[c * 4 + 1], w2 = rcw[c * 4 + 2], w3 = rcw[c * 4 + 3];
  float bias = rcb[c];
  const float* pb = pooled + b * D;
  for (int m = 0; m < 32; ++m) {
    float mx = -1e30f;
#pragma unroll
    for (int r = 0; r < 4; ++r) {
      int p = 4 * m + r;
      int base = 2 * p - 1;
      float y = bias;
      if (base >= 0) y = fmaf(w0, pb[base], y);
      y = fmaf(w1, pb[base + 1], y);
      y = fmaf(w2, pb[base + 2], y);
      if (base + 3 < 256) y = fmaf(w3, pb[base + 3], y);
      y = lrelu(y);
      mx = fmaxf(mx, y);
    }
    h[(size_t)(b * 64 + c) * 32 + m] = mx;
  }
}

// ---------------- fc layers ----------------
__global__ __launch_bounds__(256) void k_fc1(const float* __restrict__ h,
                                             const float* __restrict__ w,
                                             float* __restrict__ f1p) {
  int blk = blockIdx.x;
  int ot = blk % 10, ich = blk / 10;
  int t = threadIdx.x, o = ot * 64 + (t & 63), b = t >> 6;
  if (o >= 600) return;
  float acc = 0.f;
  const float* hb = h + (size_t)b * 2048 + (size_t)ich * 256;
  const float* wb = w + (size_t)ich * 256 * 600 + o;
  for (int i = 0; i < 256; ++i) acc = fmaf(hb[i], wb[(size_t)i * 600], acc);
  f1p[((size_t)ich * 4 + b) * 600 + o] = acc;
}

__global__ __launch_bounds__(256) void k_fc1c(const float* __restrict__ f1p,
                                              const float* __restrict__ bias,
                                              float* __restrict__ h1) {
  int idx = blockIdx.x * 256 + threadIdx.x;
  if (idx >= 2400) return;
  int o = idx % 600, b = idx / 600;
  float s = bias[o];
#pragma unroll
  for (int ich = 0; ich < 8; ++ich) s += f1p[((size_t)ich * 4 + b) * 600 + o];
  h1[(size_t)b * 600 + o] = lrelu(s);
}

__global__ __launch_bounds__(256) void k_fc2(const float* __restrict__ h1,
                                             const float* __restrict__ w,
                                             const float* __restrict__ bias,
                                             float* __restrict__ h2) {
  int idx = blockIdx.x * 256 + threadIdx.x;
  if (idx >= 1200) return;
  int o = idx % 300, b = idx / 300;
  float s = bias[o];
  const float* hb = h1 + (size_t)b * 600;
  for (int i = 0; i < 600; ++i) s = fmaf(hb[i], w[(size_t)i * 300 + o], s);
  h2[(size_t)b * 300 + o] = lrelu(s);
}

__global__ __launch_bounds__(256) void k_fc3(const float* __restrict__ h2,
                                             const float* __restrict__ w,
                                             const float* __restrict__ bias,
                                             float* __restrict__ out) {
  int t = threadIdx.x, b = t >> 6, l = t & 63;
  float s = 0.f;
#pragma unroll
  for (int m = 0; m < 5; ++m) {
    int i = l + m * 64;
    if (i < 300) s = fmaf(h2[(size_t)b * 300 + i], w[i], s);
  }
  for (int off = 32; off; off >>= 1) s += __shfl_down(s, off, 64);
  if (l == 0) out[262144 + b] = s + bias[0];
}

extern "C" void kernel_launch(void* const* d_in, const int* in_sizes, int n_in,
                              void* d_out, int out_size, void* d_ws, size_t ws_size,
                              hipStream_t stream) {
  float* ws = (float*)d_ws;
  const int* p1 = (const int*)d_in[0];
  const int* p2 = (const int*)d_in[1];
  const float* emb  = (const float*)d_in[2];
  const float* w0   = (const float*)d_in[3];
  const float* b0   = (const float*)d_in[4];
  const float* w1   = (const float*)d_in[5];
  const float* b1   = (const float*)d_in[6];
  const float* w2   = (const float*)d_in[7];
  const float* b2   = (const float*)d_in[8];
  const float* ja1w = (const float*)d_in[9];
  const float* ja1b = (const float*)d_in[10];
  const float* ja2w = (const float*)d_in[11];
  const float* ja2b = (const float*)d_in[12];
  const float* rcw  = (const float*)d_in[13];
  const float* rcb  = (const float*)d_in[14];
  const float* fc1w = (const float*)d_in[15];
  const float* fc1b = (const float*)d_in[16];
  const float* fc2w = (const float*)d_in[17];
  const float* fc2b = (const float*)d_in[18];
  const float* fc3w = (const float*)d_in[19];
  const float* fc3b = (const float*)d_in[20];
  float* out = (float*)d_out;

  u16* xa_hi = (u16*)(ws + OFF_XA);
  u16* xa_lo = xa_hi + XT_PLANE;
  u16* xb_hi = (u16*)(ws + OFF_XB);
  u16* xb_lo = xb_hi + XT_PLANE;
  u16* wbu   = (u16*)(ws + OFF_WB);
  u16* wju   = (u16*)(ws + OFF_WJ);
  u16* ebf_hi = (u16*)(ws + OFF_EBF);
  u16* ebf_lo = ebf_hi + 524288;
  u16* qk_hi  = (u16*)(ws + OFF_QK);
  u16* qk_lo  = qk_hi + 524288;

  // zero Xt buffers (pads must be 0)
  hipMemsetAsync(ws + OFF_XA, 0, 2 * 557056 * sizeof(float), stream);

  k_embed<<<2048, 256, 0, stream>>>(p1, p2, emb, ws + OFF_E0);
  k_prepW<4><<<128, 256, 0, stream>>>(w0, wbu + WB_L1);
  k_prepW<8><<<256, 256, 0, stream>>>(w1, wbu + WB_L2);
  k_prepW<12><<<384, 256, 0, stream>>>(w2, wbu + WB_L3);
  k_prepJW<<<64, 256, 0, stream>>>(ja1w, ja2w, wju);
  k_t32<<<512, 256, 0, stream>>>(ws + OFF_E0, xa_hi, xa_lo);

  k_cmf<4, 1, 0><<<512, 256, 0, stream>>>(xa_hi, xa_lo, wbu + WB_L1, b0, xb_hi, xb_lo,
                                          nullptr, nullptr, nullptr);
  k_cmf<8, 3, 0><<<512, 256, 0, stream>>>(xb_hi, xb_lo, wbu + WB_L2, b1, xa_hi, xa_lo,
                                          nullptr, nullptr, nullptr);
  k_cmf<12, 5, 1><<<512, 256, 0, stream>>>(xa_hi, xa_lo, wbu + WB_L3, b2, nullptr, nullptr,
                                           ws + OFF_E, ebf_hi, ebf_lo);

  k_jam<<<128, 256, 0, stream>>>(ebf_hi, ebf_lo, wju, ja1b, ja2b, qk_hi, qk_lo);
  k_scoresm<<<64, 256, 0, stream>>>(qk_hi, qk_lo, ws + OFF_S, ws + OFF_BS);
  k_norm_t<<<64, 256, 0, stream>>>(ws + OFF_S, ws + OFF_BS, out, ws + OFF_STN);

  k_pool<<<1024, 256, 0, stream>>>(ws + OFF_E, ws + OFF_E + SZ, ws + OFF_STN, ws + OFF_PP);
  k_poolcomb<<<4, 256, 0, stream>>>(ws + OFF_PP, ws + OFF_POOL);

  k_head1<<<1, 256, 0, stream>>>(ws + OFF_POOL, rcw, rcb, ws + OFF_H);
  k_fc1<<<80, 256, 0, stream>>>(ws + OFF_H, fc1w, ws + OFF_F1P);
  k_fc1c<<<10, 256, 0, stream>>>(ws + OFF_F1P, fc1b, ws + OFF_H1);
  k_fc2<<<5, 256, 0, stream>>>(ws + OFF_H1, fc2w, fc2b, ws + OFF_H2);
  k_fc3<<<1, 256, 0, stream>>>(ws + OFF_H2, fc3w, fc3b, out);
}

// Round 6
// 134.539 us; speedup vs baseline: 3.6599x; 1.5973x over previous
//
#include <hip/hip_runtime.h>
#include <hip/hip_bf16.h>

typedef unsigned short u16;
typedef unsigned int u32;
typedef short s8v __attribute__((ext_vector_type(8)));      // 8 bf16 bit-patterns
typedef float f32x16 __attribute__((ext_vector_type(16)));

constexpr int B = 4, L = 256, D = 256;
constexpr size_t SZ = (size_t)B * L * D;          // 262144

// Xt (transposed, padded) geometry: rows = j(-8..263) -> 272, cols = i 0..255
constexpr int XROWS = 272;
constexpr size_t XT_PLANE = (size_t)8 * XROWS * 256;   // ushorts per plane = 557056

// workspace offsets (floats)
constexpr size_t OFF_E    = 0;                        // 2*SZ fp32 e (pb 0..7)
constexpr size_t OFF_S    = 2 * SZ;
constexpr size_t OFF_STN  = 3 * SZ;
constexpr size_t OFF_E0   = 4 * SZ;                   // 2*SZ embed staging
constexpr size_t OFF_EBF  = OFF_E0;                   // alias: e bf16 hi/lo (2*SZ)
constexpr size_t OFF_XA   = 6 * SZ;                   // 557056
constexpr size_t OFF_XB   = OFF_XA + 557056;
constexpr size_t OFF_WB   = OFF_XB + 557056;          // 1572864 floats
constexpr size_t OFF_WJ   = OFF_WB + 1572864;         // 131072 floats
constexpr size_t OFF_QK   = OFF_WJ + 131072;          // 524288 floats
constexpr size_t OFF_BS   = OFF_QK + 524288;          // 64
constexpr size_t OFF_PP   = OFF_BS + 64;              // 262144
constexpr size_t OFF_POOL = OFF_PP + 262144;          // 1024
constexpr size_t OFF_H    = OFF_POOL + 1024;          // 8192
constexpr size_t OFF_F1P  = OFF_H + 8192;             // 32*4*600 = 76800
constexpr size_t OFF_F2P  = OFF_F1P + 76800;          // 8*4*300 = 9600

// Wb layer offsets in ushorts
constexpr size_t WB_L1 = 0;
constexpr size_t WB_L2 = (size_t)4 * 2 * 65536;
constexpr size_t WB_L3 = WB_L2 + (size_t)8 * 2 * 65536;

__device__ __forceinline__ float sig_fast(float x) {
  return __fdividef(1.0f, 1.0f + __expf(-x));
}
__device__ __forceinline__ float lrelu(float x) { return x >= 0.0f ? x : 0.1f * x; }

__device__ __forceinline__ void split_bf16(float v, u16& h, u16& l) {
  __bf16 hb = (__bf16)v;
  float hf = (float)hb;
  __bf16 lb = (__bf16)(v - hf);
  h = __builtin_bit_cast(u16, hb);
  l = __builtin_bit_cast(u16, lb);
}

__device__ __forceinline__ s8v lds16_8al(const u16* p) {   // 16B from LDS, 8B-aligned
  union { uint2 u[2]; s8v v; } r;
  r.u[0] = *(const uint2*)p;
  r.u[1] = *(const uint2*)(p + 4);
  return r.v;
}

// ---------------- embedding -> e0[pb][l][d] fp32 ----------------
__global__ __launch_bounds__(256) void k_embed(const int* __restrict__ t1,
                                               const int* __restrict__ t2,
                                               const float* __restrict__ emb,
                                               float* __restrict__ e0) {
  int blk = blockIdx.x;                 // pb(3) l(8)
  int l = blk & 255, pb = blk >> 8;
  const int* tok = (pb >> 2) ? t2 : t1;
  int tv = tok[(pb & 3) * L + l];
  e0[(size_t)pb * 65536 + (size_t)l * 256 + threadIdx.x] = emb[(size_t)tv * D + threadIdx.x];
}

// ---------------- conv-weight prep: fragment-major bf16 hi/lo ----------------
template <int K>
__global__ __launch_bounds__(256) void k_prepW(const float* __restrict__ w,
                                               u16* __restrict__ wl) {
  int q = blockIdx.x >> 5, ig = blockIdx.x & 31, oc = threadIdx.x;
  union { u16 us[8]; uint4 v; } H, Lo;
#pragma unroll
  for (int e = 0; e < 8; ++e) {
    float v = w[((size_t)oc * 256 + ig * 8 + e) * K + q];
    split_bf16(v, H.us[e], Lo.us[e]);
  }
  size_t dst = (size_t)(q * 2) * 65536 + (size_t)ig * 2048 + (size_t)oc * 8;
  *(uint4*)(wl + dst) = H.v;
  *(uint4*)(wl + dst + 65536) = Lo.v;
}

// ---------------- ja-weight prep ----------------
__global__ __launch_bounds__(256) void k_prepJW(const float* __restrict__ w1,
                                                const float* __restrict__ w2,
                                                u16* __restrict__ wj) {
  int kg = blockIdx.x & 31, p = blockIdx.x >> 5;
  const float* W = p ? w2 : w1;
  int n = threadIdx.x;
  union { u16 us[8]; uint4 v; } H, Lo;
#pragma unroll
  for (int e = 0; e < 8; ++e) {
    float v = W[(size_t)(kg * 8 + e) * 256 + n];
    split_bf16(v, H.us[e], Lo.us[e]);
  }
  size_t dst = (size_t)(p * 2) * 65536 + ((size_t)kg * 256 + n) * 8;
  *(uint4*)(wj + dst) = H.v;
  *(uint4*)(wj + dst + 65536) = Lo.v;
}

// ---------------- e0 fp32 [pb][l][d] -> Xt hi/lo [pb][8+d][l] ----------------
__global__ __launch_bounds__(256) void k_t32(const float* __restrict__ e0,
                                             u16* __restrict__ yhi,
                                             u16* __restrict__ ylo) {
  int blk = blockIdx.x;                 // pb(3) lt(3) dt(3)
  int dt = blk & 7, lt = (blk >> 3) & 7, pb = blk >> 6;
  int l0 = lt * 32, d0 = dt * 32;
  __shared__ float st[32][33];
  int c = threadIdx.x & 31, rq = threadIdx.x >> 5;
#pragma unroll
  for (int rr = 0; rr < 4; ++rr) {
    int r = rq * 4 + rr;
    st[r][c] = e0[(size_t)pb * 65536 + (size_t)(l0 + r) * 256 + d0 + c];
  }
  __syncthreads();
  u16 hb[4], lb[4];
#pragma unroll
  for (int cc = 0; cc < 4; ++cc) split_bf16(st[rq * 4 + cc][c], hb[cc], lb[cc]);
  size_t ro = (size_t)pb * ((size_t)XROWS * 256) + (size_t)(8 + d0 + c) * 256 + l0 + rq * 4;
  *(ushort4*)(yhi + ro) = make_ushort4(hb[0], hb[1], hb[2], hb[3]);
  *(ushort4*)(ylo + ro) = make_ushort4(lb[0], lb[1], lb[2], lb[3]);
}

// ---------------- conv via MFMA ----------------
template <int K, int P, int OUTMODE>
__global__ __launch_bounds__(256, 2) void k_cmf(const u16* __restrict__ xhi,
                                                const u16* __restrict__ xlo,
                                                const u16* __restrict__ wb,
                                                const float* __restrict__ bias,
                                                u16* __restrict__ yhi,
                                                u16* __restrict__ ylo,
                                                float* __restrict__ eout,
                                                u16* __restrict__ ebf_hi,
                                                u16* __restrict__ ebf_lo) {
  __shared__ u16 xs[2 * 12480];         // 2 planes x 48 rows x 260 ushorts

  int blk = blockIdx.x;                 // pb(3) oct(3) jt(3)
  int jt = blk & 7, oct = (blk >> 3) & 7, pb = blk >> 6;
  int oc0 = oct * 32, j0 = jt * 32;
  int tid = threadIdx.x;
  int lane = tid & 63, wv = tid >> 6;
  int l31 = lane & 31, lhi = lane >> 5;

  {
    const u32* sh = (const u32*)(xhi + (size_t)pb * (XROWS * 256) + (size_t)j0 * 256);
    const u32* sl = (const u32*)(xlo + (size_t)pb * (XROWS * 256) + (size_t)j0 * 256);
    u32* xd = (u32*)xs;
    for (int idx = tid; idx < 3072; idx += 256) {       // 48 rows x 64 x 8B
      int r = idx >> 6, c2 = (idx & 63) * 2;
      *(uint2*)(xd + r * 130 + c2) = *(const uint2*)(sh + (size_t)r * 128 + c2);
      *(uint2*)(xd + 6240 + r * 130 + c2) = *(const uint2*)(sl + (size_t)r * 128 + c2);
    }
  }
  __syncthreads();

  f32x16 acc = {};
  size_t abase = (size_t)(oc0 + l31) * 8 + (size_t)(wv * 8 + lhi) * 2048;
  int ib0 = wv * 64 + 8 * lhi;

  for (int q = 0; q < K; ++q) {
    int jr = l31 + q + (8 - P);
    const u16* bh0 = xs + jr * 260 + ib0;
    const u16* bl0 = bh0 + 12480;
    size_t aq = (size_t)q * 131072 + abase;
#pragma unroll
    for (int ic = 0; ic < 4; ++ic) {
      s8v ah = *(const s8v*)(wb + aq + ic * 4096);
      s8v al = *(const s8v*)(wb + aq + 65536 + ic * 4096);
      s8v bh = lds16_8al(bh0 + ic * 16);
      s8v bl = lds16_8al(bl0 + ic * 16);
      acc = __builtin_amdgcn_mfma_f32_32x32x16_bf16(ah, bh, acc, 0, 0, 0);
      acc = __builtin_amdgcn_mfma_f32_32x32x16_bf16(ah, bl, acc, 0, 0, 0);
      acc = __builtin_amdgcn_mfma_f32_32x32x16_bf16(al, bh, acc, 0, 0, 0);
    }
  }

  __syncthreads();
  float* cd = (float*)xs;
  int j = l31;
  if (wv > 0) {
#pragma unroll
    for (int r = 0; r < 16; ++r) {
      int ocr = (r & 3) + 8 * (r >> 2) + 4 * lhi;
      cd[(wv - 1) * 1024 + ocr * 32 + j] = acc[r];
    }
  }
  __syncthreads();
  if (wv == 0) {
#pragma unroll
    for (int r = 0; r < 16; ++r) {
      int ocr = (r & 3) + 8 * (r >> 2) + 4 * lhi;
      int idx = ocr * 32 + j;
      float s = acc[r] + cd[idx] + cd[1024 + idx] + cd[2048 + idx] + bias[oc0 + ocr];
      cd[3072 + ocr * 33 + j] = fmaxf(s, 0.0f);
    }
  }
  __syncthreads();

  if constexpr (OUTMODE == 0) {
    int jj = tid & 31, oq = tid >> 5;
    u16 hb[4], lb[4];
#pragma unroll
    for (int c2 = 0; c2 < 4; ++c2)
      split_bf16(cd[3072 + (oq * 4 + c2) * 33 + jj], hb[c2], lb[c2]);
    size_t ro = (size_t)pb * (XROWS * 256) + (size_t)(8 + j0 + jj) * 256 + oc0 + oq * 4;
    *(ushort4*)(yhi + ro) = make_ushort4(hb[0], hb[1], hb[2], hb[3]);
    *(ushort4*)(ylo + ro) = make_ushort4(lb[0], lb[1], lb[2], lb[3]);
  } else {
    int jj = tid & 31, oq = tid >> 5;
#pragma unroll
    for (int c2 = 0; c2 < 4; ++c2)
      eout[(size_t)pb * 65536 + (size_t)(oc0 + oq * 4 + c2) * 256 + j0 + jj] =
          cd[3072 + (oq * 4 + c2) * 33 + jj];
    int ocl = tid >> 3, dg = tid & 7;
    u16 hb[4], lb[4];
#pragma unroll
    for (int c2 = 0; c2 < 4; ++c2)
      split_bf16(cd[3072 + ocl * 33 + dg * 4 + c2], hb[c2], lb[c2]);
    size_t ro2 = ((size_t)pb * 256 + oc0 + ocl) * 256 + j0 + dg * 4;
    *(ushort4*)(ebf_hi + ro2) = make_ushort4(hb[0], hb[1], hb[2], hb[3]);
    *(ushort4*)(ebf_lo + ro2) = make_ushort4(lb[0], lb[1], lb[2], lb[3]);
  }
}

// ---------------- joint-attention projections via MFMA -> q/k bf16 hi/lo ----------------
__global__ __launch_bounds__(256) void k_jam(const u16* __restrict__ ebf_hi,
                                             const u16* __restrict__ ebf_lo,
                                             const u16* __restrict__ wj,
                                             const float* __restrict__ b1,
                                             const float* __restrict__ b2,
                                             u16* __restrict__ qk_hi,
                                             u16* __restrict__ qk_lo) {
  __shared__ float tile[4][32][33];
  int blk = blockIdx.x;                 // p(1) b(2) tt(4)
  int tt = blk & 15, b = (blk >> 4) & 3, p = blk >> 6;
  int wv = threadIdx.x >> 6, lane = threadIdx.x & 63;
  int tl = tt * 4 + wv;
  int it = tl >> 3, nt = tl & 7;
  int i0 = it * 32, n0 = nt * 32;
  int l31 = lane & 31, lhi = lane >> 5;

  const u16* eh = ebf_hi + ((size_t)(p * 4 + b) * 256 + i0 + l31) * 256 + lhi * 8;
  const u16* el = ebf_lo + ((size_t)(p * 4 + b) * 256 + i0 + l31) * 256 + lhi * 8;
  const u16* wjh = wj + (size_t)(p * 2) * 65536;

  f32x16 acc = {};
  for (int kc = 0; kc < 16; ++kc) {
    int kg = kc * 2 + lhi;
    s8v ah = *(const s8v*)(eh + kc * 16);
    s8v al = *(const s8v*)(el + kc * 16);
    s8v bh = *(const s8v*)(wjh + ((size_t)kg * 256 + n0 + l31) * 8);
    s8v bl = *(const s8v*)(wjh + 65536 + ((size_t)kg * 256 + n0 + l31) * 8);
    acc = __builtin_amdgcn_mfma_f32_32x32x16_bf16(ah, bh, acc, 0, 0, 0);
    acc = __builtin_amdgcn_mfma_f32_32x32x16_bf16(ah, bl, acc, 0, 0, 0);
    acc = __builtin_amdgcn_mfma_f32_32x32x16_bf16(al, bh, acc, 0, 0, 0);
  }

  float bv = (p ? b2 : b1)[n0 + l31];
#pragma unroll
  for (int r = 0; r < 16; ++r) {
    int row = (r & 3) + 8 * (r >> 2) + 4 * lhi;
    tile[wv][row][l31] = acc[r] + bv;
  }
  __syncthreads();

  float v[16];
#pragma unroll
  for (int c = 0; c < 16; ++c) v[c] = tile[wv][l31][lhi * 16 + c];
  union { u16 us[8]; uint4 q; } h0, h1, l0, l1;
#pragma unroll
  for (int c = 0; c < 8; ++c) split_bf16(v[c], h0.us[c], l0.us[c]);
#pragma unroll
  for (int c = 0; c < 8; ++c) split_bf16(v[8 + c], h1.us[c], l1.us[c]);
  size_t ro = ((size_t)(p * 4 + b) * 256 + i0 + l31) * 256 + n0 + lhi * 16;
  *(uint4*)(qk_hi + ro) = h0.q;
  *(uint4*)(qk_hi + ro + 8) = h1.q;
  *(uint4*)(qk_lo + ro) = l0.q;
  *(uint4*)(qk_lo + ro + 8) = l1.q;
}

// ---------------- scores via MFMA ----------------
__global__ __launch_bounds__(256) void k_scoresm(const u16* __restrict__ qk_hi,
                                                 const u16* __restrict__ qk_lo,
                                                 float* __restrict__ S,
                                                 float* __restrict__ bsums) {
  __shared__ float tile[4][32][33];
  __shared__ float wsum[4];
  int blk = blockIdx.x;                 // b(2) tt(4)
  int tt = blk & 15, b = blk >> 4;
  int wv = threadIdx.x >> 6, lane = threadIdx.x & 63;
  int tl = tt * 4 + wv;
  int it = tl >> 3, jt = tl & 7;
  int i0 = it * 32, j0 = jt * 32;
  int l31 = lane & 31, lhi = lane >> 5;

  const u16* qh = qk_hi + ((size_t)b * 256 + i0 + l31) * 256 + lhi * 8;
  const u16* ql = qk_lo + ((size_t)b * 256 + i0 + l31) * 256 + lhi * 8;
  const u16* kh = qk_hi + ((size_t)(4 + b) * 256 + j0 + l31) * 256 + lhi * 8;
  const u16* kl = qk_lo + ((size_t)(4 + b) * 256 + j0 + l31) * 256 + lhi * 8;

  f32x16 acc = {};
  for (int kc = 0; kc < 16; ++kc) {
    s8v ah = *(const s8v*)(qh + kc * 16);
    s8v al = *(const s8v*)(ql + kc * 16);
    s8v bh = *(const s8v*)(kh + kc * 16);
    s8v bl = *(const s8v*)(kl + kc * 16);
    acc = __builtin_amdgcn_mfma_f32_32x32x16_bf16(ah, bh, acc, 0, 0, 0);
    acc = __builtin_amdgcn_mfma_f32_32x32x16_bf16(ah, bl, acc, 0, 0, 0);
    acc = __builtin_amdgcn_mfma_f32_32x32x16_bf16(al, bh, acc, 0, 0, 0);
  }

  float part = 0.0f;
#pragma unroll
  for (int r = 0; r < 16; ++r) {
    int row = (r & 3) + 8 * (r >> 2) + 4 * lhi;
    float s = sig_fast(acc[r]);
    part += s;
    tile[wv][row][l31] = s;
  }
  for (int off = 32; off; off >>= 1) part += __shfl_down(part, off, 64);
  if (lane == 0) wsum[wv] = part;
  __syncthreads();

  float* sp = S + ((size_t)b * 256 + i0 + l31) * 256 + j0 + lhi * 16;
#pragma unroll
  for (int c4 = 0; c4 < 4; ++c4) {
    float4 v;
    v.x = tile[wv][l31][lhi * 16 + c4 * 4 + 0];
    v.y = tile[wv][l31][lhi * 16 + c4 * 4 + 1];
    v.z = tile[wv][l31][lhi * 16 + c4 * 4 + 2];
    v.w = tile[wv][l31][lhi * 16 + c4 * 4 + 3];
    *(float4*)(sp + c4 * 4) = v;
  }
  if (threadIdx.x == 0) bsums[blk] = wsum[0] + wsum[1] + wsum[2] + wsum[3];
}

// ---------------- normalize + write inter output + transposed copy ----------------
__global__ __launch_bounds__(256) void k_norm_t(const float* __restrict__ S,
                                                const float* __restrict__ bsums,
                                                float* __restrict__ inter_out,
                                                float* __restrict__ STn) {
  int blk = blockIdx.x;                 // b(2) ti(2) tk(2)
  int tk = blk & 3, ti = (blk >> 2) & 3, b = blk >> 4;
  int i0 = ti * 64, k0 = tk * 64;
  float tot = 0.0f;
#pragma unroll
  for (int m = 0; m < 16; ++m) tot += bsums[b * 16 + m];
  float inv = 1.0f / tot;
  __shared__ float lds[64][65];
  int c = threadIdx.x & 63, rq = threadIdx.x >> 6;
#pragma unroll
  for (int ps = 0; ps < 16; ++ps) {
    int r = ps * 4 + rq;
    float v = S[(size_t)(b * L + i0 + r) * D + k0 + c] * inv;
    inter_out[(size_t)(b * L + i0 + r) * D + k0 + c] = v;
    lds[r][c] = v;
  }
  __syncthreads();
#pragma unroll
  for (int ps = 0; ps < 16; ++ps) {
    int r = ps * 4 + rq;
    STn[(size_t)(b * L + k0 + r) * D + i0 + c] = lds[c][r];
  }
}

// ---------------- bilinear tanh pooling: res = Ssp - sum (2*sp)*rcp(exp2(arg)+1) ----------------
__global__ __launch_bounds__(256) void k_pool(const float* __restrict__ e1,
                                              const float* __restrict__ e2,
                                              const float* __restrict__ STn,
                                              float* __restrict__ pp) {
  int blk = blockIdx.x;                 // b(2) ich(4) kch(4)
  int kch = blk & 15, ich = (blk >> 4) & 15, b = blk >> 8;
  int d = threadIdx.x, i0 = ich * 16, k0 = kch * 16;
  __shared__ float s2[16][16];          // [kk][ii] = 2*inter
  __shared__ float red[256];
  __shared__ float ssp_s;
  {
    int kk = threadIdx.x >> 4, ii = threadIdx.x & 15;
    float v = STn[((size_t)(b * L + k0 + kk)) * D + i0 + ii];
    s2[kk][ii] = 2.0f * v;
    red[threadIdx.x] = v;
  }
  __syncthreads();
  for (int st = 128; st; st >>= 1) {
    if (threadIdx.x < st) red[threadIdx.x] += red[threadIdx.x + st];
    __syncthreads();
  }
  if (threadIdx.x == 0) ssp_s = red[0];
  __syncthreads();

  constexpr float C2L = 2.8853900817779268f;   // 2*log2(e)
  float ev2[16];
#pragma unroll
  for (int ii = 0; ii < 16; ++ii)
    ev2[ii] = e1[((size_t)(b * L + i0 + ii)) * D + d] * C2L;

  float a0 = 0.f, a1 = 0.f, a2 = 0.f, a3 = 0.f;
  for (int kk = 0; kk < 16; ++kk) {
    float e2v = e2[((size_t)(b * L + k0 + kk)) * D + d];
    float s2r[16];
    *(float4*)&s2r[0]  = *(const float4*)&s2[kk][0];
    *(float4*)&s2r[4]  = *(const float4*)&s2[kk][4];
    *(float4*)&s2r[8]  = *(const float4*)&s2[kk][8];
    *(float4*)&s2r[12] = *(const float4*)&s2[kk][12];
#pragma unroll
    for (int ii = 0; ii < 16; ++ii) {
      float r = __builtin_amdgcn_rcpf(__builtin_exp2f(ev2[ii] * e2v) + 1.0f);
      if ((ii & 3) == 0) a0 = fmaf(r, s2r[ii], a0);
      else if ((ii & 3) == 1) a1 = fmaf(r, s2r[ii], a1);
      else if ((ii & 3) == 2) a2 = fmaf(r, s2r[ii], a2);
      else a3 = fmaf(r, s2r[ii], a3);
    }
  }
  float res = ssp_s - (a0 + a1 + a2 + a3);
  pp[(((size_t)b * 16 + ich) * 16 + kch) * 256 + d] = res;
}

__global__ __launch_bounds__(256) void k_poolcomb(const float* __restrict__ pp,
                                                  float* __restrict__ pooled) {
  int blk = blockIdx.x;                 // b(2) dt(3) -> 32 blocks
  int dt = blk & 7, b = blk >> 3;
  int t = threadIdx.x, dl = t & 31, mg = t >> 5;
  int d = dt * 32 + dl;
  float s = 0.f;
#pragma unroll
  for (int m = 0; m < 32; ++m)
    s += pp[((size_t)b * 256 + mg * 32 + m) * 256 + d];
  __shared__ float red[8][32];
  red[mg][dl] = s;
  __syncthreads();
  if (mg == 0) {
    float tot = red[0][dl] + red[1][dl] + red[2][dl] + red[3][dl] +
                red[4][dl] + red[5][dl] + red[6][dl] + red[7][dl];
    pooled[b * 256 + d] = tot;
  }
}

// ---------------- head: conv(stride2) + lrelu + maxpool4 (8 m-chunks) ----------------
__global__ __launch_bounds__(256) void k_head1(const float* __restrict__ pooled,
                                               const float* __restrict__ rcw,
                                               const float* __restrict__ rcb,
                                               float* __restrict__ h) {
  int ms = blockIdx.x;                  // 0..7
  __shared__ float spb[4][258];
  int t = threadIdx.x;
#pragma unroll
  for (int s = 0; s < 4; ++s) {
    int idx = s * 256 + t;
    spb[idx >> 8][(idx & 255) + 1] = pooled[idx];
  }
  if (t < 4) { spb[t][0] = 0.0f; spb[t][257] = 0.0f; }
  __syncthreads();
  int b = t >> 6, c = t & 63;
  float w0 = rcw[c * 4 + 0], w1 = rcw[c * 4 + 1], w2 = rcw[c * 4 + 2], w3 = rcw[c * 4 + 3];
  float bias = rcb[c];
#pragma unroll
  for (int mm = 0; mm < 4; ++mm) {
    int m = ms * 4 + mm;
    float mx = -1e30f;
#pragma unroll
    for (int r = 0; r < 4; ++r) {
      int p2 = 2 * (4 * m + r);         // padded index of base
      float y = bias;
      y = fmaf(w0, spb[b][p2], y);
      y = fmaf(w1, spb[b][p2 + 1], y);
      y = fmaf(w2, spb[b][p2 + 2], y);
      y = fmaf(w3, spb[b][p2 + 3], y);
      mx = fmaxf(mx, lrelu(y));
    }
    h[(size_t)(b * 64 + c) * 32 + m] = mx;
  }
}

// ---------------- fc1: 32 i-chunks x 10 o-tiles, partials ----------------
__global__ __launch_bounds__(256) void k_fc1(const float* __restrict__ h,
                                             const float* __restrict__ w,
                                             float* __restrict__ f1p) {
  int blk = blockIdx.x;                 // ot(4b? ) : ich = blk & 31, ot = blk >> 5
  int ich = blk & 31, ot = blk >> 5;
  int t = threadIdx.x, ol = t & 63, b = t >> 6;
  int o = ot * 64 + ol;
  int oc_ = o < 600 ? o : 599;
  const float* hb = h + (size_t)b * 2048 + ich * 64;
  const float* wb = w + (size_t)(ich * 64) * 600 + oc_;
  float a0 = 0.f, a1 = 0.f, a2 = 0.f, a3 = 0.f;
#pragma unroll 4
  for (int i = 0; i < 64; i += 4) {
    a0 = fmaf(hb[i], wb[(size_t)i * 600], a0);
    a1 = fmaf(hb[i + 1], wb[(size_t)(i + 1) * 600], a1);
    a2 = fmaf(hb[i + 2], wb[(size_t)(i + 2) * 600], a2);
    a3 = fmaf(hb[i + 3], wb[(size_t)(i + 3) * 600], a3);
  }
  if (o < 600) f1p[((size_t)ich * 4 + b) * 600 + o] = a0 + a1 + a2 + a3;
}

// ---------------- fc2 (fused fc1-combine): 5 o-tiles x 8 i-chunks ----------------
__global__ __launch_bounds__(256) void k_fc2(const float* __restrict__ f1p,
                                             const float* __restrict__ fc1b,
                                             const float* __restrict__ w,
                                             float* __restrict__ f2p) {
  int blk = blockIdx.x;                 // is = blk & 7, ot = blk >> 3 (40 blocks)
  int is = blk & 7, ot = blk >> 3;
  __shared__ float h1s[4][76];
  int t = threadIdx.x;
  for (int e = t; e < 300; e += 256) {
    int bb = e / 75, ii = e % 75;
    int i = is * 75 + ii;
    float s = fc1b[i];
#pragma unroll
    for (int ich = 0; ich < 32; ++ich) s += f1p[((size_t)ich * 4 + bb) * 600 + i];
    h1s[bb][ii] = lrelu(s);
  }
  __syncthreads();
  int ol = t & 63, b = t >> 6;
  int o = ot * 64 + ol, oc_ = o < 300 ? o : 299;
  const float* wb = w + (size_t)(is * 75) * 300 + oc_;
  float a0 = 0.f, a1 = 0.f, a2 = 0.f;
#pragma unroll 5
  for (int ii = 0; ii < 75; ii += 3) {
    a0 = fmaf(h1s[b][ii], wb[(size_t)ii * 300], a0);
    a1 = fmaf(h1s[b][ii + 1], wb[(size_t)(ii + 1) * 300], a1);
    a2 = fmaf(h1s[b][ii + 2], wb[(size_t)(ii + 2) * 300], a2);
  }
  if (o < 300) f2p[((size_t)is * 4 + b) * 300 + o] = a0 + a1 + a2;
}

// ---------------- fc3 (fused fc2-combine), 1 block ----------------
__global__ __launch_bounds__(1024) void k_fc3f(const float* __restrict__ f2p,
                                               const float* __restrict__ fc2b,
                                               const float* __restrict__ w3,
                                               const float* __restrict__ fc3b,
                                               float* __restrict__ out) {
  __shared__ float h2s[4][304];
  int t = threadIdx.x;
  for (int e = t; e < 1200; e += 1024) {
    int o = e % 300, b = e / 300;
    float s = fc2b[o];
#pragma unroll
    for (int is = 0; is < 8; ++is) s += f2p[((size_t)is * 4 + b) * 300 + o];
    h2s[b][o] = lrelu(s);
  }
  __syncthreads();
  int wv = t >> 6, l = t & 63;
  if (wv < 4) {
    float s = 0.f;
#pragma unroll
    for (int m = 0; m < 5; ++m) {
      int i = m * 64 + l;
      if (i < 300) s = fmaf(h2s[wv][i], w3[i], s);
    }
    for (int off = 32; off; off >>= 1) s += __shfl_down(s, off, 64);
    if (l == 0) out[262144 + wv] = s + fc3b[0];
  }
}

extern "C" void kernel_launch(void* const* d_in, const int* in_sizes, int n_in,
                              void* d_out, int out_size, void* d_ws, size_t ws_size,
                              hipStream_t stream) {
  float* ws = (float*)d_ws;
  const int* p1 = (const int*)d_in[0];
  const int* p2 = (const int*)d_in[1];
  const float* emb  = (const float*)d_in[2];
  const float* w0   = (const float*)d_in[3];
  const float* b0   = (const float*)d_in[4];
  const float* w1   = (const float*)d_in[5];
  const float* b1   = (const float*)d_in[6];
  const float* w2   = (const float*)d_in[7];
  const float* b2   = (const float*)d_in[8];
  const float* ja1w = (const float*)d_in[9];
  const float* ja1b = (const float*)d_in[10];
  const float* ja2w = (const float*)d_in[11];
  const float* ja2b = (const float*)d_in[12];
  const float* rcw  = (const float*)d_in[13];
  const float* rcb  = (const float*)d_in[14];
  const float* fc1w = (const float*)d_in[15];
  const float* fc1b = (const float*)d_in[16];
  const float* fc2w = (const float*)d_in[17];
  const float* fc2b = (const float*)d_in[18];
  const float* fc3w = (const float*)d_in[19];
  const float* fc3b = (const float*)d_in[20];
  float* out = (float*)d_out;

  u16* xa_hi = (u16*)(ws + OFF_XA);
  u16* xa_lo = xa_hi + XT_PLANE;
  u16* xb_hi = (u16*)(ws + OFF_XB);
  u16* xb_lo = xb_hi + XT_PLANE;
  u16* wbu   = (u16*)(ws + OFF_WB);
  u16* wju   = (u16*)(ws + OFF_WJ);
  u16* ebf_hi = (u16*)(ws + OFF_EBF);
  u16* ebf_lo = ebf_hi + 524288;
  u16* qk_hi  = (u16*)(ws + OFF_QK);
  u16* qk_lo  = qk_hi + 524288;

  hipMemsetAsync(ws + OFF_XA, 0, 2 * 557056 * sizeof(float), stream);

  k_embed<<<2048, 256, 0, stream>>>(p1, p2, emb, ws + OFF_E0);
  k_prepW<4><<<128, 256, 0, stream>>>(w0, wbu + WB_L1);
  k_prepW<8><<<256, 256, 0, stream>>>(w1, wbu + WB_L2);
  k_prepW<12><<<384, 256, 0, stream>>>(w2, wbu + WB_L3);
  k_prepJW<<<64, 256, 0, stream>>>(ja1w, ja2w, wju);
  k_t32<<<512, 256, 0, stream>>>(ws + OFF_E0, xa_hi, xa_lo);

  k_cmf<4, 1, 0><<<512, 256, 0, stream>>>(xa_hi, xa_lo, wbu + WB_L1, b0, xb_hi, xb_lo,
                                          nullptr, nullptr, nullptr);
  k_cmf<8, 3, 0><<<512, 256, 0, stream>>>(xb_hi, xb_lo, wbu + WB_L2, b1, xa_hi, xa_lo,
                                          nullptr, nullptr, nullptr);
  k_cmf<12, 5, 1><<<512, 256, 0, stream>>>(xa_hi, xa_lo, wbu + WB_L3, b2, nullptr, nullptr,
                                           ws + OFF_E, ebf_hi, ebf_lo);

  k_jam<<<128, 256, 0, stream>>>(ebf_hi, ebf_lo, wju, ja1b, ja2b, qk_hi, qk_lo);
  k_scoresm<<<64, 256, 0, stream>>>(qk_hi, qk_lo, ws + OFF_S, ws + OFF_BS);
  k_norm_t<<<64, 256, 0, stream>>>(ws + OFF_S, ws + OFF_BS, out, ws + OFF_STN);

  k_pool<<<1024, 256, 0, stream>>>(ws + OFF_E, ws + OFF_E + SZ, ws + OFF_STN, ws + OFF_PP);
  k_poolcomb<<<32, 256, 0, stream>>>(ws + OFF_PP, ws + OFF_POOL);

  k_head1<<<8, 256, 0, stream>>>(ws + OFF_POOL, rcw, rcb, ws + OFF_H);
  k_fc1<<<320, 256, 0, stream>>>(ws + OFF_H, fc1w, ws + OFF_F1P);
  k_fc2<<<40, 256, 0, stream>>>(ws + OFF_F1P, fc1b, fc2w, ws + OFF_F2P);
  k_fc3f<<<1, 1024, 0, stream>>>(ws + OFF_F2P, fc2b, fc3w, fc3b, out);
}

// Round 7
// 123.473 us; speedup vs baseline: 3.9879x; 1.0896x over previous
//
#include <hip/hip_runtime.h>
#include <hip/hip_bf16.h>

typedef unsigned short u16;
typedef unsigned int u32;
typedef short s8v __attribute__((ext_vector_type(8)));      // 8 bf16 bit-patterns
typedef float f32x16 __attribute__((ext_vector_type(16)));

constexpr int B = 4, L = 256, D = 256;
constexpr size_t SZ = (size_t)B * L * D;          // 262144

// Xt (transposed, padded) geometry: rows = spatial(-8..263) -> 272, cols = channel 0..255
constexpr int XROWS = 272;
constexpr size_t XT_PLANE = (size_t)8 * XROWS * 256;   // ushorts per plane = 557056

// workspace offsets (floats)
constexpr size_t OFF_E    = 0;                        // 2*SZ fp32 e
constexpr size_t OFF_S    = 2 * SZ;                   // 262144
constexpr size_t OFF_STN  = 3 * SZ;                   // 262144
constexpr size_t OFF_EBF  = 4 * SZ;                   // 524288 (2 bf16 planes)
constexpr size_t OFF_XA   = 6 * SZ;                   // 557056
constexpr size_t OFF_XB   = OFF_XA + 557056;
constexpr size_t OFF_WB   = OFF_XB + 557056;          // 1572864
constexpr size_t OFF_WJ   = OFF_WB + 1572864;         // 131072
constexpr size_t OFF_QK   = OFF_WJ + 131072;          // 524288
constexpr size_t OFF_BS   = OFF_QK + 524288;          // 256
constexpr size_t OFF_PP   = OFF_BS + 256;             // 524288
constexpr size_t OFF_POOL = OFF_PP + 524288;          // 1024
constexpr size_t OFF_H    = OFF_POOL + 1024;          // 8192
constexpr size_t OFF_F1P  = OFF_H + 8192;             // 76800
constexpr size_t OFF_F2P  = OFF_F1P + 76800;          // 9600

// Wb layer offsets in ushorts
constexpr size_t WB_L1 = 0;
constexpr size_t WB_L2 = (size_t)4 * 2 * 65536;
constexpr size_t WB_L3 = WB_L2 + (size_t)8 * 2 * 65536;

__device__ __forceinline__ float sig_fast(float x) {
  return __fdividef(1.0f, 1.0f + __expf(-x));
}
__device__ __forceinline__ float lrelu(float x) { return x >= 0.0f ? x : 0.1f * x; }

__device__ __forceinline__ void split_bf16(float v, u16& h, u16& l) {
  __bf16 hb = (__bf16)v;
  float hf = (float)hb;
  __bf16 lb = (__bf16)(v - hf);
  h = __builtin_bit_cast(u16, hb);
  l = __builtin_bit_cast(u16, lb);
}

__device__ __forceinline__ s8v lds16_8al(const u16* p) {   // 16B from LDS, 8B-aligned
  union { uint2 u[2]; s8v v; } r;
  r.u[0] = *(const uint2*)p;
  r.u[1] = *(const uint2*)(p + 4);
  return r.v;
}

// ---------------- zero pad rows of xa/xb (all 4 planes) ----------------
__global__ __launch_bounds__(256) void k_padz(u16* __restrict__ xa_hi) {
  int gid = blockIdx.x * 256 + threadIdx.x;       // 0..32767
  int plane = gid >> 13, rem = gid & 8191;
  int pb = rem >> 10, rem2 = rem & 1023;
  int row16 = rem2 >> 6, cc = rem2 & 63;
  int row = row16 < 8 ? row16 : 256 + row16;      // 0..7 or 264..271
  size_t off = (size_t)plane * XT_PLANE + (size_t)pb * (XROWS * 256) + (size_t)row * 256 + cc * 4;
  *(ushort4*)(xa_hi + off) = make_ushort4(0, 0, 0, 0);
}

// ---------------- fused weight prep (conv w0/w1/w2 + ja w1/w2) ----------------
__global__ __launch_bounds__(256) void k_prep(const float* __restrict__ w0,
                                              const float* __restrict__ w1,
                                              const float* __restrict__ w2,
                                              const float* __restrict__ jw1,
                                              const float* __restrict__ jw2,
                                              u16* __restrict__ wb,
                                              u16* __restrict__ wj) {
  int blk = blockIdx.x;
  if (blk < 768) {
    const float* w; u16* dst; int K, lblk;
    if (blk < 128) { w = w0; dst = wb + WB_L1; K = 4; lblk = blk; }
    else if (blk < 384) { w = w1; dst = wb + WB_L2; K = 8; lblk = blk - 128; }
    else { w = w2; dst = wb + WB_L3; K = 12; lblk = blk - 384; }
    int q = lblk >> 5, ig = lblk & 31, oc = threadIdx.x;
    union { u16 us[8]; uint4 v; } H, Lo;
#pragma unroll
    for (int e = 0; e < 8; ++e) {
      float v = w[((size_t)oc * 256 + ig * 8 + e) * K + q];
      split_bf16(v, H.us[e], Lo.us[e]);
    }
    size_t d = (size_t)(q * 2) * 65536 + (size_t)ig * 2048 + (size_t)oc * 8;
    *(uint4*)(dst + d) = H.v;
    *(uint4*)(dst + d + 65536) = Lo.v;
  } else {
    int lblk = blk - 768;
    int kg = lblk & 31, p = lblk >> 5;
    const float* W = p ? jw2 : jw1;
    int n = threadIdx.x;
    union { u16 us[8]; uint4 v; } H, Lo;
#pragma unroll
    for (int e = 0; e < 8; ++e) {
      float v = W[(size_t)(kg * 8 + e) * 256 + n];
      split_bf16(v, H.us[e], Lo.us[e]);
    }
    size_t d = (size_t)(p * 2) * 65536 + ((size_t)kg * 256 + n) * 8;
    *(uint4*)(wj + d) = H.v;
    *(uint4*)(wj + d + 65536) = Lo.v;
  }
}

// ---------------- fused embedding + split + transpose -> Xt hi/lo ----------------
__global__ __launch_bounds__(256) void k_embT(const int* __restrict__ t1,
                                              const int* __restrict__ t2,
                                              const float* __restrict__ emb,
                                              u16* __restrict__ yhi,
                                              u16* __restrict__ ylo) {
  __shared__ float st[32][129];
  int blk = blockIdx.x;                 // pb(3) lt(3) dt(1)
  int dt = blk & 1, lt = (blk >> 1) & 7, pb = blk >> 4;
  int l0 = lt * 32, d0 = dt * 128;
  const int* tok = (pb >> 2) ? t2 : t1;
  int t = threadIdx.x;
  int c = t & 127, rq = t >> 7;
#pragma unroll 4
  for (int rr = 0; rr < 16; ++rr) {
    int r = rr * 2 + rq;
    int tv = tok[(pb & 3) * 256 + l0 + r];
    st[r][c] = emb[(size_t)tv * 256 + d0 + c];
  }
  __syncthreads();
  int dloc = t >> 1, lq = t & 1;
  size_t rbase = (size_t)pb * (XROWS * 256) + (size_t)(8 + d0 + dloc) * 256 + l0 + lq * 16;
#pragma unroll
  for (int lh = 0; lh < 4; ++lh) {
    u16 hb[4], lb[4];
#pragma unroll
    for (int cc = 0; cc < 4; ++cc)
      split_bf16(st[lq * 16 + lh * 4 + cc][dloc], hb[cc], lb[cc]);
    *(ushort4*)(yhi + rbase + lh * 4) = make_ushort4(hb[0], hb[1], hb[2], hb[3]);
    *(ushort4*)(ylo + rbase + lh * 4) = make_ushort4(lb[0], lb[1], lb[2], lb[3]);
  }
}

// ---------------- conv via MFMA ----------------
template <int K, int P, int OUTMODE>
__global__ __launch_bounds__(256, 3) void k_cmf(const u16* __restrict__ xhi,
                                                const u16* __restrict__ xlo,
                                                const u16* __restrict__ wb,
                                                const float* __restrict__ bias,
                                                u16* __restrict__ yhi,
                                                u16* __restrict__ ylo,
                                                float* __restrict__ eout,
                                                u16* __restrict__ ebf_hi,
                                                u16* __restrict__ ebf_lo) {
  __shared__ u16 xs[2 * 12480];         // 2 planes x 48 rows x 260 ushorts

  int blk = blockIdx.x;                 // pb(3) oct(3) jt(3)
  int jt = blk & 7, oct = (blk >> 3) & 7, pb = blk >> 6;
  int oc0 = oct * 32, j0 = jt * 32;
  int tid = threadIdx.x;
  int lane = tid & 63, wv = tid >> 6;
  int l31 = lane & 31, lhi = lane >> 5;

  {
    const u32* sh = (const u32*)(xhi + (size_t)pb * (XROWS * 256) + (size_t)j0 * 256);
    const u32* sl = (const u32*)(xlo + (size_t)pb * (XROWS * 256) + (size_t)j0 * 256);
    u32* xd = (u32*)xs;
    for (int idx = tid; idx < 3072; idx += 256) {       // 48 rows x 64 x 8B
      int r = idx >> 6, c2 = (idx & 63) * 2;
      *(uint2*)(xd + r * 130 + c2) = *(const uint2*)(sh + (size_t)r * 128 + c2);
      *(uint2*)(xd + 6240 + r * 130 + c2) = *(const uint2*)(sl + (size_t)r * 128 + c2);
    }
  }
  __syncthreads();

  f32x16 acc = {};
  size_t abase = (size_t)(oc0 + l31) * 8 + (size_t)(wv * 8 + lhi) * 2048;
  int ib0 = wv * 64 + 8 * lhi;

  for (int q = 0; q < K; ++q) {
    int jr = l31 + q + (8 - P);
    const u16* bh0 = xs + jr * 260 + ib0;
    const u16* bl0 = bh0 + 12480;
    size_t aq = (size_t)q * 131072 + abase;
#pragma unroll
    for (int ic = 0; ic < 4; ++ic) {
      s8v ah = *(const s8v*)(wb + aq + ic * 4096);
      s8v al = *(const s8v*)(wb + aq + 65536 + ic * 4096);
      s8v bh = lds16_8al(bh0 + ic * 16);
      s8v bl = lds16_8al(bl0 + ic * 16);
      acc = __builtin_amdgcn_mfma_f32_32x32x16_bf16(ah, bh, acc, 0, 0, 0);
      acc = __builtin_amdgcn_mfma_f32_32x32x16_bf16(ah, bl, acc, 0, 0, 0);
      acc = __builtin_amdgcn_mfma_f32_32x32x16_bf16(al, bh, acc, 0, 0, 0);
    }
  }

  __syncthreads();
  float* cd = (float*)xs;
  int j = l31;
  if (wv > 0) {
#pragma unroll
    for (int r = 0; r < 16; ++r) {
      int ocr = (r & 3) + 8 * (r >> 2) + 4 * lhi;
      cd[(wv - 1) * 1024 + ocr * 32 + j] = acc[r];
    }
  }
  __syncthreads();
  if (wv == 0) {
#pragma unroll
    for (int r = 0; r < 16; ++r) {
      int ocr = (r & 3) + 8 * (r >> 2) + 4 * lhi;
      int idx = ocr * 32 + j;
      float s = acc[r] + cd[idx] + cd[1024 + idx] + cd[2048 + idx] + bias[oc0 + ocr];
      cd[3072 + ocr * 33 + j] = fmaxf(s, 0.0f);
    }
  }
  __syncthreads();

  if constexpr (OUTMODE == 0) {
    int jj = tid & 31, oq = tid >> 5;
    u16 hb[4], lb[4];
#pragma unroll
    for (int c2 = 0; c2 < 4; ++c2)
      split_bf16(cd[3072 + (oq * 4 + c2) * 33 + jj], hb[c2], lb[c2]);
    size_t ro = (size_t)pb * (XROWS * 256) + (size_t)(8 + j0 + jj) * 256 + oc0 + oq * 4;
    *(ushort4*)(yhi + ro) = make_ushort4(hb[0], hb[1], hb[2], hb[3]);
    *(ushort4*)(ylo + ro) = make_ushort4(lb[0], lb[1], lb[2], lb[3]);
  } else {
    int jj = tid & 31, oq = tid >> 5;
#pragma unroll
    for (int c2 = 0; c2 < 4; ++c2)
      eout[(size_t)pb * 65536 + (size_t)(oc0 + oq * 4 + c2) * 256 + j0 + jj] =
          cd[3072 + (oq * 4 + c2) * 33 + jj];
    int ocl = tid >> 3, dg = tid & 7;
    u16 hb[4], lb[4];
#pragma unroll
    for (int c2 = 0; c2 < 4; ++c2)
      split_bf16(cd[3072 + ocl * 33 + dg * 4 + c2], hb[c2], lb[c2]);
    size_t ro2 = ((size_t)pb * 256 + oc0 + ocl) * 256 + j0 + dg * 4;
    *(ushort4*)(ebf_hi + ro2) = make_ushort4(hb[0], hb[1], hb[2], hb[3]);
    *(ushort4*)(ebf_lo + ro2) = make_ushort4(lb[0], lb[1], lb[2], lb[3]);
  }
}

// ---------------- ja projections via MFMA, 4-way k-split, 512 blocks ----------------
__global__ __launch_bounds__(256) void k_jam(const u16* __restrict__ ebf_hi,
                                             const u16* __restrict__ ebf_lo,
                                             const u16* __restrict__ wj,
                                             const float* __restrict__ b1,
                                             const float* __restrict__ b2,
                                             u16* __restrict__ qk_hi,
                                             u16* __restrict__ qk_lo) {
  __shared__ float cd[3072 + 1056];
  int blk = blockIdx.x;                 // pb(3) it(3) nt(3)
  int nt = blk & 7, it = (blk >> 3) & 7, pb = blk >> 6;
  int p = pb >> 2;
  int i0 = it * 32, n0 = nt * 32;
  int tid = threadIdx.x, wv = tid >> 6, lane = tid & 63;
  int l31 = lane & 31, lhi = lane >> 5;

  const u16* eh = ebf_hi + ((size_t)pb * 256 + i0 + l31) * 256 + lhi * 8;
  const u16* el = ebf_lo + ((size_t)pb * 256 + i0 + l31) * 256 + lhi * 8;
  const u16* wjh = wj + (size_t)(p * 2) * 65536;

  f32x16 acc = {};
#pragma unroll
  for (int c = 0; c < 4; ++c) {
    int kc = wv * 4 + c;
    int kg = kc * 2 + lhi;
    s8v ah = *(const s8v*)(eh + kc * 16);
    s8v al = *(const s8v*)(el + kc * 16);
    s8v bh = *(const s8v*)(wjh + ((size_t)kg * 256 + n0 + l31) * 8);
    s8v bl = *(const s8v*)(wjh + 65536 + ((size_t)kg * 256 + n0 + l31) * 8);
    acc = __builtin_amdgcn_mfma_f32_32x32x16_bf16(ah, bh, acc, 0, 0, 0);
    acc = __builtin_amdgcn_mfma_f32_32x32x16_bf16(ah, bl, acc, 0, 0, 0);
    acc = __builtin_amdgcn_mfma_f32_32x32x16_bf16(al, bh, acc, 0, 0, 0);
  }

  if (wv > 0) {
#pragma unroll
    for (int r = 0; r < 16; ++r) {
      int row = (r & 3) + 8 * (r >> 2) + 4 * lhi;
      cd[(wv - 1) * 1024 + row * 32 + l31] = acc[r];
    }
  }
  __syncthreads();
  if (wv == 0) {
    float bv = (p ? b2 : b1)[n0 + l31];
#pragma unroll
    for (int r = 0; r < 16; ++r) {
      int row = (r & 3) + 8 * (r >> 2) + 4 * lhi;
      int idx = row * 32 + l31;
      cd[3072 + row * 33 + l31] = acc[r] + cd[idx] + cd[1024 + idx] + cd[2048 + idx] + bv;
    }
  }
  __syncthreads();

  int row = tid & 31, c8 = tid >> 5;
  u16 hb[4], lb[4];
#pragma unroll
  for (int cc = 0; cc < 4; ++cc)
    split_bf16(cd[3072 + row * 33 + c8 * 4 + cc], hb[cc], lb[cc]);
  size_t ro = ((size_t)pb * 256 + i0 + row) * 256 + n0 + c8 * 4;
  *(ushort4*)(qk_hi + ro) = make_ushort4(hb[0], hb[1], hb[2], hb[3]);
  *(ushort4*)(qk_lo + ro) = make_ushort4(lb[0], lb[1], lb[2], lb[3]);
}

// ---------------- scores via MFMA, 4-way k-split, 256 blocks ----------------
__global__ __launch_bounds__(256) void k_scoresm(const u16* __restrict__ qk_hi,
                                                 const u16* __restrict__ qk_lo,
                                                 float* __restrict__ S,
                                                 float* __restrict__ bsums) {
  __shared__ float cd[3072 + 1056];
  int blk = blockIdx.x;                 // b(2) it(3) jt(3)
  int jt = blk & 7, it = (blk >> 3) & 7, b = blk >> 6;
  int i0 = it * 32, j0 = jt * 32;
  int tid = threadIdx.x, wv = tid >> 6, lane = tid & 63;
  int l31 = lane & 31, lhi = lane >> 5;

  const u16* qh = qk_hi + ((size_t)b * 256 + i0 + l31) * 256 + lhi * 8;
  const u16* ql = qk_lo + ((size_t)b * 256 + i0 + l31) * 256 + lhi * 8;
  const u16* kh = qk_hi + ((size_t)(4 + b) * 256 + j0 + l31) * 256 + lhi * 8;
  const u16* kl = qk_lo + ((size_t)(4 + b) * 256 + j0 + l31) * 256 + lhi * 8;

  f32x16 acc = {};
#pragma unroll
  for (int c = 0; c < 4; ++c) {
    int kc = wv * 4 + c;
    s8v ah = *(const s8v*)(qh + kc * 16);
    s8v al = *(const s8v*)(ql + kc * 16);
    s8v bh = *(const s8v*)(kh + kc * 16);
    s8v bl = *(const s8v*)(kl + kc * 16);
    acc = __builtin_amdgcn_mfma_f32_32x32x16_bf16(ah, bh, acc, 0, 0, 0);
    acc = __builtin_amdgcn_mfma_f32_32x32x16_bf16(ah, bl, acc, 0, 0, 0);
    acc = __builtin_amdgcn_mfma_f32_32x32x16_bf16(al, bh, acc, 0, 0, 0);
  }

  if (wv > 0) {
#pragma unroll
    for (int r = 0; r < 16; ++r) {
      int row = (r & 3) + 8 * (r >> 2) + 4 * lhi;
      cd[(wv - 1) * 1024 + row * 32 + l31] = acc[r];
    }
  }
  __syncthreads();
  if (wv == 0) {
    float psum = 0.0f;
#pragma unroll
    for (int r = 0; r < 16; ++r) {
      int row = (r & 3) + 8 * (r >> 2) + 4 * lhi;
      int idx = row * 32 + l31;
      float s = sig_fast(acc[r] + cd[idx] + cd[1024 + idx] + cd[2048 + idx]);
      psum += s;
      cd[3072 + row * 33 + l31] = s;
    }
    for (int off = 32; off; off >>= 1) psum += __shfl_down(psum, off, 64);
    if (lane == 0) bsums[blk] = psum;
  }
  __syncthreads();

  int row = tid & 31, c8 = tid >> 5;
  float4 v;
  v.x = cd[3072 + row * 33 + c8 * 4 + 0];
  v.y = cd[3072 + row * 33 + c8 * 4 + 1];
  v.z = cd[3072 + row * 33 + c8 * 4 + 2];
  v.w = cd[3072 + row * 33 + c8 * 4 + 3];
  *(float4*)(S + ((size_t)b * 256 + i0 + row) * 256 + j0 + c8 * 4) = v;
}

// ---------------- normalize + inter output + transposed copy (256 blocks) ----------------
__global__ __launch_bounds__(256) void k_norm_t(const float* __restrict__ S,
                                                const float* __restrict__ bsums,
                                                float* __restrict__ inter_out,
                                                float* __restrict__ STn) {
  int blk = blockIdx.x;                 // b(2) ti(3) tk(3)
  int tk = blk & 7, ti = (blk >> 3) & 7, b = blk >> 6;
  int i0 = ti * 32, k0 = tk * 32;
  float tot = 0.0f;
#pragma unroll
  for (int m = 0; m < 64; ++m) tot += bsums[b * 64 + m];
  float inv = 1.0f / tot;
  __shared__ float lds[32][33];
  int c = threadIdx.x & 31, rq = threadIdx.x >> 5;
#pragma unroll
  for (int ps = 0; ps < 4; ++ps) {
    int r = ps * 8 + rq;
    float v = S[(size_t)(b * L + i0 + r) * D + k0 + c] * inv;
    inter_out[(size_t)(b * L + i0 + r) * D + k0 + c] = v;
    lds[r][c] = v;
  }
  __syncthreads();
#pragma unroll
  for (int ps = 0; ps < 4; ++ps) {
    int r = ps * 8 + rq;
    STn[(size_t)(b * L + k0 + r) * D + i0 + c] = lds[c][r];
  }
}

// ---------------- bilinear tanh pooling: 8i x 16k tiles, 2048 blocks ----------------
__global__ __launch_bounds__(256) void k_pool(const float* __restrict__ e1,
                                              const float* __restrict__ e2,
                                              const float* __restrict__ STn,
                                              float* __restrict__ pp) {
  int blk = blockIdx.x;                 // b(2) ich(5) kch(4)
  int kch = blk & 15, ich = (blk >> 4) & 31, b = blk >> 9;
  int d = threadIdx.x, i0 = ich * 8, k0 = kch * 16;
  __shared__ float s2[16][8];           // [kk][ii] = 2*inter
  __shared__ float red[256];
  __shared__ float ssp_s;
  {
    float v = 0.0f;
    if (threadIdx.x < 128) {
      int kk = threadIdx.x >> 3, ii = threadIdx.x & 7;
      v = STn[((size_t)(b * L + k0 + kk)) * D + i0 + ii];
      s2[kk][ii] = 2.0f * v;
    }
    red[threadIdx.x] = v;
  }
  __syncthreads();
  for (int st = 128; st; st >>= 1) {
    if (threadIdx.x < st) red[threadIdx.x] += red[threadIdx.x + st];
    __syncthreads();
  }
  if (threadIdx.x == 0) ssp_s = red[0];
  __syncthreads();

  constexpr float C2L = 2.8853900817779268f;   // 2*log2(e)
  float ev2[8];
#pragma unroll
  for (int ii = 0; ii < 8; ++ii)
    ev2[ii] = e1[((size_t)(b * L + i0 + ii)) * D + d] * C2L;

  float a0 = 0.f, a1 = 0.f, a2 = 0.f, a3 = 0.f;
  for (int kk = 0; kk < 16; ++kk) {
    float e2v = e2[((size_t)(b * L + k0 + kk)) * D + d];
    float s2r[8];
    *(float4*)&s2r[0] = *(const float4*)&s2[kk][0];
    *(float4*)&s2r[4] = *(const float4*)&s2[kk][4];
#pragma unroll
    for (int ii = 0; ii < 8; ++ii) {
      float r = __builtin_amdgcn_rcpf(__builtin_exp2f(ev2[ii] * e2v) + 1.0f);
      if ((ii & 3) == 0) a0 = fmaf(r, s2r[ii], a0);
      else if ((ii & 3) == 1) a1 = fmaf(r, s2r[ii], a1);
      else if ((ii & 3) == 2) a2 = fmaf(r, s2r[ii], a2);
      else a3 = fmaf(r, s2r[ii], a3);
    }
  }
  float res = ssp_s - (a0 + a1 + a2 + a3);
  pp[(((size_t)b * 32 + ich) * 16 + kch) * 256 + d] = res;
}

__global__ __launch_bounds__(256) void k_poolcomb(const float* __restrict__ pp,
                                                  float* __restrict__ pooled) {
  int blk = blockIdx.x;                 // b(2) dt(3) -> 32 blocks
  int dt = blk & 7, b = blk >> 3;
  int t = threadIdx.x, dl = t & 31, mg = t >> 5;
  int d = dt * 32 + dl;
  float s = 0.f;
#pragma unroll
  for (int m = 0; m < 64; ++m)
    s += pp[((size_t)b * 512 + mg * 64 + m) * 256 + d];
  __shared__ float red[8][32];
  red[mg][dl] = s;
  __syncthreads();
  if (mg == 0) {
    float tot = red[0][dl] + red[1][dl] + red[2][dl] + red[3][dl] +
                red[4][dl] + red[5][dl] + red[6][dl] + red[7][dl];
    pooled[b * 256 + d] = tot;
  }
}

// ---------------- head: conv(stride2) + lrelu + maxpool4 ----------------
__global__ __launch_bounds__(256) void k_head1(const float* __restrict__ pooled,
                                               const float* __restrict__ rcw,
                                               const float* __restrict__ rcb,
                                               float* __restrict__ h) {
  int ms = blockIdx.x;                  // 0..7
  __shared__ float spb[4][258];
  int t = threadIdx.x;
#pragma unroll
  for (int s = 0; s < 4; ++s) {
    int idx = s * 256 + t;
    spb[idx >> 8][(idx & 255) + 1] = pooled[idx];
  }
  if (t < 4) { spb[t][0] = 0.0f; spb[t][257] = 0.0f; }
  __syncthreads();
  int b = t >> 6, c = t & 63;
  float w0 = rcw[c * 4 + 0], w1 = rcw[c * 4 + 1], w2 = rcw[c * 4 + 2], w3 = rcw[c * 4 + 3];
  float bias = rcb[c];
#pragma unroll
  for (int mm = 0; mm < 4; ++mm) {
    int m = ms * 4 + mm;
    float mx = -1e30f;
#pragma unroll
    for (int r = 0; r < 4; ++r) {
      int p2 = 2 * (4 * m + r);
      float y = bias;
      y = fmaf(w0, spb[b][p2], y);
      y = fmaf(w1, spb[b][p2 + 1], y);
      y = fmaf(w2, spb[b][p2 + 2], y);
      y = fmaf(w3, spb[b][p2 + 3], y);
      mx = fmaxf(mx, lrelu(y));
    }
    h[(size_t)(b * 64 + c) * 32 + m] = mx;
  }
}

// ---------------- fc layers ----------------
__global__ __launch_bounds__(256) void k_fc1(const float* __restrict__ h,
                                             const float* __restrict__ w,
                                             float* __restrict__ f1p) {
  int blk = blockIdx.x;
  int ich = blk & 31, ot = blk >> 5;
  int t = threadIdx.x, ol = t & 63, b = t >> 6;
  int o = ot * 64 + ol;
  int oc_ = o < 600 ? o : 599;
  const float* hb = h + (size_t)b * 2048 + ich * 64;
  const float* wb = w + (size_t)(ich * 64) * 600 + oc_;
  float a0 = 0.f, a1 = 0.f, a2 = 0.f, a3 = 0.f;
#pragma unroll 4
  for (int i = 0; i < 64; i += 4) {
    a0 = fmaf(hb[i], wb[(size_t)i * 600], a0);
    a1 = fmaf(hb[i + 1], wb[(size_t)(i + 1) * 600], a1);
    a2 = fmaf(hb[i + 2], wb[(size_t)(i + 2) * 600], a2);
    a3 = fmaf(hb[i + 3], wb[(size_t)(i + 3) * 600], a3);
  }
  if (o < 600) f1p[((size_t)ich * 4 + b) * 600 + o] = a0 + a1 + a2 + a3;
}

__global__ __launch_bounds__(256) void k_fc2(const float* __restrict__ f1p,
                                             const float* __restrict__ fc1b,
                                             const float* __restrict__ w,
                                             float* __restrict__ f2p) {
  int blk = blockIdx.x;
  int is = blk & 7, ot = blk >> 3;
  __shared__ float h1s[4][76];
  int t = threadIdx.x;
  for (int e = t; e < 300; e += 256) {
    int bb = e / 75, ii = e % 75;
    int i = is * 75 + ii;
    float s = fc1b[i];
#pragma unroll
    for (int ich = 0; ich < 32; ++ich) s += f1p[((size_t)ich * 4 + bb) * 600 + i];
    h1s[bb][ii] = lrelu(s);
  }
  __syncthreads();
  int ol = t & 63, b = t >> 6;
  int o = ot * 64 + ol, oc_ = o < 300 ? o : 299;
  const float* wb = w + (size_t)(is * 75) * 300 + oc_;
  float a0 = 0.f, a1 = 0.f, a2 = 0.f;
#pragma unroll 5
  for (int ii = 0; ii < 75; ii += 3) {
    a0 = fmaf(h1s[b][ii], wb[(size_t)ii * 300], a0);
    a1 = fmaf(h1s[b][ii + 1], wb[(size_t)(ii + 1) * 300], a1);
    a2 = fmaf(h1s[b][ii + 2], wb[(size_t)(ii + 2) * 300], a2);
  }
  if (o < 300) f2p[((size_t)is * 4 + b) * 300 + o] = a0 + a1 + a2;
}

__global__ __launch_bounds__(1024) void k_fc3f(const float* __restrict__ f2p,
                                               const float* __restrict__ fc2b,
                                               const float* __restrict__ w3,
                                               const float* __restrict__ fc3b,
                                               float* __restrict__ out) {
  __shared__ float h2s[4][304];
  int t = threadIdx.x;
  for (int e = t; e < 1200; e += 1024) {
    int o = e % 300, b = e / 300;
    float s = fc2b[o];
#pragma unroll
    for (int is = 0; is < 8; ++is) s += f2p[((size_t)is * 4 + b) * 300 + o];
    h2s[b][o] = lrelu(s);
  }
  __syncthreads();
  int wv = t >> 6, l = t & 63;
  if (wv < 4) {
    float s = 0.f;
#pragma unroll
    for (int m = 0; m < 5; ++m) {
      int i = m * 64 + l;
      if (i < 300) s = fmaf(h2s[wv][i], w3[i], s);
    }
    for (int off = 32; off; off >>= 1) s += __shfl_down(s, off, 64);
    if (l == 0) out[262144 + wv] = s + fc3b[0];
  }
}

extern "C" void kernel_launch(void* const* d_in, const int* in_sizes, int n_in,
                              void* d_out, int out_size, void* d_ws, size_t ws_size,
                              hipStream_t stream) {
  float* ws = (float*)d_ws;
  const int* p1 = (const int*)d_in[0];
  const int* p2 = (const int*)d_in[1];
  const float* emb  = (const float*)d_in[2];
  const float* w0   = (const float*)d_in[3];
  const float* b0   = (const float*)d_in[4];
  const float* w1   = (const float*)d_in[5];
  const float* b1   = (const float*)d_in[6];
  const float* w2   = (const float*)d_in[7];
  const float* b2   = (const float*)d_in[8];
  const float* ja1w = (const float*)d_in[9];
  const float* ja1b = (const float*)d_in[10];
  const float* ja2w = (const float*)d_in[11];
  const float* ja2b = (const float*)d_in[12];
  const float* rcw  = (const float*)d_in[13];
  const float* rcb  = (const float*)d_in[14];
  const float* fc1w = (const float*)d_in[15];
  const float* fc1b = (const float*)d_in[16];
  const float* fc2w = (const float*)d_in[17];
  const float* fc2b = (const float*)d_in[18];
  const float* fc3w = (const float*)d_in[19];
  const float* fc3b = (const float*)d_in[20];
  float* out = (float*)d_out;

  u16* xa_hi = (u16*)(ws + OFF_XA);
  u16* xa_lo = xa_hi + XT_PLANE;
  u16* xb_hi = (u16*)(ws + OFF_XB);
  u16* xb_lo = xb_hi + XT_PLANE;
  u16* wbu   = (u16*)(ws + OFF_WB);
  u16* wju   = (u16*)(ws + OFF_WJ);
  u16* ebf_hi = (u16*)(ws + OFF_EBF);
  u16* ebf_lo = ebf_hi + 524288;
  u16* qk_hi  = (u16*)(ws + OFF_QK);
  u16* qk_lo  = qk_hi + 524288;

  k_padz<<<128, 256, 0, stream>>>(xa_hi);
  k_prep<<<832, 256, 0, stream>>>(w0, w1, w2, ja1w, ja2w, wbu, wju);
  k_embT<<<128, 256, 0, stream>>>(p1, p2, emb, xa_hi, xa_lo);

  k_cmf<4, 1, 0><<<512, 256, 0, stream>>>(xa_hi, xa_lo, wbu + WB_L1, b0, xb_hi, xb_lo,
                                          nullptr, nullptr, nullptr);
  k_cmf<8, 3, 0><<<512, 256, 0, stream>>>(xb_hi, xb_lo, wbu + WB_L2, b1, xa_hi, xa_lo,
                                          nullptr, nullptr, nullptr);
  k_cmf<12, 5, 1><<<512, 256, 0, stream>>>(xa_hi, xa_lo, wbu + WB_L3, b2, nullptr, nullptr,
                                           ws + OFF_E, ebf_hi, ebf_lo);

  k_jam<<<512, 256, 0, stream>>>(ebf_hi, ebf_lo, wju, ja1b, ja2b, qk_hi, qk_lo);
  k_scoresm<<<256, 256, 0, stream>>>(qk_hi, qk_lo, ws + OFF_S, ws + OFF_BS);
  k_norm_t<<<256, 256, 0, stream>>>(ws + OFF_S, ws + OFF_BS, out, ws + OFF_STN);

  k_pool<<<2048, 256, 0, stream>>>(ws + OFF_E, ws + OFF_E + SZ, ws + OFF_STN, ws + OFF_PP);
  k_poolcomb<<<32, 256, 0, stream>>>(ws + OFF_PP, ws + OFF_POOL);

  k_head1<<<8, 256, 0, stream>>>(ws + OFF_POOL, rcw, rcb, ws + OFF_H);
  k_fc1<<<320, 256, 0, stream>>>(ws + OFF_H, fc1w, ws + OFF_F1P);
  k_fc2<<<40, 256, 0, stream>>>(ws + OFF_F1P, fc1b, fc2w, ws + OFF_F2P);
  k_fc3f<<<1, 1024, 0, stream>>>(ws + OFF_F2P, fc2b, fc3w, fc3b, out);
}

// Round 8
// 101.146 us; speedup vs baseline: 4.8682x; 1.2207x over previous
//
#include <hip/hip_runtime.h>
#include <hip/hip_bf16.h>

typedef unsigned short u16;
typedef unsigned int u32;
typedef short s8v __attribute__((ext_vector_type(8)));      // 8 bf16 bit-patterns
typedef float f32x16 __attribute__((ext_vector_type(16)));

constexpr int B = 4, L = 256, D = 256;
constexpr size_t SZ = (size_t)B * L * D;          // 262144

// Xt (transposed, padded): rows = spatial(-8..263) -> 272, cols = channel 0..255
constexpr int XROWS = 272;
constexpr size_t XT_PLANE = (size_t)8 * XROWS * 256;   // ushorts = 557056 (278528 floats)

// workspace offsets (floats)
constexpr size_t OFF_E    = 0;                        // 2*SZ fp32 e
constexpr size_t OFF_S    = 2 * SZ;                   // 262144 (raw sigmoid)
constexpr size_t OFF_EBF  = 3 * SZ;                   // 262144 (single bf16 plane, 8 pb)
constexpr size_t OFF_XA   = 4 * SZ;                   // 278528
constexpr size_t OFF_XB   = OFF_XA + 278528;          // 278528
constexpr size_t OFF_WB   = OFF_XB + 278528;          // 1572864 (hi/lo conv weights)
constexpr size_t OFF_WJ   = OFF_WB + 1572864;         // 131072 (hi/lo ja weights)
constexpr size_t OFF_QK   = OFF_WJ + 131072;          // 262144 (q,k single plane)
constexpr size_t OFF_BS   = OFF_QK + 262144;          // 256
constexpr size_t OFF_PP   = OFF_BS + 256;             // 524288
constexpr size_t OFF_POOL = OFF_PP + 524288;          // 1024
constexpr size_t OFF_H    = OFF_POOL + 1024;          // 8192
constexpr size_t OFF_F1P  = OFF_H + 8192;             // 76800
constexpr size_t OFF_F2P  = OFF_F1P + 76800;          // 9600

// Wb layer offsets in ushorts
constexpr size_t WB_L1 = 0;
constexpr size_t WB_L2 = (size_t)4 * 2 * 65536;
constexpr size_t WB_L3 = WB_L2 + (size_t)8 * 2 * 65536;

__device__ __forceinline__ float sig_fast(float x) {
  return __fdividef(1.0f, 1.0f + __expf(-x));
}
__device__ __forceinline__ float lrelu(float x) { return x >= 0.0f ? x : 0.1f * x; }

__device__ __forceinline__ void split_bf16(float v, u16& h, u16& l) {
  __bf16 hb = (__bf16)v;
  float hf = (float)hb;
  __bf16 lb = (__bf16)(v - hf);
  h = __builtin_bit_cast(u16, hb);
  l = __builtin_bit_cast(u16, lb);
}
__device__ __forceinline__ u16 to_bf16(float v) {
  return __builtin_bit_cast(u16, (__bf16)v);
}

__device__ __forceinline__ s8v lds16_8al(const u16* p) {   // 16B from LDS, 8B-aligned
  union { uint2 u[2]; s8v v; } r;
  r.u[0] = *(const uint2*)p;
  r.u[1] = *(const uint2*)(p + 4);
  return r.v;
}

// ---------------- fused prep: pad-zero + weight prep + embed/transpose ----------------
__global__ __launch_bounds__(256) void k_prepall(const int* __restrict__ t1,
                                                 const int* __restrict__ t2,
                                                 const float* __restrict__ emb,
                                                 const float* __restrict__ w0,
                                                 const float* __restrict__ w1,
                                                 const float* __restrict__ w2,
                                                 const float* __restrict__ jw1,
                                                 const float* __restrict__ jw2,
                                                 u16* __restrict__ xa,
                                                 u16* __restrict__ xb,
                                                 u16* __restrict__ wb,
                                                 u16* __restrict__ wj) {
  __shared__ float st[32][129];
  int blk = blockIdx.x;
  int t = threadIdx.x;
  if (blk < 64) {
    // zero pad rows (rows 0..7, 264..271) of xa and xb single planes
    int gid = blk * 256 + t;                    // 0..16383
    int plane = gid >> 13, rem = gid & 8191;
    int pb = rem >> 10, rem2 = rem & 1023;
    int row16 = rem2 >> 6, cc = rem2 & 63;
    int row = row16 < 8 ? row16 : 256 + row16;
    u16* dst = plane ? xb : xa;
    *(ushort4*)(dst + (size_t)pb * (XROWS * 256) + (size_t)row * 256 + cc * 4) =
        make_ushort4(0, 0, 0, 0);
  } else if (blk < 896) {
    int b2 = blk - 64;                          // 0..831
    if (b2 < 768) {
      const float* w; u16* dst; int K, lblk;
      if (b2 < 128) { w = w0; dst = wb + WB_L1; K = 4; lblk = b2; }
      else if (b2 < 384) { w = w1; dst = wb + WB_L2; K = 8; lblk = b2 - 128; }
      else { w = w2; dst = wb + WB_L3; K = 12; lblk = b2 - 384; }
      int q = lblk >> 5, ig = lblk & 31, oc = t;
      union { u16 us[8]; uint4 v; } H, Lo;
#pragma unroll
      for (int e = 0; e < 8; ++e) {
        float v = w[((size_t)oc * 256 + ig * 8 + e) * K + q];
        split_bf16(v, H.us[e], Lo.us[e]);
      }
      size_t d = (size_t)(q * 2) * 65536 + (size_t)ig * 2048 + (size_t)oc * 8;
      *(uint4*)(dst + d) = H.v;
      *(uint4*)(dst + d + 65536) = Lo.v;
    } else {
      int lblk = b2 - 768;
      int kg = lblk & 31, p = lblk >> 5;
      const float* W = p ? jw2 : jw1;
      int n = t;
      union { u16 us[8]; uint4 v; } H, Lo;
#pragma unroll
      for (int e = 0; e < 8; ++e) {
        float v = W[(size_t)(kg * 8 + e) * 256 + n];
        split_bf16(v, H.us[e], Lo.us[e]);
      }
      size_t d = (size_t)(p * 2) * 65536 + ((size_t)kg * 256 + n) * 8;
      *(uint4*)(wj + d) = H.v;
      *(uint4*)(wj + d + 65536) = Lo.v;
    }
  } else {
    // embedding + transpose -> xa (single bf16 plane)
    int lb = blk - 896;                         // pb(3) lt(3) dt(1)
    int dt = lb & 1, lt = (lb >> 1) & 7, pb = lb >> 4;
    int l0 = lt * 32, d0 = dt * 128;
    const int* tok = (pb >> 2) ? t2 : t1;
    int c = t & 127, rq = t >> 7;
#pragma unroll 4
    for (int rr = 0; rr < 16; ++rr) {
      int r = rr * 2 + rq;
      int tv = tok[(pb & 3) * 256 + l0 + r];
      st[r][c] = emb[(size_t)tv * 256 + d0 + c];
    }
    __syncthreads();
    int dloc = t >> 1, lq = t & 1;
    size_t rbase = (size_t)pb * (XROWS * 256) + (size_t)(8 + d0 + dloc) * 256 + l0 + lq * 16;
#pragma unroll
    for (int lh = 0; lh < 4; ++lh) {
      u16 hb[4];
#pragma unroll
      for (int cc = 0; cc < 4; ++cc)
        hb[cc] = to_bf16(st[lq * 16 + lh * 4 + cc][dloc]);
      *(ushort4*)(xa + rbase + lh * 4) = make_ushort4(hb[0], hb[1], hb[2], hb[3]);
    }
  }
}

// ---------------- conv via MFMA (X single bf16 plane, W hi/lo -> 2 MFMAs) ----------------
template <int K, int P, int OUTMODE>
__global__ __launch_bounds__(256, 4) void k_cmf(const u16* __restrict__ xh,
                                                const u16* __restrict__ wb,
                                                const float* __restrict__ bias,
                                                u16* __restrict__ yh,
                                                float* __restrict__ eout,
                                                u16* __restrict__ ebf) {
  __shared__ u16 xs[12480];             // 48 rows x 260 ushorts (24.4 KB)

  int blk = blockIdx.x;                 // pb(3) oct(3) jt(3)
  int jt = blk & 7, oct = (blk >> 3) & 7, pb = blk >> 6;
  int oc0 = oct * 32, j0 = jt * 32;
  int tid = threadIdx.x;
  int lane = tid & 63, wv = tid >> 6;
  int l31 = lane & 31, lhi = lane >> 5;

  {
    const u32* sh = (const u32*)(xh + (size_t)pb * (XROWS * 256) + (size_t)j0 * 256);
    u32* xd = (u32*)xs;
    for (int idx = tid; idx < 3072; idx += 256) {       // 48 rows x 64 x 8B
      int r = idx >> 6, c2 = (idx & 63) * 2;
      *(uint2*)(xd + r * 130 + c2) = *(const uint2*)(sh + (size_t)r * 128 + c2);
    }
  }
  __syncthreads();

  f32x16 acc = {};
  size_t abase = (size_t)(oc0 + l31) * 8 + (size_t)(wv * 8 + lhi) * 2048;
  int ib0 = wv * 64 + 8 * lhi;

  for (int q = 0; q < K; ++q) {
    int jr = l31 + q + (8 - P);
    const u16* bh0 = xs + jr * 260 + ib0;
    size_t aq = (size_t)q * 131072 + abase;
#pragma unroll
    for (int ic = 0; ic < 4; ++ic) {
      s8v ah = *(const s8v*)(wb + aq + ic * 4096);
      s8v al = *(const s8v*)(wb + aq + 65536 + ic * 4096);
      s8v bh = lds16_8al(bh0 + ic * 16);
      acc = __builtin_amdgcn_mfma_f32_32x32x16_bf16(ah, bh, acc, 0, 0, 0);
      acc = __builtin_amdgcn_mfma_f32_32x32x16_bf16(al, bh, acc, 0, 0, 0);
    }
  }

  __syncthreads();
  float* cd = (float*)xs;
  int j = l31;
  if (wv > 0) {
#pragma unroll
    for (int r = 0; r < 16; ++r) {
      int ocr = (r & 3) + 8 * (r >> 2) + 4 * lhi;
      cd[(wv - 1) * 1024 + ocr * 32 + j] = acc[r];
    }
  }
  __syncthreads();
  if (wv == 0) {
#pragma unroll
    for (int r = 0; r < 16; ++r) {
      int ocr = (r & 3) + 8 * (r >> 2) + 4 * lhi;
      int idx = ocr * 32 + j;
      float s = acc[r] + cd[idx] + cd[1024 + idx] + cd[2048 + idx] + bias[oc0 + ocr];
      cd[3072 + ocr * 33 + j] = fmaxf(s, 0.0f);
    }
  }
  __syncthreads();

  if constexpr (OUTMODE == 0) {
    int jj = tid & 31, oq = tid >> 5;
    u16 hb[4];
#pragma unroll
    for (int c2 = 0; c2 < 4; ++c2)
      hb[c2] = to_bf16(cd[3072 + (oq * 4 + c2) * 33 + jj]);
    size_t ro = (size_t)pb * (XROWS * 256) + (size_t)(8 + j0 + jj) * 256 + oc0 + oq * 4;
    *(ushort4*)(yh + ro) = make_ushort4(hb[0], hb[1], hb[2], hb[3]);
  } else {
    int jj = tid & 31, oq = tid >> 5;
#pragma unroll
    for (int c2 = 0; c2 < 4; ++c2)
      eout[(size_t)pb * 65536 + (size_t)(oc0 + oq * 4 + c2) * 256 + j0 + jj] =
          cd[3072 + (oq * 4 + c2) * 33 + jj];
    int ocl = tid >> 3, dg = tid & 7;
    u16 hb[4];
#pragma unroll
    for (int c2 = 0; c2 < 4; ++c2)
      hb[c2] = to_bf16(cd[3072 + ocl * 33 + dg * 4 + c2]);
    size_t ro2 = ((size_t)pb * 256 + oc0 + ocl) * 256 + j0 + dg * 4;
    *(ushort4*)(ebf + ro2) = make_ushort4(hb[0], hb[1], hb[2], hb[3]);
  }
}

// ---------------- ja projections: e (bf16) x W (hi/lo) -> 2 MFMAs, q/k bf16 ----------------
__global__ __launch_bounds__(256) void k_jam(const u16* __restrict__ ebf,
                                             const u16* __restrict__ wj,
                                             const float* __restrict__ b1,
                                             const float* __restrict__ b2,
                                             u16* __restrict__ qk) {
  __shared__ float cd[3072 + 1056];
  int blk = blockIdx.x;                 // pb(3) it(3) nt(3)
  int nt = blk & 7, it = (blk >> 3) & 7, pb = blk >> 6;
  int p = pb >> 2;
  int i0 = it * 32, n0 = nt * 32;
  int tid = threadIdx.x, wv = tid >> 6, lane = tid & 63;
  int l31 = lane & 31, lhi = lane >> 5;

  const u16* eh = ebf + ((size_t)pb * 256 + i0 + l31) * 256 + lhi * 8;
  const u16* wjh = wj + (size_t)(p * 2) * 65536;

  f32x16 acc = {};
#pragma unroll
  for (int c = 0; c < 4; ++c) {
    int kc = wv * 4 + c;
    int kg = kc * 2 + lhi;
    s8v ah = *(const s8v*)(eh + kc * 16);
    s8v bh = *(const s8v*)(wjh + ((size_t)kg * 256 + n0 + l31) * 8);
    s8v bl = *(const s8v*)(wjh + 65536 + ((size_t)kg * 256 + n0 + l31) * 8);
    acc = __builtin_amdgcn_mfma_f32_32x32x16_bf16(ah, bh, acc, 0, 0, 0);
    acc = __builtin_amdgcn_mfma_f32_32x32x16_bf16(ah, bl, acc, 0, 0, 0);
  }

  if (wv > 0) {
#pragma unroll
    for (int r = 0; r < 16; ++r) {
      int row = (r & 3) + 8 * (r >> 2) + 4 * lhi;
      cd[(wv - 1) * 1024 + row * 32 + l31] = acc[r];
    }
  }
  __syncthreads();
  if (wv == 0) {
    float bv = (p ? b2 : b1)[n0 + l31];
#pragma unroll
    for (int r = 0; r < 16; ++r) {
      int row = (r & 3) + 8 * (r >> 2) + 4 * lhi;
      int idx = row * 32 + l31;
      cd[3072 + row * 33 + l31] = acc[r] + cd[idx] + cd[1024 + idx] + cd[2048 + idx] + bv;
    }
  }
  __syncthreads();

  int row = tid & 31, c8 = tid >> 5;
  u16 hb[4];
#pragma unroll
  for (int cc = 0; cc < 4; ++cc)
    hb[cc] = to_bf16(cd[3072 + row * 33 + c8 * 4 + cc]);
  size_t ro = ((size_t)pb * 256 + i0 + row) * 256 + n0 + c8 * 4;
  *(ushort4*)(qk + ro) = make_ushort4(hb[0], hb[1], hb[2], hb[3]);
}

// ---------------- scores: q x k (both bf16) -> 1 MFMA per chunk ----------------
__global__ __launch_bounds__(256) void k_scoresm(const u16* __restrict__ qk,
                                                 float* __restrict__ S,
                                                 float* __restrict__ bsums) {
  __shared__ float cd[3072 + 1056];
  int blk = blockIdx.x;                 // b(2) it(3) jt(3)
  int jt = blk & 7, it = (blk >> 3) & 7, b = blk >> 6;
  int i0 = it * 32, j0 = jt * 32;
  int tid = threadIdx.x, wv = tid >> 6, lane = tid & 63;
  int l31 = lane & 31, lhi = lane >> 5;

  const u16* qh = qk + ((size_t)b * 256 + i0 + l31) * 256 + lhi * 8;
  const u16* kh = qk + ((size_t)(4 + b) * 256 + j0 + l31) * 256 + lhi * 8;

  f32x16 acc = {};
#pragma unroll
  for (int c = 0; c < 4; ++c) {
    int kc = wv * 4 + c;
    s8v a = *(const s8v*)(qh + kc * 16);
    s8v bb = *(const s8v*)(kh + kc * 16);
    acc = __builtin_amdgcn_mfma_f32_32x32x16_bf16(a, bb, acc, 0, 0, 0);
  }

  if (wv > 0) {
#pragma unroll
    for (int r = 0; r < 16; ++r) {
      int row = (r & 3) + 8 * (r >> 2) + 4 * lhi;
      cd[(wv - 1) * 1024 + row * 32 + l31] = acc[r];
    }
  }
  __syncthreads();
  if (wv == 0) {
    float psum = 0.0f;
#pragma unroll
    for (int r = 0; r < 16; ++r) {
      int row = (r & 3) + 8 * (r >> 2) + 4 * lhi;
      int idx = row * 32 + l31;
      float s = sig_fast(acc[r] + cd[idx] + cd[1024 + idx] + cd[2048 + idx]);
      psum += s;
      cd[3072 + row * 33 + l31] = s;
    }
    for (int off = 32; off; off >>= 1) psum += __shfl_down(psum, off, 64);
    if (lane == 0) bsums[blk] = psum;
  }
  __syncthreads();

  int row = tid & 31, c8 = tid >> 5;
  float4 v;
  v.x = cd[3072 + row * 33 + c8 * 4 + 0];
  v.y = cd[3072 + row * 33 + c8 * 4 + 1];
  v.z = cd[3072 + row * 33 + c8 * 4 + 2];
  v.w = cd[3072 + row * 33 + c8 * 4 + 3];
  *(float4*)(S + ((size_t)b * 256 + i0 + row) * 256 + j0 + c8 * 4) = v;
}

// ---------------- normalize raw S -> inter output ----------------
__global__ __launch_bounds__(256) void k_norm(const float* __restrict__ S,
                                              const float* __restrict__ bsums,
                                              float* __restrict__ inter_out) {
  int blk = blockIdx.x;                 // 256 blocks x 1024 floats, b = blk>>6
  int b = blk >> 6;
  __shared__ float inv_s;
  int t = threadIdx.x;
  if (t < 64) {
    float v = bsums[b * 64 + t];
    for (int off = 32; off; off >>= 1) v += __shfl_down(v, off, 64);
    if (t == 0) inv_s = 1.0f / v;
  }
  __syncthreads();
  float inv = inv_s;
  size_t base = (size_t)blk * 1024 + (size_t)t * 4;
  float4 v = *(const float4*)(S + base);
  v.x *= inv; v.y *= inv; v.z *= inv; v.w *= inv;
  *(float4*)(inter_out + base) = v;
}

// ---------------- bilinear tanh pooling from raw S ----------------
__global__ __launch_bounds__(256) void k_pool(const float* __restrict__ e1,
                                              const float* __restrict__ e2,
                                              const float* __restrict__ S,
                                              const float* __restrict__ bsums,
                                              float* __restrict__ pp) {
  int blk = blockIdx.x;                 // b(2) ich(5) kch(4)
  int kch = blk & 15, ich = (blk >> 4) & 31, b = blk >> 9;
  int d = threadIdx.x, i0 = ich * 8, k0 = kch * 16;
  __shared__ float s2[16][8];           // [kk][ii] = 2*s_raw
  __shared__ float red[128];
  __shared__ float ssp_s, tot_s;
  int t = threadIdx.x;
  if (t < 64) {
    float v = bsums[b * 64 + t];
    for (int off = 32; off; off >>= 1) v += __shfl_down(v, off, 64);
    if (t == 0) tot_s = v;
  }
  if (t < 128) {
    int ii = t >> 4, kk = t & 15;
    float v = S[((size_t)(b * 256 + i0 + ii)) * 256 + k0 + kk];
    s2[kk][ii] = 2.0f * v;
    red[t] = v;
  }
  __syncthreads();
  for (int st = 64; st; st >>= 1) {
    if (t < st) red[t] += red[t + st];
    __syncthreads();
  }
  if (t == 0) ssp_s = red[0];
  __syncthreads();

  constexpr float C2L = 2.8853900817779268f;   // 2*log2(e)
  float ev2[8];
#pragma unroll
  for (int ii = 0; ii < 8; ++ii)
    ev2[ii] = e1[((size_t)(b * L + i0 + ii)) * D + d] * C2L;

  float a0 = 0.f, a1 = 0.f, a2 = 0.f, a3 = 0.f;
  for (int kk = 0; kk < 16; ++kk) {
    float e2v = e2[((size_t)(b * L + k0 + kk)) * D + d];
    float s2r[8];
    *(float4*)&s2r[0] = *(const float4*)&s2[kk][0];
    *(float4*)&s2r[4] = *(const float4*)&s2[kk][4];
#pragma unroll
    for (int ii = 0; ii < 8; ++ii) {
      float r = __builtin_amdgcn_rcpf(__builtin_exp2f(ev2[ii] * e2v) + 1.0f);
      if ((ii & 3) == 0) a0 = fmaf(r, s2r[ii], a0);
      else if ((ii & 3) == 1) a1 = fmaf(r, s2r[ii], a1);
      else if ((ii & 3) == 2) a2 = fmaf(r, s2r[ii], a2);
      else a3 = fmaf(r, s2r[ii], a3);
    }
  }
  float res = (ssp_s - (a0 + a1 + a2 + a3)) * (1.0f / tot_s);
  pp[(((size_t)b * 32 + ich) * 16 + kch) * 256 + d] = res;
}

__global__ __launch_bounds__(256) void k_poolcomb(const float* __restrict__ pp,
                                                  float* __restrict__ pooled) {
  int blk = blockIdx.x;                 // b(2) dt(3)
  int dt = blk & 7, b = blk >> 3;
  int t = threadIdx.x, dl = t & 31, mg = t >> 5;
  int d = dt * 32 + dl;
  float s = 0.f;
#pragma unroll
  for (int m = 0; m < 64; ++m)
    s += pp[((size_t)b * 512 + mg * 64 + m) * 256 + d];
  __shared__ float red[8][32];
  red[mg][dl] = s;
  __syncthreads();
  if (mg == 0) {
    float tot = red[0][dl] + red[1][dl] + red[2][dl] + red[3][dl] +
                red[4][dl] + red[5][dl] + red[6][dl] + red[7][dl];
    pooled[b * 256 + d] = tot;
  }
}

// ---------------- head: conv(stride2) + lrelu + maxpool4 ----------------
__global__ __launch_bounds__(256) void k_head1(const float* __restrict__ pooled,
                                               const float* __restrict__ rcw,
                                               const float* __restrict__ rcb,
                                               float* __restrict__ h) {
  int ms = blockIdx.x;                  // 0..7
  __shared__ float spb[4][258];
  int t = threadIdx.x;
#pragma unroll
  for (int s = 0; s < 4; ++s) {
    int idx = s * 256 + t;
    spb[idx >> 8][(idx & 255) + 1] = pooled[idx];
  }
  if (t < 4) { spb[t][0] = 0.0f; spb[t][257] = 0.0f; }
  __syncthreads();
  int b = t >> 6, c = t & 63;
  float w0 = rcw[c * 4 + 0], w1 = rcw[c * 4 + 1], w2 = rcw[c * 4 + 2], w3 = rcw[c * 4 + 3];
  float bias = rcb[c];
#pragma unroll
  for (int mm = 0; mm < 4; ++mm) {
    int m = ms * 4 + mm;
    float mx = -1e30f;
#pragma unroll
    for (int r = 0; r < 4; ++r) {
      int p2 = 2 * (4 * m + r);
      float y = bias;
      y = fmaf(w0, spb[b][p2], y);
      y = fmaf(w1, spb[b][p2 + 1], y);
      y = fmaf(w2, spb[b][p2 + 2], y);
      y = fmaf(w3, spb[b][p2 + 3], y);
      mx = fmaxf(mx, lrelu(y));
    }
    h[(size_t)(b * 64 + c) * 32 + m] = mx;
  }
}

// ---------------- fc layers ----------------
__global__ __launch_bounds__(256) void k_fc1(const float* __restrict__ h,
                                             const float* __restrict__ w,
                                             float* __restrict__ f1p) {
  int blk = blockIdx.x;
  int ich = blk & 31, ot = blk >> 5;
  int t = threadIdx.x, ol = t & 63, b = t >> 6;
  int o = ot * 64 + ol;
  int oc_ = o < 600 ? o : 599;
  const float* hb = h + (size_t)b * 2048 + ich * 64;
  const float* wb = w + (size_t)(ich * 64) * 600 + oc_;
  float a0 = 0.f, a1 = 0.f, a2 = 0.f, a3 = 0.f;
#pragma unroll 4
  for (int i = 0; i < 64; i += 4) {
    a0 = fmaf(hb[i], wb[(size_t)i * 600], a0);
    a1 = fmaf(hb[i + 1], wb[(size_t)(i + 1) * 600], a1);
    a2 = fmaf(hb[i + 2], wb[(size_t)(i + 2) * 600], a2);
    a3 = fmaf(hb[i + 3], wb[(size_t)(i + 3) * 600], a3);
  }
  if (o < 600) f1p[((size_t)ich * 4 + b) * 600 + o] = a0 + a1 + a2 + a3;
}

__global__ __launch_bounds__(256) void k_fc2(const float* __restrict__ f1p,
                                             const float* __restrict__ fc1b,
                                             const float* __restrict__ w,
                                             float* __restrict__ f2p) {
  int blk = blockIdx.x;
  int is = blk & 7, ot = blk >> 3;
  __shared__ float h1s[4][76];
  int t = threadIdx.x;
  for (int e = t; e < 300; e += 256) {
    int bb = e / 75, ii = e % 75;
    int i = is * 75 + ii;
    float s = fc1b[i];
#pragma unroll
    for (int ich = 0; ich < 32; ++ich) s += f1p[((size_t)ich * 4 + bb) * 600 + i];
    h1s[bb][ii] = lrelu(s);
  }
  __syncthreads();
  int ol = t & 63, b = t >> 6;
  int o = ot * 64 + ol, oc_ = o < 300 ? o : 299;
  const float* wb = w + (size_t)(is * 75) * 300 + oc_;
  float a0 = 0.f, a1 = 0.f, a2 = 0.f;
#pragma unroll 5
  for (int ii = 0; ii < 75; ii += 3) {
    a0 = fmaf(h1s[b][ii], wb[(size_t)ii * 300], a0);
    a1 = fmaf(h1s[b][ii + 1], wb[(size_t)(ii + 1) * 300], a1);
    a2 = fmaf(h1s[b][ii + 2], wb[(size_t)(ii + 2) * 300], a2);
  }
  if (o < 300) f2p[((size_t)is * 4 + b) * 300 + o] = a0 + a1 + a2;
}

__global__ __launch_bounds__(1024) void k_fc3f(const float* __restrict__ f2p,
                                               const float* __restrict__ fc2b,
                                               const float* __restrict__ w3,
                                               const float* __restrict__ fc3b,
                                               float* __restrict__ out) {
  __shared__ float h2s[4][304];
  int t = threadIdx.x;
  for (int e = t; e < 1200; e += 1024) {
    int o = e % 300, b = e / 300;
    float s = fc2b[o];
#pragma unroll
    for (int is = 0; is < 8; ++is) s += f2p[((size_t)is * 4 + b) * 300 + o];
    h2s[b][o] = lrelu(s);
  }
  __syncthreads();
  int wv = t >> 6, l = t & 63;
  if (wv < 4) {
    float s = 0.f;
#pragma unroll
    for (int m = 0; m < 5; ++m) {
      int i = m * 64 + l;
      if (i < 300) s = fmaf(h2s[wv][i], w3[i], s);
    }
    for (int off = 32; off; off >>= 1) s += __shfl_down(s, off, 64);
    if (l == 0) out[262144 + wv] = s + fc3b[0];
  }
}

extern "C" void kernel_launch(void* const* d_in, const int* in_sizes, int n_in,
                              void* d_out, int out_size, void* d_ws, size_t ws_size,
                              hipStream_t stream) {
  float* ws = (float*)d_ws;
  const int* p1 = (const int*)d_in[0];
  const int* p2 = (const int*)d_in[1];
  const float* emb  = (const float*)d_in[2];
  const float* w0   = (const float*)d_in[3];
  const float* b0   = (const float*)d_in[4];
  const float* w1   = (const float*)d_in[5];
  const float* b1   = (const float*)d_in[6];
  const float* w2   = (const float*)d_in[7];
  const float* b2   = (const float*)d_in[8];
  const float* ja1w = (const float*)d_in[9];
  const float* ja1b = (const float*)d_in[10];
  const float* ja2w = (const float*)d_in[11];
  const float* ja2b = (const float*)d_in[12];
  const float* rcw  = (const float*)d_in[13];
  const float* rcb  = (const float*)d_in[14];
  const float* fc1w = (const float*)d_in[15];
  const float* fc1b = (const float*)d_in[16];
  const float* fc2w = (const float*)d_in[17];
  const float* fc2b = (const float*)d_in[18];
  const float* fc3w = (const float*)d_in[19];
  const float* fc3b = (const float*)d_in[20];
  float* out = (float*)d_out;

  u16* xa  = (u16*)(ws + OFF_XA);
  u16* xb  = (u16*)(ws + OFF_XB);
  u16* wbu = (u16*)(ws + OFF_WB);
  u16* wju = (u16*)(ws + OFF_WJ);
  u16* ebf = (u16*)(ws + OFF_EBF);
  u16* qk  = (u16*)(ws + OFF_QK);

  k_prepall<<<1024, 256, 0, stream>>>(p1, p2, emb, w0, w1, w2, ja1w, ja2w, xa, xb, wbu, wju);

  k_cmf<4, 1, 0><<<512, 256, 0, stream>>>(xa, wbu + WB_L1, b0, xb, nullptr, nullptr);
  k_cmf<8, 3, 0><<<512, 256, 0, stream>>>(xb, wbu + WB_L2, b1, xa, nullptr, nullptr);
  k_cmf<12, 5, 1><<<512, 256, 0, stream>>>(xa, wbu + WB_L3, b2, nullptr, ws + OFF_E, ebf);

  k_jam<<<512, 256, 0, stream>>>(ebf, wju, ja1b, ja2b, qk);
  k_scoresm<<<256, 256, 0, stream>>>(qk, ws + OFF_S, ws + OFF_BS);
  k_norm<<<256, 256, 0, stream>>>(ws + OFF_S, ws + OFF_BS, out);

  k_pool<<<2048, 256, 0, stream>>>(ws + OFF_E, ws + OFF_E + SZ, ws + OFF_S, ws + OFF_BS,
                                   ws + OFF_PP);
  k_poolcomb<<<32, 256, 0, stream>>>(ws + OFF_PP, ws + OFF_POOL);

  k_head1<<<8, 256, 0, stream>>>(ws + OFF_POOL, rcw, rcb, ws + OFF_H);
  k_fc1<<<320, 256, 0, stream>>>(ws + OFF_H, fc1w, ws + OFF_F1P);
  k_fc2<<<40, 256, 0, stream>>>(ws + OFF_F1P, fc1b, fc2w, ws + OFF_F2P);
  k_fc3f<<<1, 1024, 0, stream>>>(ws + OFF_F2P, fc2b, fc3w, fc3b, out);
}

// Round 9
// 98.141 us; speedup vs baseline: 5.0172x; 1.0306x over previous
//
#include <hip/hip_runtime.h>
#include <hip/hip_bf16.h>

typedef unsigned short u16;
typedef unsigned int u32;
typedef short s8v __attribute__((ext_vector_type(8)));      // 8 bf16 bit-patterns
typedef float f32x16 __attribute__((ext_vector_type(16)));

constexpr int B = 4, L = 256, D = 256;
constexpr size_t SZ = (size_t)B * L * D;          // 262144

// Xt (transposed, padded): rows = spatial(-8..263) -> 272, cols = channel 0..255
constexpr int XROWS = 272;
constexpr size_t XT_PLANE = (size_t)8 * XROWS * 256;   // ushorts = 557056 (278528 floats)

// workspace offsets (floats)
constexpr size_t OFF_E    = 0;                        // 2*SZ fp32 e
constexpr size_t OFF_S    = 2 * SZ;                   // 262144 (raw sigmoid)
constexpr size_t OFF_EBF  = 3 * SZ;                   // 262144 (single bf16 plane, 8 pb)
constexpr size_t OFF_XA   = 4 * SZ;                   // 278528
constexpr size_t OFF_XB   = OFF_XA + 278528;          // 278528
constexpr size_t OFF_WB   = OFF_XB + 278528;          // 1572864 (hi/lo conv weights)
constexpr size_t OFF_WJ   = OFF_WB + 1572864;         // 131072 (hi/lo ja weights)
constexpr size_t OFF_QK   = OFF_WJ + 131072;          // 262144 (q,k single plane)
constexpr size_t OFF_BS   = OFF_QK + 262144;          // 256
constexpr size_t OFF_PP   = OFF_BS + 256;             // 524288
constexpr size_t OFF_POOL = OFF_PP + 524288;          // 1024
constexpr size_t OFF_H    = OFF_POOL + 1024;          // 8192
constexpr size_t OFF_F1P  = OFF_H + 8192;             // 76800
constexpr size_t OFF_F2P  = OFF_F1P + 76800;          // 9600

// Wb layer offsets in ushorts
constexpr size_t WB_L1 = 0;
constexpr size_t WB_L2 = (size_t)4 * 2 * 65536;
constexpr size_t WB_L3 = WB_L2 + (size_t)8 * 2 * 65536;

__device__ __forceinline__ float sig_fast(float x) {
  return __fdividef(1.0f, 1.0f + __expf(-x));
}
__device__ __forceinline__ float lrelu(float x) { return x >= 0.0f ? x : 0.1f * x; }

__device__ __forceinline__ void split_bf16(float v, u16& h, u16& l) {
  __bf16 hb = (__bf16)v;
  float hf = (float)hb;
  __bf16 lb = (__bf16)(v - hf);
  h = __builtin_bit_cast(u16, hb);
  l = __builtin_bit_cast(u16, lb);
}
__device__ __forceinline__ u16 to_bf16(float v) {
  return __builtin_bit_cast(u16, (__bf16)v);
}

__device__ __forceinline__ s8v lds16_8al(const u16* p) {   // 16B from LDS, 8B-aligned
  union { uint2 u[2]; s8v v; } r;
  r.u[0] = *(const uint2*)p;
  r.u[1] = *(const uint2*)(p + 4);
  return r.v;
}

// ---------------- fused prep: pad-zero + weight prep + embed/transpose ----------------
__global__ __launch_bounds__(256) void k_prepall(const int* __restrict__ t1,
                                                 const int* __restrict__ t2,
                                                 const float* __restrict__ emb,
                                                 const float* __restrict__ w0,
                                                 const float* __restrict__ w1,
                                                 const float* __restrict__ w2,
                                                 const float* __restrict__ jw1,
                                                 const float* __restrict__ jw2,
                                                 u16* __restrict__ xa,
                                                 u16* __restrict__ xb,
                                                 u16* __restrict__ wb,
                                                 u16* __restrict__ wj) {
  __shared__ float st[32][129];
  int blk = blockIdx.x;
  int t = threadIdx.x;
  if (blk < 64) {
    int gid = blk * 256 + t;                    // 0..16383
    int plane = gid >> 13, rem = gid & 8191;
    int pb = rem >> 10, rem2 = rem & 1023;
    int row16 = rem2 >> 6, cc = rem2 & 63;
    int row = row16 < 8 ? row16 : 256 + row16;
    u16* dst = plane ? xb : xa;
    *(ushort4*)(dst + (size_t)pb * (XROWS * 256) + (size_t)row * 256 + cc * 4) =
        make_ushort4(0, 0, 0, 0);
  } else if (blk < 896) {
    int b2 = blk - 64;                          // 0..831
    if (b2 < 768) {
      const float* w; u16* dst; int K, lblk;
      if (b2 < 128) { w = w0; dst = wb + WB_L1; K = 4; lblk = b2; }
      else if (b2 < 384) { w = w1; dst = wb + WB_L2; K = 8; lblk = b2 - 128; }
      else { w = w2; dst = wb + WB_L3; K = 12; lblk = b2 - 384; }
      int q = lblk >> 5, ig = lblk & 31, oc = t;
      union { u16 us[8]; uint4 v; } H, Lo;
#pragma unroll
      for (int e = 0; e < 8; ++e) {
        float v = w[((size_t)oc * 256 + ig * 8 + e) * K + q];
        split_bf16(v, H.us[e], Lo.us[e]);
      }
      size_t d = (size_t)(q * 2) * 65536 + (size_t)ig * 2048 + (size_t)oc * 8;
      *(uint4*)(dst + d) = H.v;
      *(uint4*)(dst + d + 65536) = Lo.v;
    } else {
      int lblk = b2 - 768;
      int kg = lblk & 31, p = lblk >> 5;
      const float* W = p ? jw2 : jw1;
      int n = t;
      union { u16 us[8]; uint4 v; } H, Lo;
#pragma unroll
      for (int e = 0; e < 8; ++e) {
        float v = W[(size_t)(kg * 8 + e) * 256 + n];
        split_bf16(v, H.us[e], Lo.us[e]);
      }
      size_t d = (size_t)(p * 2) * 65536 + ((size_t)kg * 256 + n) * 8;
      *(uint4*)(wj + d) = H.v;
      *(uint4*)(wj + d + 65536) = Lo.v;
    }
  } else {
    // embedding + transpose -> xa (single bf16 plane)
    int lb = blk - 896;                         // pb(3) lt(3) dt(1)
    int dt = lb & 1, lt = (lb >> 1) & 7, pb = lb >> 4;
    int l0 = lt * 32, d0 = dt * 128;
    const int* tok = (pb >> 2) ? t2 : t1;
    int c = t & 127, rq = t >> 7;
#pragma unroll 4
    for (int rr = 0; rr < 16; ++rr) {
      int r = rr * 2 + rq;
      int tv = tok[(pb & 3) * 256 + l0 + r];
      st[r][c] = emb[(size_t)tv * 256 + d0 + c];
    }
    __syncthreads();
    int dloc = t >> 1, lq = t & 1;
    size_t rbase = (size_t)pb * (XROWS * 256) + (size_t)(8 + d0 + dloc) * 256 + l0 + lq * 16;
#pragma unroll
    for (int lh = 0; lh < 4; ++lh) {
      u16 hb[4];
#pragma unroll
      for (int cc = 0; cc < 4; ++cc)
        hb[cc] = to_bf16(st[lq * 16 + lh * 4 + cc][dloc]);
      *(ushort4*)(xa + rbase + lh * 4) = make_ushort4(hb[0], hb[1], hb[2], hb[3]);
    }
  }
}

// ---------------- conv via MFMA: wave-private staging, 1-barrier epilogue ----------------
// wave wv stages rows 0..47 x its own i-slice [wv*64, wv*64+64) into a private LDS
// region (stride 68 u16 -> 2-way bank aliasing, free); no block barrier until the
// cross-wave accumulator reduce.
template <int K, int P, int OUTMODE>
__global__ __launch_bounds__(256, 2) void k_cmf(const u16* __restrict__ xh,
                                                const u16* __restrict__ wb,
                                                const float* __restrict__ bias,
                                                u16* __restrict__ yh,
                                                float* __restrict__ eout,
                                                u16* __restrict__ ebf) {
  __shared__ u16 xsl[4 * 3264];         // 4 waves x 48 rows x 68 u16 = 25.5 KB
  __shared__ float cd[3072];            // waves 1..3 partials

  int blk = blockIdx.x;                 // pb(3) oct(3) jt(3)
  int jt = blk & 7, oct = (blk >> 3) & 7, pb = blk >> 6;
  int oc0 = oct * 32, j0 = jt * 32;
  int tid = threadIdx.x;
  int lane = tid & 63, wv = tid >> 6;
  int l31 = lane & 31, lhi = lane >> 5;

  // wave-private staging
  {
    const u16* src = xh + (size_t)pb * (XROWS * 256) + (size_t)j0 * 256 + wv * 64;
    u16* dst = xsl + wv * 3264;
#pragma unroll
    for (int it2 = 0; it2 < 12; ++it2) {
      int e = it2 * 64 + lane;
      int r = e >> 4, c4 = (e & 15) * 4;
      *(uint2*)(dst + r * 68 + c4) = *(const uint2*)(src + (size_t)r * 256 + c4);
    }
  }
  asm volatile("s_waitcnt lgkmcnt(0)" ::: "memory");
  __builtin_amdgcn_sched_barrier(0);

  f32x16 acc = {};
  size_t abase = (size_t)(oc0 + l31) * 8 + (size_t)(wv * 8 + lhi) * 2048;
  const u16* wslice = xsl + wv * 3264 + 8 * lhi;

  for (int q = 0; q < K; ++q) {
    int jr = l31 + q + (8 - P);
    const u16* bh0 = wslice + jr * 68;
    size_t aq = (size_t)q * 131072 + abase;
#pragma unroll
    for (int ic = 0; ic < 4; ++ic) {
      s8v ah = *(const s8v*)(wb + aq + ic * 4096);
      s8v al = *(const s8v*)(wb + aq + 65536 + ic * 4096);
      s8v bh = lds16_8al(bh0 + ic * 16);
      acc = __builtin_amdgcn_mfma_f32_32x32x16_bf16(ah, bh, acc, 0, 0, 0);
      acc = __builtin_amdgcn_mfma_f32_32x32x16_bf16(al, bh, acc, 0, 0, 0);
    }
  }

  // single-barrier cross-wave reduce; wave 0 writes outputs straight from registers
  if (wv > 0) {
#pragma unroll
    for (int r = 0; r < 16; ++r) {
      int ocr = (r & 3) + 8 * (r >> 2) + 4 * lhi;
      cd[(wv - 1) * 1024 + ocr * 32 + l31] = acc[r];
    }
  }
  __syncthreads();
  if (wv == 0) {
    float v[16];
#pragma unroll
    for (int r = 0; r < 16; ++r) {
      int ocr = (r & 3) + 8 * (r >> 2) + 4 * lhi;
      int idx = ocr * 32 + l31;
      v[r] = fmaxf(acc[r] + cd[idx] + cd[1024 + idx] + cd[2048 + idx] + bias[oc0 + ocr], 0.0f);
    }
    if constexpr (OUTMODE == 0) {
      size_t ro = (size_t)pb * (XROWS * 256) + (size_t)(8 + j0 + l31) * 256 + oc0 + 4 * lhi;
#pragma unroll
      for (int rq = 0; rq < 4; ++rq) {
        *(ushort4*)(yh + ro + 8 * rq) =
            make_ushort4(to_bf16(v[rq * 4 + 0]), to_bf16(v[rq * 4 + 1]),
                         to_bf16(v[rq * 4 + 2]), to_bf16(v[rq * 4 + 3]));
      }
    } else {
#pragma unroll
      for (int r = 0; r < 16; ++r) {
        int ocr = (r & 3) + 8 * (r >> 2) + 4 * lhi;
        size_t eo = (size_t)pb * 65536 + (size_t)(oc0 + ocr) * 256 + j0 + l31;
        eout[eo] = v[r];
        ebf[((size_t)pb * 256 + oc0 + ocr) * 256 + j0 + l31] = to_bf16(v[r]);
      }
    }
  }
}

// ---------------- ja projections: e (bf16) x W (hi/lo) -> 2 MFMAs, q/k bf16 ----------------
__global__ __launch_bounds__(256) void k_jam(const u16* __restrict__ ebf,
                                             const u16* __restrict__ wj,
                                             const float* __restrict__ b1,
                                             const float* __restrict__ b2,
                                             u16* __restrict__ qk) {
  __shared__ float cd[3072 + 1056];
  int blk = blockIdx.x;                 // pb(3) it(3) nt(3)
  int nt = blk & 7, it = (blk >> 3) & 7, pb = blk >> 6;
  int p = pb >> 2;
  int i0 = it * 32, n0 = nt * 32;
  int tid = threadIdx.x, wv = tid >> 6, lane = tid & 63;
  int l31 = lane & 31, lhi = lane >> 5;

  const u16* eh = ebf + ((size_t)pb * 256 + i0 + l31) * 256 + lhi * 8;
  const u16* wjh = wj + (size_t)(p * 2) * 65536;

  f32x16 acc = {};
#pragma unroll
  for (int c = 0; c < 4; ++c) {
    int kc = wv * 4 + c;
    int kg = kc * 2 + lhi;
    s8v ah = *(const s8v*)(eh + kc * 16);
    s8v bh = *(const s8v*)(wjh + ((size_t)kg * 256 + n0 + l31) * 8);
    s8v bl = *(const s8v*)(wjh + 65536 + ((size_t)kg * 256 + n0 + l31) * 8);
    acc = __builtin_amdgcn_mfma_f32_32x32x16_bf16(ah, bh, acc, 0, 0, 0);
    acc = __builtin_amdgcn_mfma_f32_32x32x16_bf16(ah, bl, acc, 0, 0, 0);
  }

  if (wv > 0) {
#pragma unroll
    for (int r = 0; r < 16; ++r) {
      int row = (r & 3) + 8 * (r >> 2) + 4 * lhi;
      cd[(wv - 1) * 1024 + row * 32 + l31] = acc[r];
    }
  }
  __syncthreads();
  if (wv == 0) {
    float bv = (p ? b2 : b1)[n0 + l31];
#pragma unroll
    for (int r = 0; r < 16; ++r) {
      int row = (r & 3) + 8 * (r >> 2) + 4 * lhi;
      int idx = row * 32 + l31;
      cd[3072 + row * 33 + l31] = acc[r] + cd[idx] + cd[1024 + idx] + cd[2048 + idx] + bv;
    }
  }
  __syncthreads();

  int row = tid & 31, c8 = tid >> 5;
  u16 hb[4];
#pragma unroll
  for (int cc = 0; cc < 4; ++cc)
    hb[cc] = to_bf16(cd[3072 + row * 33 + c8 * 4 + cc]);
  size_t ro = ((size_t)pb * 256 + i0 + row) * 256 + n0 + c8 * 4;
  *(ushort4*)(qk + ro) = make_ushort4(hb[0], hb[1], hb[2], hb[3]);
}

// ---------------- scores: q x k (both bf16) -> 1 MFMA per chunk ----------------
__global__ __launch_bounds__(256) void k_scoresm(const u16* __restrict__ qk,
                                                 float* __restrict__ S,
                                                 float* __restrict__ bsums) {
  __shared__ float cd[3072 + 1056];
  int blk = blockIdx.x;                 // b(2) it(3) jt(3)
  int jt = blk & 7, it = (blk >> 3) & 7, b = blk >> 6;
  int i0 = it * 32, j0 = jt * 32;
  int tid = threadIdx.x, wv = tid >> 6, lane = tid & 63;
  int l31 = lane & 31, lhi = lane >> 5;

  const u16* qh = qk + ((size_t)b * 256 + i0 + l31) * 256 + lhi * 8;
  const u16* kh = qk + ((size_t)(4 + b) * 256 + j0 + l31) * 256 + lhi * 8;

  f32x16 acc = {};
#pragma unroll
  for (int c = 0; c < 4; ++c) {
    int kc = wv * 4 + c;
    s8v a = *(const s8v*)(qh + kc * 16);
    s8v bb = *(const s8v*)(kh + kc * 16);
    acc = __builtin_amdgcn_mfma_f32_32x32x16_bf16(a, bb, acc, 0, 0, 0);
  }

  if (wv > 0) {
#pragma unroll
    for (int r = 0; r < 16; ++r) {
      int row = (r & 3) + 8 * (r >> 2) + 4 * lhi;
      cd[(wv - 1) * 1024 + row * 32 + l31] = acc[r];
    }
  }
  __syncthreads();
  if (wv == 0) {
    float psum = 0.0f;
#pragma unroll
    for (int r = 0; r < 16; ++r) {
      int row = (r & 3) + 8 * (r >> 2) + 4 * lhi;
      int idx = row * 32 + l31;
      float s = sig_fast(acc[r] + cd[idx] + cd[1024 + idx] + cd[2048 + idx]);
      psum += s;
      cd[3072 + row * 33 + l31] = s;
    }
    for (int off = 32; off; off >>= 1) psum += __shfl_down(psum, off, 64);
    if (lane == 0) bsums[blk] = psum;
  }
  __syncthreads();

  int row = tid & 31, c8 = tid >> 5;
  float4 v;
  v.x = cd[3072 + row * 33 + c8 * 4 + 0];
  v.y = cd[3072 + row * 33 + c8 * 4 + 1];
  v.z = cd[3072 + row * 33 + c8 * 4 + 2];
  v.w = cd[3072 + row * 33 + c8 * 4 + 3];
  *(float4*)(S + ((size_t)b * 256 + i0 + row) * 256 + j0 + c8 * 4) = v;
}

// ---------------- bilinear tanh pooling from raw S (+ writes normalized inter) --------
__global__ __launch_bounds__(256) void k_pool(const float* __restrict__ e1,
                                              const float* __restrict__ e2,
                                              const float* __restrict__ S,
                                              const float* __restrict__ bsums,
                                              float* __restrict__ inter_out,
                                              float* __restrict__ pp) {
  int blk = blockIdx.x;                 // b(2) ich(5) kch(4)
  int kch = blk & 15, ich = (blk >> 4) & 31, b = blk >> 9;
  int d = threadIdx.x, i0 = ich * 8, k0 = kch * 16;
  __shared__ float s2[16][8];           // [kk][ii] = 2*s_raw
  __shared__ float red[128];
  __shared__ float ssp_s, tot_s;
  int t = threadIdx.x;
  int ii = t >> 4, kk = t & 15;
  float sv = 0.0f;
  if (t < 64) {
    float v = bsums[b * 64 + t];
    for (int off = 32; off; off >>= 1) v += __shfl_down(v, off, 64);
    if (t == 0) tot_s = v;
  }
  if (t < 128) {
    sv = S[((size_t)(b * 256 + i0 + ii)) * 256 + k0 + kk];
    s2[kk][ii] = 2.0f * sv;
    red[t] = sv;
  }
  __syncthreads();
  for (int st = 64; st; st >>= 1) {
    if (t < st) red[t] += red[t + st];
    __syncthreads();
  }
  if (t == 0) ssp_s = red[0];
  __syncthreads();

  float invt = 1.0f / tot_s;
  if (t < 128)
    inter_out[((size_t)(b * 256 + i0 + ii)) * 256 + k0 + kk] = sv * invt;

  constexpr float C2L = 2.8853900817779268f;   // 2*log2(e)
  float ev2[8];
#pragma unroll
  for (int i2 = 0; i2 < 8; ++i2)
    ev2[i2] = e1[((size_t)(b * L + i0 + i2)) * D + d] * C2L;

  float a0 = 0.f, a1 = 0.f, a2 = 0.f, a3 = 0.f;
  for (int k2 = 0; k2 < 16; ++k2) {
    float e2v = e2[((size_t)(b * L + k0 + k2)) * D + d];
    float s2r[8];
    *(float4*)&s2r[0] = *(const float4*)&s2[k2][0];
    *(float4*)&s2r[4] = *(const float4*)&s2[k2][4];
#pragma unroll
    for (int i2 = 0; i2 < 8; ++i2) {
      float r = __builtin_amdgcn_rcpf(__builtin_exp2f(ev2[i2] * e2v) + 1.0f);
      if ((i2 & 3) == 0) a0 = fmaf(r, s2r[i2], a0);
      else if ((i2 & 3) == 1) a1 = fmaf(r, s2r[i2], a1);
      else if ((i2 & 3) == 2) a2 = fmaf(r, s2r[i2], a2);
      else a3 = fmaf(r, s2r[i2], a3);
    }
  }
  float res = (ssp_s - (a0 + a1 + a2 + a3)) * invt;
  pp[(((size_t)b * 32 + ich) * 16 + kch) * 256 + d] = res;
}

__global__ __launch_bounds__(256) void k_poolcomb(const float* __restrict__ pp,
                                                  float* __restrict__ pooled) {
  int blk = blockIdx.x;                 // b(2) dt(3)
  int dt = blk & 7, b = blk >> 3;
  int t = threadIdx.x, dl = t & 31, mg = t >> 5;
  int d = dt * 32 + dl;
  float s = 0.f;
#pragma unroll
  for (int m = 0; m < 64; ++m)
    s += pp[((size_t)b * 512 + mg * 64 + m) * 256 + d];
  __shared__ float red[8][32];
  red[mg][dl] = s;
  __syncthreads();
  if (mg == 0) {
    float tot = red[0][dl] + red[1][dl] + red[2][dl] + red[3][dl] +
                red[4][dl] + red[5][dl] + red[6][dl] + red[7][dl];
    pooled[b * 256 + d] = tot;
  }
}

// ---------------- head: conv(stride2) + lrelu + maxpool4 ----------------
__global__ __launch_bounds__(256) void k_head1(const float* __restrict__ pooled,
                                               const float* __restrict__ rcw,
                                               const float* __restrict__ rcb,
                                               float* __restrict__ h) {
  int ms = blockIdx.x;                  // 0..7
  __shared__ float spb[4][258];
  int t = threadIdx.x;
#pragma unroll
  for (int s = 0; s < 4; ++s) {
    int idx = s * 256 + t;
    spb[idx >> 8][(idx & 255) + 1] = pooled[idx];
  }
  if (t < 4) { spb[t][0] = 0.0f; spb[t][257] = 0.0f; }
  __syncthreads();
  int b = t >> 6, c = t & 63;
  float w0 = rcw[c * 4 + 0], w1 = rcw[c * 4 + 1], w2 = rcw[c * 4 + 2], w3 = rcw[c * 4 + 3];
  float bias = rcb[c];
#pragma unroll
  for (int mm = 0; mm < 4; ++mm) {
    int m = ms * 4 + mm;
    float mx = -1e30f;
#pragma unroll
    for (int r = 0; r < 4; ++r) {
      int p2 = 2 * (4 * m + r);
      float y = bias;
      y = fmaf(w0, spb[b][p2], y);
      y = fmaf(w1, spb[b][p2 + 1], y);
      y = fmaf(w2, spb[b][p2 + 2], y);
      y = fmaf(w3, spb[b][p2 + 3], y);
      mx = fmaxf(mx, lrelu(y));
    }
    h[(size_t)(b * 64 + c) * 32 + m] = mx;
  }
}

// ---------------- fc layers ----------------
__global__ __launch_bounds__(256) void k_fc1(const float* __restrict__ h,
                                             const float* __restrict__ w,
                                             float* __restrict__ f1p) {
  int blk = blockIdx.x;
  int ich = blk & 31, ot = blk >> 5;
  int t = threadIdx.x, ol = t & 63, b = t >> 6;
  int o = ot * 64 + ol;
  int oc_ = o < 600 ? o : 599;
  const float* hb = h + (size_t)b * 2048 + ich * 64;
  const float* wb = w + (size_t)(ich * 64) * 600 + oc_;
  float a0 = 0.f, a1 = 0.f, a2 = 0.f, a3 = 0.f;
#pragma unroll 4
  for (int i = 0; i < 64; i += 4) {
    a0 = fmaf(hb[i], wb[(size_t)i * 600], a0);
    a1 = fmaf(hb[i + 1], wb[(size_t)(i + 1) * 600], a1);
    a2 = fmaf(hb[i + 2], wb[(size_t)(i + 2) * 600], a2);
    a3 = fmaf(hb[i + 3], wb[(size_t)(i + 3) * 600], a3);
  }
  if (o < 600) f1p[((size_t)ich * 4 + b) * 600 + o] = a0 + a1 + a2 + a3;
}

__global__ __launch_bounds__(256) void k_fc2(const float* __restrict__ f1p,
                                             const float* __restrict__ fc1b,
                                             const float* __restrict__ w,
                                             float* __restrict__ f2p) {
  int blk = blockIdx.x;
  int is = blk & 7, ot = blk >> 3;
  __shared__ float h1s[4][76];
  int t = threadIdx.x;
  for (int e = t; e < 300; e += 256) {
    int bb = e / 75, ii = e % 75;
    int i = is * 75 + ii;
    float s = fc1b[i];
#pragma unroll
    for (int ich = 0; ich < 32; ++ich) s += f1p[((size_t)ich * 4 + bb) * 600 + i];
    h1s[bb][ii] = lrelu(s);
  }
  __syncthreads();
  int ol = t & 63, b = t >> 6;
  int o = ot * 64 + ol, oc_ = o < 300 ? o : 299;
  const float* wb = w + (size_t)(is * 75) * 300 + oc_;
  float a0 = 0.f, a1 = 0.f, a2 = 0.f;
#pragma unroll 5
  for (int ii = 0; ii < 75; ii += 3) {
    a0 = fmaf(h1s[b][ii], wb[(size_t)ii * 300], a0);
    a1 = fmaf(h1s[b][ii + 1], wb[(size_t)(ii + 1) * 300], a1);
    a2 = fmaf(h1s[b][ii + 2], wb[(size_t)(ii + 2) * 300], a2);
  }
  if (o < 300) f2p[((size_t)is * 4 + b) * 300 + o] = a0 + a1 + a2;
}

__global__ __launch_bounds__(1024) void k_fc3f(const float* __restrict__ f2p,
                                               const float* __restrict__ fc2b,
                                               const float* __restrict__ w3,
                                               const float* __restrict__ fc3b,
                                               float* __restrict__ out) {
  __shared__ float h2s[4][304];
  int t = threadIdx.x;
  for (int e = t; e < 1200; e += 1024) {
    int o = e % 300, b = e / 300;
    float s = fc2b[o];
#pragma unroll
    for (int is = 0; is < 8; ++is) s += f2p[((size_t)is * 4 + b) * 300 + o];
    h2s[b][o] = lrelu(s);
  }
  __syncthreads();
  int wv = t >> 6, l = t & 63;
  if (wv < 4) {
    float s = 0.f;
#pragma unroll
    for (int m = 0; m < 5; ++m) {
      int i = m * 64 + l;
      if (i < 300) s = fmaf(h2s[wv][i], w3[i], s);
    }
    for (int off = 32; off; off >>= 1) s += __shfl_down(s, off, 64);
    if (l == 0) out[262144 + wv] = s + fc3b[0];
  }
}

extern "C" void kernel_launch(void* const* d_in, const int* in_sizes, int n_in,
                              void* d_out, int out_size, void* d_ws, size_t ws_size,
                              hipStream_t stream) {
  float* ws = (float*)d_ws;
  const int* p1 = (const int*)d_in[0];
  const int* p2 = (const int*)d_in[1];
  const float* emb  = (const float*)d_in[2];
  const float* w0   = (const float*)d_in[3];
  const float* b0   = (const float*)d_in[4];
  const float* w1   = (const float*)d_in[5];
  const float* b1   = (const float*)d_in[6];
  const float* w2   = (const float*)d_in[7];
  const float* b2   = (const float*)d_in[8];
  const float* ja1w = (const float*)d_in[9];
  const float* ja1b = (const float*)d_in[10];
  const float* ja2w = (const float*)d_in[11];
  const float* ja2b = (const float*)d_in[12];
  const float* rcw  = (const float*)d_in[13];
  const float* rcb  = (const float*)d_in[14];
  const float* fc1w = (const float*)d_in[15];
  const float* fc1b = (const float*)d_in[16];
  const float* fc2w = (const float*)d_in[17];
  const float* fc2b = (const float*)d_in[18];
  const float* fc3w = (const float*)d_in[19];
  const float* fc3b = (const float*)d_in[20];
  float* out = (float*)d_out;

  u16* xa  = (u16*)(ws + OFF_XA);
  u16* xb  = (u16*)(ws + OFF_XB);
  u16* wbu = (u16*)(ws + OFF_WB);
  u16* wju = (u16*)(ws + OFF_WJ);
  u16* ebf = (u16*)(ws + OFF_EBF);
  u16* qk  = (u16*)(ws + OFF_QK);

  k_prepall<<<1024, 256, 0, stream>>>(p1, p2, emb, w0, w1, w2, ja1w, ja2w, xa, xb, wbu, wju);

  k_cmf<4, 1, 0><<<512, 256, 0, stream>>>(xa, wbu + WB_L1, b0, xb, nullptr, nullptr);
  k_cmf<8, 3, 0><<<512, 256, 0, stream>>>(xb, wbu + WB_L2, b1, xa, nullptr, nullptr);
  k_cmf<12, 5, 1><<<512, 256, 0, stream>>>(xa, wbu + WB_L3, b2, nullptr, ws + OFF_E, ebf);

  k_jam<<<512, 256, 0, stream>>>(ebf, wju, ja1b, ja2b, qk);
  k_scoresm<<<256, 256, 0, stream>>>(qk, ws + OFF_S, ws + OFF_BS);

  k_pool<<<2048, 256, 0, stream>>>(ws + OFF_E, ws + OFF_E + SZ, ws + OFF_S, ws + OFF_BS,
                                   out, ws + OFF_PP);
  k_poolcomb<<<32, 256, 0, stream>>>(ws + OFF_PP, ws + OFF_POOL);

  k_head1<<<8, 256, 0, stream>>>(ws + OFF_POOL, rcw, rcb, ws + OFF_H);
  k_fc1<<<320, 256, 0, stream>>>(ws + OFF_H, fc1w, ws + OFF_F1P);
  k_fc2<<<40, 256, 0, stream>>>(ws + OFF_F1P, fc1b, fc2w, ws + OFF_F2P);
  k_fc3f<<<1, 1024, 0, stream>>>(ws + OFF_F2P, fc2b, fc3w, fc3b, out);
}

// Round 10
// 96.408 us; speedup vs baseline: 5.1075x; 1.0180x over previous
//
#include <hip/hip_runtime.h>
#include <hip/hip_bf16.h>

typedef unsigned short u16;
typedef unsigned int u32;
typedef short s8v __attribute__((ext_vector_type(8)));      // 8 bf16 bit-patterns
typedef float f32x16 __attribute__((ext_vector_type(16)));

constexpr int B = 4, L = 256, D = 256;
constexpr size_t SZ = (size_t)B * L * D;          // 262144

// Xt (transposed, padded): rows = spatial(-8..263) -> 272, cols = channel 0..255
constexpr int XROWS = 272;

// workspace offsets (floats)
constexpr size_t OFF_E    = 0;                        // 2*SZ fp32 e
constexpr size_t OFF_S    = 2 * SZ;                   // 262144 (raw sigmoid)
constexpr size_t OFF_EBF  = 3 * SZ;                   // 262144 (bf16 plane, 8 pb)
constexpr size_t OFF_XA   = 4 * SZ;                   // 278528
constexpr size_t OFF_XB   = OFF_XA + 278528;          // 278528
constexpr size_t OFF_WB   = OFF_XB + 278528;          // 786432 (single-plane conv W)
constexpr size_t OFF_WJ   = OFF_WB + 786432;          // 131072 (hi/lo ja weights)
constexpr size_t OFF_QK   = OFF_WJ + 131072;          // 262144
constexpr size_t OFF_BS   = OFF_QK + 262144;          // 256
constexpr size_t OFF_PP   = OFF_BS + 256;             // 524288
constexpr size_t OFF_POOL = OFF_PP + 524288;          // 1024
constexpr size_t OFF_F1P  = OFF_POOL + 1024;          // 76800
constexpr size_t OFF_F2P  = OFF_F1P + 76800;          // 9600

// Wb layer offsets in ushorts (single plane: K q-planes of 65536)
constexpr size_t WB_L1 = 0;
constexpr size_t WB_L2 = (size_t)4 * 65536;           // 262144
constexpr size_t WB_L3 = (size_t)12 * 65536;          // 786432

__device__ __forceinline__ float sig_fast(float x) {
  return __fdividef(1.0f, 1.0f + __expf(-x));
}
__device__ __forceinline__ float lrelu(float x) { return x >= 0.0f ? x : 0.1f * x; }

__device__ __forceinline__ void split_bf16(float v, u16& h, u16& l) {
  __bf16 hb = (__bf16)v;
  float hf = (float)hb;
  __bf16 lb = (__bf16)(v - hf);
  h = __builtin_bit_cast(u16, hb);
  l = __builtin_bit_cast(u16, lb);
}
__device__ __forceinline__ u16 to_bf16(float v) {
  return __builtin_bit_cast(u16, (__bf16)v);
}

// ---------------- fused prep: pad-zero + weight prep + embed/transpose ----------------
__global__ __launch_bounds__(256) void k_prepall(const int* __restrict__ t1,
                                                 const int* __restrict__ t2,
                                                 const float* __restrict__ emb,
                                                 const float* __restrict__ w0,
                                                 const float* __restrict__ w1,
                                                 const float* __restrict__ w2,
                                                 const float* __restrict__ jw1,
                                                 const float* __restrict__ jw2,
                                                 u16* __restrict__ xa,
                                                 u16* __restrict__ xb,
                                                 u16* __restrict__ wb,
                                                 u16* __restrict__ wj) {
  __shared__ float st[32][129];
  int blk = blockIdx.x;
  int t = threadIdx.x;
  if (blk < 64) {
    int gid = blk * 256 + t;                    // 0..16383
    int plane = gid >> 13, rem = gid & 8191;
    int pb = rem >> 10, rem2 = rem & 1023;
    int row16 = rem2 >> 6, cc = rem2 & 63;
    int row = row16 < 8 ? row16 : 256 + row16;
    u16* dst = plane ? xb : xa;
    *(ushort4*)(dst + (size_t)pb * (XROWS * 256) + (size_t)row * 256 + cc * 4) =
        make_ushort4(0, 0, 0, 0);
  } else if (blk < 896) {
    int b2 = blk - 64;                          // 0..831
    if (b2 < 768) {
      const float* w; u16* dst; int K, lblk;
      if (b2 < 128) { w = w0; dst = wb + WB_L1; K = 4; lblk = b2; }
      else if (b2 < 384) { w = w1; dst = wb + WB_L2; K = 8; lblk = b2 - 128; }
      else { w = w2; dst = wb + WB_L3; K = 12; lblk = b2 - 384; }
      int q = lblk >> 5, ig = lblk & 31, oc = t;
      union { u16 us[8]; uint4 v; } H;
#pragma unroll
      for (int e = 0; e < 8; ++e)
        H.us[e] = to_bf16(w[((size_t)oc * 256 + ig * 8 + e) * K + q]);
      *(uint4*)(dst + (size_t)q * 65536 + (size_t)ig * 2048 + (size_t)oc * 8) = H.v;
    } else {
      int lblk = b2 - 768;
      int kg = lblk & 31, p = lblk >> 5;
      const float* W = p ? jw2 : jw1;
      int n = t;
      union { u16 us[8]; uint4 v; } H, Lo;
#pragma unroll
      for (int e = 0; e < 8; ++e) {
        float v = W[(size_t)(kg * 8 + e) * 256 + n];
        split_bf16(v, H.us[e], Lo.us[e]);
      }
      size_t d = (size_t)(p * 2) * 65536 + ((size_t)kg * 256 + n) * 8;
      *(uint4*)(wj + d) = H.v;
      *(uint4*)(wj + d + 65536) = Lo.v;
    }
  } else {
    // embedding + transpose -> xa (single bf16 plane)
    int lb = blk - 896;                         // pb(3) lt(3) dt(1)
    int dt = lb & 1, lt = (lb >> 1) & 7, pb = lb >> 4;
    int l0 = lt * 32, d0 = dt * 128;
    const int* tok = (pb >> 2) ? t2 : t1;
    int c = t & 127, rq = t >> 7;
#pragma unroll 4
    for (int rr = 0; rr < 16; ++rr) {
      int r = rr * 2 + rq;
      int tv = tok[(pb & 3) * 256 + l0 + r];
      st[r][c] = emb[(size_t)tv * 256 + d0 + c];
    }
    __syncthreads();
    int dloc = t >> 1, lq = t & 1;
    size_t rbase = (size_t)pb * (XROWS * 256) + (size_t)(8 + d0 + dloc) * 256 + l0 + lq * 16;
#pragma unroll
    for (int lh = 0; lh < 4; ++lh) {
      u16 hb[4];
#pragma unroll
      for (int cc = 0; cc < 4; ++cc)
        hb[cc] = to_bf16(st[lq * 16 + lh * 4 + cc][dloc]);
      *(ushort4*)(xa + rbase + lh * 4) = make_ushort4(hb[0], hb[1], hb[2], hb[3]);
    }
  }
}

// ---------------- conv via MFMA: direct-global B, single-bf16 W, 1-barrier ----------------
template <int K, int P, int OUTMODE>
__global__ __launch_bounds__(256) void k_cmf(const u16* __restrict__ xh,
                                             const u16* __restrict__ wb,
                                             const float* __restrict__ bias,
                                             u16* __restrict__ yh,
                                             float* __restrict__ eout,
                                             u16* __restrict__ ebf) {
  __shared__ float cd[3072];            // waves 1..3 partials (12 KB)

  int blk = blockIdx.x;                 // pb(3) oct(3) jt(3)
  int jt = blk & 7, oct = (blk >> 3) & 7, pb = blk >> 6;
  int oc0 = oct * 32, j0 = jt * 32;
  int tid = threadIdx.x;
  int lane = tid & 63, wv = tid >> 6;
  int l31 = lane & 31, lhi = lane >> 5;

  f32x16 acc = {};
  size_t abase = (size_t)(oc0 + l31) * 8 + (size_t)(wv * 8 + lhi) * 2048;
  // B row for q=0: padded row j0 + l31 + 8 - P, i-offset = wv*64 + lhi*8
  const u16* brow = xh + (size_t)pb * (XROWS * 256) +
                    (size_t)(j0 + l31 + 8 - P) * 256 + wv * 64 + lhi * 8;

  for (int q = 0; q < K; ++q) {
    const u16* bsrc = brow + (size_t)q * 256;
    size_t aq = (size_t)q * 65536 + abase;
#pragma unroll
    for (int ic = 0; ic < 4; ++ic) {
      s8v ah = *(const s8v*)(wb + aq + ic * 4096);
      s8v bh = *(const s8v*)(bsrc + ic * 16);
      acc = __builtin_amdgcn_mfma_f32_32x32x16_bf16(ah, bh, acc, 0, 0, 0);
    }
  }

  // single-barrier cross-wave reduce; wave 0 writes outputs from registers
  if (wv > 0) {
#pragma unroll
    for (int r = 0; r < 16; ++r) {
      int ocr = (r & 3) + 8 * (r >> 2) + 4 * lhi;
      cd[(wv - 1) * 1024 + ocr * 32 + l31] = acc[r];
    }
  }
  __syncthreads();
  if (wv == 0) {
    float v[16];
#pragma unroll
    for (int r = 0; r < 16; ++r) {
      int ocr = (r & 3) + 8 * (r >> 2) + 4 * lhi;
      int idx = ocr * 32 + l31;
      v[r] = fmaxf(acc[r] + cd[idx] + cd[1024 + idx] + cd[2048 + idx] + bias[oc0 + ocr], 0.0f);
    }
    if constexpr (OUTMODE == 0) {
      size_t ro = (size_t)pb * (XROWS * 256) + (size_t)(8 + j0 + l31) * 256 + oc0 + 4 * lhi;
#pragma unroll
      for (int rq = 0; rq < 4; ++rq) {
        *(ushort4*)(yh + ro + 8 * rq) =
            make_ushort4(to_bf16(v[rq * 4 + 0]), to_bf16(v[rq * 4 + 1]),
                         to_bf16(v[rq * 4 + 2]), to_bf16(v[rq * 4 + 3]));
      }
    } else {
#pragma unroll
      for (int r = 0; r < 16; ++r) {
        int ocr = (r & 3) + 8 * (r >> 2) + 4 * lhi;
        size_t eo = (size_t)pb * 65536 + (size_t)(oc0 + ocr) * 256 + j0 + l31;
        eout[eo] = v[r];
        ebf[((size_t)pb * 256 + oc0 + ocr) * 256 + j0 + l31] = to_bf16(v[r]);
      }
    }
  }
}

// ---------------- ja projections: e (bf16) x W (hi/lo) -> 2 MFMAs, q/k bf16 ----------------
__global__ __launch_bounds__(256) void k_jam(const u16* __restrict__ ebf,
                                             const u16* __restrict__ wj,
                                             const float* __restrict__ b1,
                                             const float* __restrict__ b2,
                                             u16* __restrict__ qk) {
  __shared__ float cd[3072 + 1056];
  int blk = blockIdx.x;                 // pb(3) it(3) nt(3)
  int nt = blk & 7, it = (blk >> 3) & 7, pb = blk >> 6;
  int p = pb >> 2;
  int i0 = it * 32, n0 = nt * 32;
  int tid = threadIdx.x, wv = tid >> 6, lane = tid & 63;
  int l31 = lane & 31, lhi = lane >> 5;

  const u16* eh = ebf + ((size_t)pb * 256 + i0 + l31) * 256 + lhi * 8;
  const u16* wjh = wj + (size_t)(p * 2) * 65536;

  f32x16 acc = {};
#pragma unroll
  for (int c = 0; c < 4; ++c) {
    int kc = wv * 4 + c;
    int kg = kc * 2 + lhi;
    s8v ah = *(const s8v*)(eh + kc * 16);
    s8v bh = *(const s8v*)(wjh + ((size_t)kg * 256 + n0 + l31) * 8);
    s8v bl = *(const s8v*)(wjh + 65536 + ((size_t)kg * 256 + n0 + l31) * 8);
    acc = __builtin_amdgcn_mfma_f32_32x32x16_bf16(ah, bh, acc, 0, 0, 0);
    acc = __builtin_amdgcn_mfma_f32_32x32x16_bf16(ah, bl, acc, 0, 0, 0);
  }

  if (wv > 0) {
#pragma unroll
    for (int r = 0; r < 16; ++r) {
      int row = (r & 3) + 8 * (r >> 2) + 4 * lhi;
      cd[(wv - 1) * 1024 + row * 32 + l31] = acc[r];
    }
  }
  __syncthreads();
  if (wv == 0) {
    float bv = (p ? b2 : b1)[n0 + l31];
#pragma unroll
    for (int r = 0; r < 16; ++r) {
      int row = (r & 3) + 8 * (r >> 2) + 4 * lhi;
      int idx = row * 32 + l31;
      cd[3072 + row * 33 + l31] = acc[r] + cd[idx] + cd[1024 + idx] + cd[2048 + idx] + bv;
    }
  }
  __syncthreads();

  int row = tid & 31, c8 = tid >> 5;
  u16 hb[4];
#pragma unroll
  for (int cc = 0; cc < 4; ++cc)
    hb[cc] = to_bf16(cd[3072 + row * 33 + c8 * 4 + cc]);
  size_t ro = ((size_t)pb * 256 + i0 + row) * 256 + n0 + c8 * 4;
  *(ushort4*)(qk + ro) = make_ushort4(hb[0], hb[1], hb[2], hb[3]);
}

// ---------------- scores: q x k (both bf16) -> 1 MFMA per chunk ----------------
__global__ __launch_bounds__(256) void k_scoresm(const u16* __restrict__ qk,
                                                 float* __restrict__ S,
                                                 float* __restrict__ bsums) {
  __shared__ float cd[3072 + 1056];
  int blk = blockIdx.x;                 // b(2) it(3) jt(3)
  int jt = blk & 7, it = (blk >> 3) & 7, b = blk >> 6;
  int i0 = it * 32, j0 = jt * 32;
  int tid = threadIdx.x, wv = tid >> 6, lane = tid & 63;
  int l31 = lane & 31, lhi = lane >> 5;

  const u16* qh = qk + ((size_t)b * 256 + i0 + l31) * 256 + lhi * 8;
  const u16* kh = qk + ((size_t)(4 + b) * 256 + j0 + l31) * 256 + lhi * 8;

  f32x16 acc = {};
#pragma unroll
  for (int c = 0; c < 4; ++c) {
    int kc = wv * 4 + c;
    s8v a = *(const s8v*)(qh + kc * 16);
    s8v bb = *(const s8v*)(kh + kc * 16);
    acc = __builtin_amdgcn_mfma_f32_32x32x16_bf16(a, bb, acc, 0, 0, 0);
  }

  if (wv > 0) {
#pragma unroll
    for (int r = 0; r < 16; ++r) {
      int row = (r & 3) + 8 * (r >> 2) + 4 * lhi;
      cd[(wv - 1) * 1024 + row * 32 + l31] = acc[r];
    }
  }
  __syncthreads();
  if (wv == 0) {
    float psum = 0.0f;
#pragma unroll
    for (int r = 0; r < 16; ++r) {
      int row = (r & 3) + 8 * (r >> 2) + 4 * lhi;
      int idx = row * 32 + l31;
      float s = sig_fast(acc[r] + cd[idx] + cd[1024 + idx] + cd[2048 + idx]);
      psum += s;
      cd[3072 + row * 33 + l31] = s;
    }
    for (int off = 32; off; off >>= 1) psum += __shfl_down(psum, off, 64);
    if (lane == 0) bsums[blk] = psum;
  }
  __syncthreads();

  int row = tid & 31, c8 = tid >> 5;
  float4 v;
  v.x = cd[3072 + row * 33 + c8 * 4 + 0];
  v.y = cd[3072 + row * 33 + c8 * 4 + 1];
  v.z = cd[3072 + row * 33 + c8 * 4 + 2];
  v.w = cd[3072 + row * 33 + c8 * 4 + 3];
  *(float4*)(S + ((size_t)b * 256 + i0 + row) * 256 + j0 + c8 * 4) = v;
}

// ---------------- bilinear tanh pooling from raw S (+ writes normalized inter) --------
__global__ __launch_bounds__(256) void k_pool(const float* __restrict__ e1,
                                              const float* __restrict__ e2,
                                              const float* __restrict__ S,
                                              const float* __restrict__ bsums,
                                              float* __restrict__ inter_out,
                                              float* __restrict__ pp) {
  int blk = blockIdx.x;                 // b(2) ich(5) kch(4)
  int kch = blk & 15, ich = (blk >> 4) & 31, b = blk >> 9;
  int d = threadIdx.x, i0 = ich * 8, k0 = kch * 16;
  __shared__ float s2[16][8];
  __shared__ float red[128];
  __shared__ float ssp_s, tot_s;
  int t = threadIdx.x;
  int ii = t >> 4, kk = t & 15;
  float sv = 0.0f;
  if (t < 64) {
    float v = bsums[b * 64 + t];
    for (int off = 32; off; off >>= 1) v += __shfl_down(v, off, 64);
    if (t == 0) tot_s = v;
  }
  if (t < 128) {
    sv = S[((size_t)(b * 256 + i0 + ii)) * 256 + k0 + kk];
    s2[kk][ii] = 2.0f * sv;
    red[t] = sv;
  }
  __syncthreads();
  for (int st = 64; st; st >>= 1) {
    if (t < st) red[t] += red[t + st];
    __syncthreads();
  }
  if (t == 0) ssp_s = red[0];
  __syncthreads();

  float invt = 1.0f / tot_s;
  if (t < 128)
    inter_out[((size_t)(b * 256 + i0 + ii)) * 256 + k0 + kk] = sv * invt;

  constexpr float C2L = 2.8853900817779268f;   // 2*log2(e)
  float ev2[8];
#pragma unroll
  for (int i2 = 0; i2 < 8; ++i2)
    ev2[i2] = e1[((size_t)(b * L + i0 + i2)) * D + d] * C2L;

  float a0 = 0.f, a1 = 0.f, a2 = 0.f, a3 = 0.f;
  for (int k2 = 0; k2 < 16; ++k2) {
    float e2v = e2[((size_t)(b * L + k0 + k2)) * D + d];
    float s2r[8];
    *(float4*)&s2r[0] = *(const float4*)&s2[k2][0];
    *(float4*)&s2r[4] = *(const float4*)&s2[k2][4];
#pragma unroll
    for (int i2 = 0; i2 < 8; ++i2) {
      float r = __builtin_amdgcn_rcpf(__builtin_exp2f(ev2[i2] * e2v) + 1.0f);
      if ((i2 & 3) == 0) a0 = fmaf(r, s2r[i2], a0);
      else if ((i2 & 3) == 1) a1 = fmaf(r, s2r[i2], a1);
      else if ((i2 & 3) == 2) a2 = fmaf(r, s2r[i2], a2);
      else a3 = fmaf(r, s2r[i2], a3);
    }
  }
  float res = (ssp_s - (a0 + a1 + a2 + a3)) * invt;
  pp[(((size_t)b * 32 + ich) * 16 + kch) * 256 + d] = res;
}

__global__ __launch_bounds__(256) void k_poolcomb(const float* __restrict__ pp,
                                                  float* __restrict__ pooled) {
  int blk = blockIdx.x;                 // b(2) dt(3)
  int dt = blk & 7, b = blk >> 3;
  int t = threadIdx.x, dl = t & 31, mg = t >> 5;
  int d = dt * 32 + dl;
  float s = 0.f;
#pragma unroll
  for (int m = 0; m < 64; ++m)
    s += pp[((size_t)b * 512 + mg * 64 + m) * 256 + d];
  __shared__ float red[8][32];
  red[mg][dl] = s;
  __syncthreads();
  if (mg == 0) {
    float tot = red[0][dl] + red[1][dl] + red[2][dl] + red[3][dl] +
                red[4][dl] + red[5][dl] + red[6][dl] + red[7][dl];
    pooled[b * 256 + d] = tot;
  }
}

// ---------------- fc1 with fused head (conv+pool from pooled) ----------------
__global__ __launch_bounds__(256) void k_fc1h(const float* __restrict__ pooled,
                                              const float* __restrict__ rcw,
                                              const float* __restrict__ rcb,
                                              const float* __restrict__ w,
                                              float* __restrict__ f1p) {
  int blk = blockIdx.x;
  int ich = blk & 31, ot = blk >> 5;
  __shared__ float spb[4][258];
  __shared__ float hs[4][64];
  int t = threadIdx.x;
#pragma unroll
  for (int s = 0; s < 4; ++s) {
    int idx = s * 256 + t;
    spb[idx >> 8][(idx & 255) + 1] = pooled[idx];
  }
  if (t < 4) { spb[t][0] = 0.0f; spb[t][257] = 0.0f; }
  __syncthreads();
  {
    int b = t >> 6, idx = t & 63;
    int c = ich * 2 + (idx >> 5), m = idx & 31;
    float w0 = rcw[c * 4 + 0], w1 = rcw[c * 4 + 1], w2 = rcw[c * 4 + 2], w3 = rcw[c * 4 + 3];
    float bias = rcb[c];
    float mx = -1e30f;
#pragma unroll
    for (int r = 0; r < 4; ++r) {
      int p2 = 2 * (4 * m + r);
      float y = bias;
      y = fmaf(w0, spb[b][p2], y);
      y = fmaf(w1, spb[b][p2 + 1], y);
      y = fmaf(w2, spb[b][p2 + 2], y);
      y = fmaf(w3, spb[b][p2 + 3], y);
      mx = fmaxf(mx, lrelu(y));
    }
    hs[b][idx] = mx;
  }
  __syncthreads();

  int ol = t & 63, b = t >> 6;
  int o = ot * 64 + ol;
  int oc_ = o < 600 ? o : 599;
  const float* wb = w + (size_t)(ich * 64) * 600 + oc_;
  float a0 = 0.f, a1 = 0.f, a2 = 0.f, a3 = 0.f;
#pragma unroll 4
  for (int i = 0; i < 64; i += 4) {
    a0 = fmaf(hs[b][i], wb[(size_t)i * 600], a0);
    a1 = fmaf(hs[b][i + 1], wb[(size_t)(i + 1) * 600], a1);
    a2 = fmaf(hs[b][i + 2], wb[(size_t)(i + 2) * 600], a2);
    a3 = fmaf(hs[b][i + 3], wb[(size_t)(i + 3) * 600], a3);
  }
  if (o < 600) f1p[((size_t)ich * 4 + b) * 600 + o] = a0 + a1 + a2 + a3;
}

__global__ __launch_bounds__(256) void k_fc2(const float* __restrict__ f1p,
                                             const float* __restrict__ fc1b,
                                             const float* __restrict__ w,
                                             float* __restrict__ f2p) {
  int blk = blockIdx.x;
  int is = blk & 7, ot = blk >> 3;
  __shared__ float h1s[4][76];
  int t = threadIdx.x;
  for (int e = t; e < 300; e += 256) {
    int bb = e / 75, ii = e % 75;
    int i = is * 75 + ii;
    float s = fc1b[i];
#pragma unroll
    for (int ich = 0; ich < 32; ++ich) s += f1p[((size_t)ich * 4 + bb) * 600 + i];
    h1s[bb][ii] = lrelu(s);
  }
  __syncthreads();
  int ol = t & 63, b = t >> 6;
  int o = ot * 64 + ol, oc_ = o < 300 ? o : 299;
  const float* wb = w + (size_t)(is * 75) * 300 + oc_;
  float a0 = 0.f, a1 = 0.f, a2 = 0.f;
#pragma unroll 5
  for (int ii = 0; ii < 75; ii += 3) {
    a0 = fmaf(h1s[b][ii], wb[(size_t)ii * 300], a0);
    a1 = fmaf(h1s[b][ii + 1], wb[(size_t)(ii + 1) * 300], a1);
    a2 = fmaf(h1s[b][ii + 2], wb[(size_t)(ii + 2) * 300], a2);
  }
  if (o < 300) f2p[((size_t)is * 4 + b) * 300 + o] = a0 + a1 + a2;
}

__global__ __launch_bounds__(1024) void k_fc3f(const float* __restrict__ f2p,
                                               const float* __restrict__ fc2b,
                                               const float* __restrict__ w3,
                                               const float* __restrict__ fc3b,
                                               float* __restrict__ out) {
  __shared__ float h2s[4][304];
  int t = threadIdx.x;
  for (int e = t; e < 1200; e += 1024) {
    int o = e % 300, b = e / 300;
    float s = fc2b[o];
#pragma unroll
    for (int is = 0; is < 8; ++is) s += f2p[((size_t)is * 4 + b) * 300 + o];
    h2s[b][o] = lrelu(s);
  }
  __syncthreads();
  int wv = t >> 6, l = t & 63;
  if (wv < 4) {
    float s = 0.f;
#pragma unroll
    for (int m = 0; m < 5; ++m) {
      int i = m * 64 + l;
      if (i < 300) s = fmaf(h2s[wv][i], w3[i], s);
    }
    for (int off = 32; off; off >>= 1) s += __shfl_down(s, off, 64);
    if (l == 0) out[262144 + wv] = s + fc3b[0];
  }
}

extern "C" void kernel_launch(void* const* d_in, const int* in_sizes, int n_in,
                              void* d_out, int out_size, void* d_ws, size_t ws_size,
                              hipStream_t stream) {
  float* ws = (float*)d_ws;
  const int* p1 = (const int*)d_in[0];
  const int* p2 = (const int*)d_in[1];
  const float* emb  = (const float*)d_in[2];
  const float* w0   = (const float*)d_in[3];
  const float* b0   = (const float*)d_in[4];
  const float* w1   = (const float*)d_in[5];
  const float* b1   = (const float*)d_in[6];
  const float* w2   = (const float*)d_in[7];
  const float* b2   = (const float*)d_in[8];
  const float* ja1w = (const float*)d_in[9];
  const float* ja1b = (const float*)d_in[10];
  const float* ja2w = (const float*)d_in[11];
  const float* ja2b = (const float*)d_in[12];
  const float* rcw  = (const float*)d_in[13];
  const float* rcb  = (const float*)d_in[14];
  const float* fc1w = (const float*)d_in[15];
  const float* fc1b = (const float*)d_in[16];
  const float* fc2w = (const float*)d_in[17];
  const float* fc2b = (const float*)d_in[18];
  const float* fc3w = (const float*)d_in[19];
  const float* fc3b = (const float*)d_in[20];
  float* out = (float*)d_out;

  u16* xa  = (u16*)(ws + OFF_XA);
  u16* xb  = (u16*)(ws + OFF_XB);
  u16* wbu = (u16*)(ws + OFF_WB);
  u16* wju = (u16*)(ws + OFF_WJ);
  u16* ebf = (u16*)(ws + OFF_EBF);
  u16* qk  = (u16*)(ws + OFF_QK);

  k_prepall<<<1024, 256, 0, stream>>>(p1, p2, emb, w0, w1, w2, ja1w, ja2w, xa, xb, wbu, wju);

  k_cmf<4, 1, 0><<<512, 256, 0, stream>>>(xa, wbu + WB_L1, b0, xb, nullptr, nullptr);
  k_cmf<8, 3, 0><<<512, 256, 0, stream>>>(xb, wbu + WB_L2, b1, xa, nullptr, nullptr);
  k_cmf<12, 5, 1><<<512, 256, 0, stream>>>(xa, wbu + WB_L3, b2, nullptr, ws + OFF_E, ebf);

  k_jam<<<512, 256, 0, stream>>>(ebf, wju, ja1b, ja2b, qk);
  k_scoresm<<<256, 256, 0, stream>>>(qk, ws + OFF_S, ws + OFF_BS);

  k_pool<<<2048, 256, 0, stream>>>(ws + OFF_E, ws + OFF_E + SZ, ws + OFF_S, ws + OFF_BS,
                                   out, ws + OFF_PP);
  k_poolcomb<<<32, 256, 0, stream>>>(ws + OFF_PP, ws + OFF_POOL);

  k_fc1h<<<320, 256, 0, stream>>>(ws + OFF_POOL, rcw, rcb, fc1w, ws + OFF_F1P);
  k_fc2<<<40, 256, 0, stream>>>(ws + OFF_F1P, fc1b, fc2w, ws + OFF_F2P);
  k_fc3f<<<1, 1024, 0, stream>>>(ws + OFF_F2P, fc2b, fc3w, fc3b, out);
}